// Round 14
// baseline (391.500 us; speedup 1.0000x reference)
//
#include <hip/hip_runtime.h>
#include <math.h>

#define LDEC 512
#define LENC 2048
#define DMODEL 1024
#define NH 16
#define HD 64
#define SCALE 0.125f
#define NTOP 31
#define NSAMP 38

typedef __attribute__((ext_vector_type(8))) short bf16x8;
typedef __attribute__((ext_vector_type(4))) float f32x4;

__device__ inline float wave_sum(float v) {
#pragma unroll
  for (int m = 32; m > 0; m >>= 1) v += __shfl_xor(v, m);
  return v;
}

__device__ inline unsigned short f2bf(float x) {
  unsigned u = __float_as_uint(x);
  u += 0x7fff + ((u >> 16) & 1);  // RNE
  return (unsigned short)(u >> 16);
}
__device__ inline float bf2f(unsigned short h) {
  return __uint_as_float(((unsigned)h) << 16);
}

// ---------------- fp32 -> bf16 hi/lo split for dec (hi+lo) and enc (hi only)
__global__ __launch_bounds__(256) void cvt_in(const float* __restrict__ dec,
                                              const float* __restrict__ enc,
                                              unsigned short* __restrict__ dh,
                                              unsigned short* __restrict__ dl,
                                              unsigned short* __restrict__ eh) {
  int i = blockIdx.x * 256 + threadIdx.x;
  if (i < 262144) {
    float4 v = ((const float4*)dec)[i];
    ushort4 h = make_ushort4(f2bf(v.x), f2bf(v.y), f2bf(v.z), f2bf(v.w));
    ushort4 l = make_ushort4(f2bf(v.x - bf2f(h.x)), f2bf(v.y - bf2f(h.y)),
                             f2bf(v.z - bf2f(h.z)), f2bf(v.w - bf2f(h.w)));
    *(ushort4*)(dh + i * 4) = h;
    *(ushort4*)(dl + i * 4) = l;
  } else {
    int j = i - 262144;
    float4 v = ((const float4*)enc)[j];
    *(ushort4*)(eh + j * 4) =
        make_ushort4(f2bf(v.x), f2bf(v.y), f2bf(v.z), f2bf(v.w));
  }
}

// ---------------- W[k][n] fp32 -> Wt[n][k] bf16; z selects Wq(hi+lo)/Wk/Wv
__global__ __launch_bounds__(256) void cvt_w3(
    const float* __restrict__ Wq, const float* __restrict__ Wk,
    const float* __restrict__ Wv, unsigned short* __restrict__ Wqh,
    unsigned short* __restrict__ Wql, unsigned short* __restrict__ Wkh,
    unsigned short* __restrict__ Wvh) {
  __shared__ float t[64][68];
  int which = blockIdx.z;
  const float* W = which == 0 ? Wq : (which == 1 ? Wk : Wv);
  unsigned short* Th = which == 0 ? Wqh : (which == 1 ? Wkh : Wvh);
  unsigned short* Tl = which == 0 ? Wql : nullptr;
  int k0 = blockIdx.x * 64, n0 = blockIdx.y * 64;
  int tid = threadIdx.x;
#pragma unroll
  for (int i = 0; i < 4; ++i) {
    int c = tid + 256 * i;
    int r = c >> 4, c4 = (c & 15) * 4;
    float4 v = *(const float4*)(W + (size_t)(k0 + r) * DMODEL + n0 + c4);
    t[c4 + 0][r] = v.x; t[c4 + 1][r] = v.y; t[c4 + 2][r] = v.z; t[c4 + 3][r] = v.w;
  }
  __syncthreads();
#pragma unroll
  for (int i = 0; i < 4; ++i) {
    int c = tid + 256 * i;
    int n = c >> 4, k4 = (c & 15) * 4;
    float4 v = *(const float4*)&t[n][k4];
    ushort4 h = make_ushort4(f2bf(v.x), f2bf(v.y), f2bf(v.z), f2bf(v.w));
    *(ushort4*)(Th + (size_t)(n0 + n) * DMODEL + k0 + k4) = h;
    if (Tl) {
      ushort4 l = make_ushort4(f2bf(v.x - bf2f(h.x)), f2bf(v.y - bf2f(h.y)),
                               f2bf(v.z - bf2f(h.z)), f2bf(v.w - bf2f(h.w)));
      *(ushort4*)(Tl + (size_t)(n0 + n) * DMODEL + k0 + k4) = l;
    }
  }
}

// ---------------- W[k][n] fp32 -> Wt[n][k] bf16 hi only (Wo, late phase)
__global__ __launch_bounds__(256) void cvt_w(const float* __restrict__ W,
                                             unsigned short* __restrict__ Th) {
  __shared__ float t[64][68];
  int k0 = blockIdx.x * 64, n0 = blockIdx.y * 64;
  int tid = threadIdx.x;
#pragma unroll
  for (int i = 0; i < 4; ++i) {
    int c = tid + 256 * i;
    int r = c >> 4, c4 = (c & 15) * 4;
    float4 v = *(const float4*)(W + (size_t)(k0 + r) * DMODEL + n0 + c4);
    t[c4 + 0][r] = v.x; t[c4 + 1][r] = v.y; t[c4 + 2][r] = v.z; t[c4 + 3][r] = v.w;
  }
  __syncthreads();
#pragma unroll
  for (int i = 0; i < 4; ++i) {
    int c = tid + 256 * i;
    int n = c >> 4, k4 = (c & 15) * 4;
    float4 v = *(const float4*)&t[n][k4];
    *(ushort4*)(Th + (size_t)(n0 + n) * DMODEL + k0 + k4) =
        make_ushort4(f2bf(v.x), f2bf(v.y), f2bf(v.z), f2bf(v.w));
  }
}

// ---------------- fp32 -> bf16 flat (braw only)
__global__ __launch_bounds__(256) void cvt_braw(const float* __restrict__ src,
                                                unsigned short* __restrict__ dst) {
  int i = blockIdx.x * 256 + threadIdx.x;
  float4 v = ((const float4*)src)[i];
  *(ushort4*)(dst + i * 4) = make_ushort4(f2bf(v.x), f2bf(v.y), f2bf(v.z), f2bf(v.w));
}

// ---------------- sampled K rows in pure fp32 (top-k accuracy anchor)
__global__ __launch_bounds__(128) void k_samp(const float* __restrict__ enc,
                                              const float* __restrict__ Wk,
                                              const int* __restrict__ sidx,
                                              float* __restrict__ KsAcc) {
  __shared__ float er[1024];
  int s = blockIdx.x;
  int c = blockIdx.y * 128 + threadIdx.x;
  int srow = sidx[s];
#pragma unroll
  for (int i = 0; i < 2; ++i) {
    int idx = (threadIdx.x + 128 * i) * 4;
    *(float4*)&er[idx] = *(const float4*)(enc + (size_t)srow * DMODEL + idx);
  }
  __syncthreads();
  float acc = 0.f;
  for (int k = 0; k < 1024; ++k)
    acc = fmaf(er[k], Wk[(size_t)k * DMODEL + c], acc);
  KsAcc[s * DMODEL + c] = acc;
}

// ======= shared epilogue: 64x64 wave tile via LDS transpose (stride 72) ====
template <int BF16OUT>
__device__ __forceinline__ void gemm_epi64(
    unsigned short* sm, f32x4 (&acc)[4][4], float* __restrict__ C,
    unsigned short* __restrict__ Cb, int row0, int col0, int wave, int lane) {
  const int l16 = lane & 15, quad = lane >> 4;
  const int wr = wave >> 1, wc = wave & 1;
  float* eL = (float*)sm + wave * 1152;  // 16 rows x stride 72
  const int rr = lane >> 2, cc = (lane & 3) * 16;
#pragma unroll
  for (int x = 0; x < 4; ++x) {
#pragma unroll
    for (int y = 0; y < 4; ++y)
#pragma unroll
      for (int q = 0; q < 4; ++q)
        eL[(quad * 4 + q) * 72 + y * 16 + l16] = acc[x][y][q];
    size_t ro = (size_t)(row0 + wr * 64 + x * 16 + rr) * DMODEL + col0 + wc * 64 + cc;
    float4 v0 = *(const float4*)&eL[rr * 72 + cc];
    float4 v1 = *(const float4*)&eL[rr * 72 + cc + 4];
    float4 v2 = *(const float4*)&eL[rr * 72 + cc + 8];
    float4 v3 = *(const float4*)&eL[rr * 72 + cc + 12];
    if (BF16OUT) {
      uint4 o0, o1;
      o0.x = (unsigned)f2bf(v0.x) | ((unsigned)f2bf(v0.y) << 16);
      o0.y = (unsigned)f2bf(v0.z) | ((unsigned)f2bf(v0.w) << 16);
      o0.z = (unsigned)f2bf(v1.x) | ((unsigned)f2bf(v1.y) << 16);
      o0.w = (unsigned)f2bf(v1.z) | ((unsigned)f2bf(v1.w) << 16);
      o1.x = (unsigned)f2bf(v2.x) | ((unsigned)f2bf(v2.y) << 16);
      o1.y = (unsigned)f2bf(v2.z) | ((unsigned)f2bf(v2.w) << 16);
      o1.z = (unsigned)f2bf(v3.x) | ((unsigned)f2bf(v3.y) << 16);
      o1.w = (unsigned)f2bf(v3.z) | ((unsigned)f2bf(v3.w) << 16);
      *(uint4*)(Cb + ro) = o0;
      *(uint4*)(Cb + ro + 8) = o1;
    } else {
      *(float4*)(C + ro) = v0;
      *(float4*)(C + ro + 4) = v1;
      *(float4*)(C + ro + 8) = v2;
      *(float4*)(C + ro + 12) = v3;
    }
  }
}

// ======= 1-pass bf16 GEMM, 256 thr, 4 waves 2x2, wave-tile 64x64, dbuf LDS ==
template <int BF16OUT>
__device__ __forceinline__ void gemm256_db(
    const unsigned short* __restrict__ Ah, const unsigned short* __restrict__ Bh,
    float* __restrict__ C, unsigned short* __restrict__ Cb, int row0, int col0) {
  extern __shared__ unsigned short sm[];
  const int BUFS = 10240;
  const int tid = threadIdx.x, lane = tid & 63, wave = tid >> 6;
  const int l16 = lane & 15, quad = lane >> 4;
  const int wr = wave >> 1, wc = wave & 1;

  const int r = tid >> 2, kc = tid & 3;  // 2 chunks: rows r and r+64
  const unsigned short* gA0 = Ah + (size_t)(row0 + r) * DMODEL + kc * 8;
  const unsigned short* gA1 = Ah + (size_t)(row0 + r + 64) * DMODEL + kc * 8;
  const unsigned short* gB0 = Bh + (size_t)(col0 + r) * DMODEL + kc * 8;
  const unsigned short* gB1 = Bh + (size_t)(col0 + r + 64) * DMODEL + kc * 8;
  const int lo0 = r * 40 + kc * 8, lo1 = (r + 64) * 40 + kc * 8;

  f32x4 acc[4][4];
#pragma unroll
  for (int x = 0; x < 4; ++x)
#pragma unroll
    for (int y = 0; y < 4; ++y) acc[x][y] = (f32x4){0.f, 0.f, 0.f, 0.f};

  uint4 pa0 = *(const uint4*)gA0, pa1 = *(const uint4*)gA1;
  uint4 pb0 = *(const uint4*)gB0, pb1 = *(const uint4*)gB1;
  *(uint4*)&sm[lo0] = pa0; *(uint4*)&sm[lo1] = pa1;
  *(uint4*)&sm[5120 + lo0] = pb0; *(uint4*)&sm[5120 + lo1] = pb1;
  pa0 = *(const uint4*)(gA0 + 32); pa1 = *(const uint4*)(gA1 + 32);
  pb0 = *(const uint4*)(gB0 + 32); pb1 = *(const uint4*)(gB1 + 32);
  __syncthreads();

  for (int it = 0; it < 32; ++it) {
    const unsigned short* cur = sm + (it & 1) * BUFS;
    bf16x8 a[4], b[4];
#pragma unroll
    for (int x = 0; x < 4; ++x)
      a[x] = *(const bf16x8*)&cur[(wr * 64 + x * 16 + l16) * 40 + quad * 8];
#pragma unroll
    for (int y = 0; y < 4; ++y)
      b[y] = *(const bf16x8*)&cur[5120 + (wc * 64 + y * 16 + l16) * 40 + quad * 8];
#pragma unroll
    for (int x = 0; x < 4; ++x)
#pragma unroll
      for (int y = 0; y < 4; ++y)
        acc[x][y] = __builtin_amdgcn_mfma_f32_16x16x32_bf16(a[x], b[y], acc[x][y], 0, 0, 0);
    if (it < 31) {
      unsigned short* nxt = sm + ((it + 1) & 1) * BUFS;
      *(uint4*)&nxt[lo0] = pa0; *(uint4*)&nxt[lo1] = pa1;
      *(uint4*)&nxt[5120 + lo0] = pb0; *(uint4*)&nxt[5120 + lo1] = pb1;
      if (it < 30) {
        int ko = (it + 2) * 32;
        pa0 = *(const uint4*)(gA0 + ko); pa1 = *(const uint4*)(gA1 + ko);
        pb0 = *(const uint4*)(gB0 + ko); pb1 = *(const uint4*)(gB1 + ko);
      }
    }
    __syncthreads();
  }
  gemm_epi64<BF16OUT>(sm, acc, C, Cb, row0, col0, wave, lane);
}

// ======= 3-pass hi/lo GEMM, 256 thr, wave-tile 64x64, single-buffer LDS =====
__device__ __forceinline__ void gemm256_3p(
    const unsigned short* __restrict__ Ah, const unsigned short* __restrict__ Al,
    const unsigned short* __restrict__ Bh, const unsigned short* __restrict__ Bl,
    float* __restrict__ C, int row0, int col0) {
  extern __shared__ unsigned short sm[];
  const int tid = threadIdx.x, lane = tid & 63, wave = tid >> 6;
  const int l16 = lane & 15, quad = lane >> 4;
  const int wr = wave >> 1, wc = wave & 1;

  const int r = tid >> 2, kc = tid & 3;
  const unsigned short* gAh0 = Ah + (size_t)(row0 + r) * DMODEL + kc * 8;
  const unsigned short* gAh1 = Ah + (size_t)(row0 + r + 64) * DMODEL + kc * 8;
  const unsigned short* gBh0 = Bh + (size_t)(col0 + r) * DMODEL + kc * 8;
  const unsigned short* gBh1 = Bh + (size_t)(col0 + r + 64) * DMODEL + kc * 8;
  const unsigned short* gAl0 = Al + (size_t)(row0 + r) * DMODEL + kc * 8;
  const unsigned short* gAl1 = Al + (size_t)(row0 + r + 64) * DMODEL + kc * 8;
  const unsigned short* gBl0 = Bl + (size_t)(col0 + r) * DMODEL + kc * 8;
  const unsigned short* gBl1 = Bl + (size_t)(col0 + r + 64) * DMODEL + kc * 8;
  const int lo0 = r * 40 + kc * 8, lo1 = (r + 64) * 40 + kc * 8;

  f32x4 acc[4][4];
#pragma unroll
  for (int x = 0; x < 4; ++x)
#pragma unroll
    for (int y = 0; y < 4; ++y) acc[x][y] = (f32x4){0.f, 0.f, 0.f, 0.f};

  uint4 ph0 = *(const uint4*)gAh0, ph1 = *(const uint4*)gAh1;
  uint4 ph2 = *(const uint4*)gBh0, ph3 = *(const uint4*)gBh1;
  uint4 pl0 = *(const uint4*)gAl0, pl1 = *(const uint4*)gAl1;
  uint4 pl2 = *(const uint4*)gBl0, pl3 = *(const uint4*)gBl1;
  *(uint4*)&sm[lo0] = ph0; *(uint4*)&sm[lo1] = ph1;
  *(uint4*)&sm[5120 + lo0] = ph2; *(uint4*)&sm[5120 + lo1] = ph3;
  *(uint4*)&sm[10240 + lo0] = pl0; *(uint4*)&sm[10240 + lo1] = pl1;
  *(uint4*)&sm[15360 + lo0] = pl2; *(uint4*)&sm[15360 + lo1] = pl3;
  __syncthreads();

  for (int it = 0; it < 32; ++it) {
    if (it < 31) {
      int ko = (it + 1) * 32;
      ph0 = *(const uint4*)(gAh0 + ko); ph1 = *(const uint4*)(gAh1 + ko);
      ph2 = *(const uint4*)(gBh0 + ko); ph3 = *(const uint4*)(gBh1 + ko);
      pl0 = *(const uint4*)(gAl0 + ko); pl1 = *(const uint4*)(gAl1 + ko);
      pl2 = *(const uint4*)(gBl0 + ko); pl3 = *(const uint4*)(gBl1 + ko);
    }
    bf16x8 ah[4], bh[4], al[4], bl[4];
#pragma unroll
    for (int x = 0; x < 4; ++x) {
      ah[x] = *(const bf16x8*)&sm[(wr * 64 + x * 16 + l16) * 40 + quad * 8];
      al[x] = *(const bf16x8*)&sm[10240 + (wr * 64 + x * 16 + l16) * 40 + quad * 8];
    }
#pragma unroll
    for (int y = 0; y < 4; ++y) {
      bh[y] = *(const bf16x8*)&sm[5120 + (wc * 64 + y * 16 + l16) * 40 + quad * 8];
      bl[y] = *(const bf16x8*)&sm[15360 + (wc * 64 + y * 16 + l16) * 40 + quad * 8];
    }
#pragma unroll
    for (int x = 0; x < 4; ++x)
#pragma unroll
      for (int y = 0; y < 4; ++y) {
        acc[x][y] = __builtin_amdgcn_mfma_f32_16x16x32_bf16(ah[x], bh[y], acc[x][y], 0, 0, 0);
        acc[x][y] = __builtin_amdgcn_mfma_f32_16x16x32_bf16(ah[x], bl[y], acc[x][y], 0, 0, 0);
        acc[x][y] = __builtin_amdgcn_mfma_f32_16x16x32_bf16(al[x], bh[y], acc[x][y], 0, 0, 0);
      }
    __syncthreads();
    if (it < 31) {
      *(uint4*)&sm[lo0] = ph0; *(uint4*)&sm[lo1] = ph1;
      *(uint4*)&sm[5120 + lo0] = ph2; *(uint4*)&sm[5120 + lo1] = ph3;
      *(uint4*)&sm[10240 + lo0] = pl0; *(uint4*)&sm[10240 + lo1] = pl1;
      *(uint4*)&sm[15360 + lo0] = pl2; *(uint4*)&sm[15360 + lo1] = pl3;
    }
    __syncthreads();
  }
  gemm_epi64<0>(sm, acc, C, nullptr, row0, col0, wave, lane);
}

// merged Q(3-pass) + K(1-pass,bf16-out) + V(1-pass) — uniform 40960 B LDS
__global__ __launch_bounds__(256, 4) void gemm_qkv(
    const unsigned short* __restrict__ dh, const unsigned short* __restrict__ dl,
    const unsigned short* __restrict__ Wqh, const unsigned short* __restrict__ Wql,
    float* __restrict__ Q,
    const unsigned short* __restrict__ eh, const unsigned short* __restrict__ Wkh,
    unsigned short* __restrict__ Kb16,
    const unsigned short* __restrict__ Wvh, float* __restrict__ V) {
  int bx = blockIdx.x;
  if (bx < 8)
    gemm256_3p(dh, dl, Wqh, Wql, Q, bx * 128, blockIdx.y * 128);
  else if (bx < 40)
    gemm256_db<1>(eh, Wkh, nullptr, Kb16, (bx - 8) * 128, blockIdx.y * 128);
  else
    gemm256_db<0>(eh, Wvh, V, nullptr, (bx - 40) * 128, blockIdx.y * 128);
}

__global__ __launch_bounds__(256, 4) void gemm_one(
    const unsigned short* __restrict__ Ah, const unsigned short* __restrict__ Bh,
    float* __restrict__ C) {
  gemm256_db<0>(Ah, Bh, C, nullptr, blockIdx.x * 128, blockIdx.y * 128);
}

// V fp32 -> bf16 transposed per head: Vt[(b*16+h)*64 + d][s]
__global__ __launch_bounds__(256) void cvt_vt(const float* __restrict__ V,
                                              unsigned short* __restrict__ Vt) {
  __shared__ unsigned short tile[64][72];
  int bh = blockIdx.x >> 5;
  int s0 = (blockIdx.x & 31) * 64;
  int b = bh >> 4, h = bh & 15;
  int tid = threadIdx.x;
#pragma unroll
  for (int i = 0; i < 4; ++i) {
    int c = tid + 256 * i;
    int s = c >> 4, d4 = (c & 15) * 4;
    float4 v = *(const float4*)(V + (size_t)(b * LENC + s0 + s) * DMODEL + h * HD + d4);
    tile[d4 + 0][s] = f2bf(v.x);
    tile[d4 + 1][s] = f2bf(v.y);
    tile[d4 + 2][s] = f2bf(v.z);
    tile[d4 + 3][s] = f2bf(v.w);
  }
  __syncthreads();
#pragma unroll
  for (int i = 0; i < 2; ++i) {
    int c = tid + 256 * i;
    int d = c >> 3, soff = (c & 7) * 8;
    uint4 o = *(const uint4*)&tile[d][soff];
    *(uint4*)(Vt + (size_t)(bh * 64 + d) * LENC + s0 + soff) = o;
  }
}

// ---------------- MFMA flash attention, split-K 2-way + XCD swizzle, bf16 K
#define TSTR 72

__global__ __launch_bounds__(256) void attn_mfma(
    const float* __restrict__ Qf, const unsigned short* __restrict__ Kb,
    const unsigned short* __restrict__ Vt,
    float* __restrict__ Ps0, float* __restrict__ Ps1,
    float* __restrict__ Pl0, float* __restrict__ Pl1,
    float* __restrict__ st) {
  __shared__ unsigned short Ks[2][64 * TSTR];
  __shared__ unsigned short Vs[2][64 * TSTR];
  __shared__ unsigned short Ps[4][16 * TSTR];
  const int tid = threadIdx.x;
  const int wave = tid >> 6, lane = tid & 63;
  const int l16 = lane & 15, quad = lane >> 4;
  const int bx = blockIdx.x;
  const int xcd = bx & 7, sub = bx >> 3;
  const int qt = sub & 7, half = (sub >> 3) & 1, grp = sub >> 4;
  const int bh = xcd + 8 * grp;
  const int b = bh >> 4, h = bh & 15;
  const int tbase = qt * 64 + wave * 16;
  const int sbase = half * 1024;

  const float* qrow = Qf + (size_t)(b * LDEC + tbase + l16) * DMODEL + h * HD + quad * 8;
  bf16x8 qa0, qa1;
  {
    float4 a0 = *(const float4*)qrow, a1 = *(const float4*)(qrow + 4);
    float4 a2 = *(const float4*)(qrow + 32), a3 = *(const float4*)(qrow + 36);
    qa0[0] = f2bf(a0.x * SCALE); qa0[1] = f2bf(a0.y * SCALE);
    qa0[2] = f2bf(a0.z * SCALE); qa0[3] = f2bf(a0.w * SCALE);
    qa0[4] = f2bf(a1.x * SCALE); qa0[5] = f2bf(a1.y * SCALE);
    qa0[6] = f2bf(a1.z * SCALE); qa0[7] = f2bf(a1.w * SCALE);
    qa1[0] = f2bf(a2.x * SCALE); qa1[1] = f2bf(a2.y * SCALE);
    qa1[2] = f2bf(a2.z * SCALE); qa1[3] = f2bf(a2.w * SCALE);
    qa1[4] = f2bf(a3.x * SCALE); qa1[5] = f2bf(a3.y * SCALE);
    qa1[6] = f2bf(a3.z * SCALE); qa1[7] = f2bf(a3.w * SCALE);
  }

  int loC[4], hiC[4];
#pragma unroll
  for (int r = 0; r < 4; ++r) {
    int t = tbase + quad * 4 + r;
    int c = min(4 * t, LENC - 1);
    loC[r] = max(c - 256, 0); hiC[r] = min(c + 256, LENC - 1);
  }
  int tA = tbase + l16;
  int cA = min(4 * tA, LENC - 1);
  int loA = max(cA - 256, 0), hiA = min(cA + 256, LENC - 1);
  const int loW = max(4 * tbase - 256, 0);
  const int hiW = min(4 * (tbase + 15) + 256, LENC - 1);

  f32x4 Os[4], Ol[4];
#pragma unroll
  for (int n = 0; n < 4; ++n) {
    Os[n] = (f32x4){0.f, 0.f, 0.f, 0.f};
    Ol[n] = (f32x4){0.f, 0.f, 0.f, 0.f};
  }
  float lS[4], lL[4];
#pragma unroll
  for (int r = 0; r < 4; ++r) { lS[r] = 0.f; lL[r] = 0.f; }

  const int c0 = tid, c1 = tid + 256;
  const unsigned short* kg0 = Kb + (size_t)(b * LENC + sbase + (c0 >> 3)) * DMODEL + h * HD + (c0 & 7) * 8;
  const unsigned short* kg1 = Kb + (size_t)(b * LENC + sbase + (c1 >> 3)) * DMODEL + h * HD + (c1 & 7) * 8;
  const unsigned short* vg0 = Vt + (size_t)(bh * 64 + (c0 >> 3)) * LENC + sbase + (c0 & 7) * 8;
  const unsigned short* vg1 = Vt + (size_t)(bh * 64 + (c1 >> 3)) * LENC + sbase + (c1 & 7) * 8;
  const int of0 = (c0 >> 3) * TSTR + (c0 & 7) * 8;
  const int of1 = (c1 >> 3) * TSTR + (c1 & 7) * 8;

  uint4 pk0, pk1, pv0, pv1;
  pk0 = *(const uint4*)kg0; pk1 = *(const uint4*)kg1;
  pv0 = *(const uint4*)vg0; pv1 = *(const uint4*)vg1;
  *(uint4*)&Ks[0][of0] = pk0; *(uint4*)&Ks[0][of1] = pk1;
  *(uint4*)&Vs[0][of0] = pv0; *(uint4*)&Vs[0][of1] = pv1;
  __syncthreads();

  for (int it = 0; it < 16; ++it) {
    const int cur = it & 1;
    const int s0 = sbase + it * 64;
    const bool anyL = (s0 <= hiW) && (s0 + 63 >= loW);
    if (it < 15) {
      pk0 = *(const uint4*)(kg0 + (size_t)(it + 1) * 64 * DMODEL);
      pk1 = *(const uint4*)(kg1 + (size_t)(it + 1) * 64 * DMODEL);
      pv0 = *(const uint4*)(vg0 + (it + 1) * 64);
      pv1 = *(const uint4*)(vg1 + (it + 1) * 64);
    }
    const unsigned short* K_ = Ks[cur];
    const unsigned short* V_ = Vs[cur];

    f32x4 S[4];
#pragma unroll
    for (int n = 0; n < 4; ++n) {
      bf16x8 bk0 = *(const bf16x8*)&K_[(n * 16 + l16) * TSTR + quad * 8];
      bf16x8 bk1 = *(const bf16x8*)&K_[(n * 16 + l16) * TSTR + 32 + quad * 8];
      f32x4 z = (f32x4){0.f, 0.f, 0.f, 0.f};
      z = __builtin_amdgcn_mfma_f32_16x16x32_bf16(qa0, bk0, z, 0, 0, 0);
      S[n] = __builtin_amdgcn_mfma_f32_16x16x32_bf16(qa1, bk1, z, 0, 0, 0);
    }

    float e[4][4];
#pragma unroll
    for (int r = 0; r < 4; ++r) {
#pragma unroll
      for (int n = 0; n < 4; ++n) e[n][r] = __expf(S[n][r]);
      float se = e[0][r] + e[1][r] + e[2][r] + e[3][r];
      float sl = 0.f;
      if (anyL) {
#pragma unroll
        for (int n = 0; n < 4; ++n) {
          int sc = s0 + n * 16 + l16;
          sl += (sc >= loC[r] && sc <= hiC[r]) ? e[n][r] : 0.f;
        }
      }
#pragma unroll
      for (int d = 1; d < 16; d <<= 1) { se += __shfl_xor(se, d); sl += __shfl_xor(sl, d); }
      lS[r] += se;
      lL[r] += sl;
    }

    unsigned short* Pw = Ps[wave];
#pragma unroll
    for (int n = 0; n < 4; ++n)
#pragma unroll
      for (int r = 0; r < 4; ++r)
        Pw[(quad * 4 + r) * TSTR + n * 16 + l16] = f2bf(e[n][r]);
    bf16x8 aP0 = *(const bf16x8*)&Pw[l16 * TSTR + quad * 8];
    bf16x8 aP1 = *(const bf16x8*)&Pw[l16 * TSTR + 32 + quad * 8];
#pragma unroll
    for (int n = 0; n < 4; ++n) {
      bf16x8 bv0 = *(const bf16x8*)&V_[(n * 16 + l16) * TSTR + quad * 8];
      bf16x8 bv1 = *(const bf16x8*)&V_[(n * 16 + l16) * TSTR + 32 + quad * 8];
      Os[n] = __builtin_amdgcn_mfma_f32_16x16x32_bf16(aP0, bv0, Os[n], 0, 0, 0);
      Os[n] = __builtin_amdgcn_mfma_f32_16x16x32_bf16(aP1, bv1, Os[n], 0, 0, 0);
    }
    if (anyL) {
      bf16x8 aL0 = aP0, aL1 = aP1;
#pragma unroll
      for (int j = 0; j < 8; ++j) {
        int sc = s0 + quad * 8 + j;
        if (sc < loA || sc > hiA) aL0[j] = 0;
        if (sc + 32 < loA || sc + 32 > hiA) aL1[j] = 0;
      }
#pragma unroll
      for (int n = 0; n < 4; ++n) {
        bf16x8 bv0 = *(const bf16x8*)&V_[(n * 16 + l16) * TSTR + quad * 8];
        bf16x8 bv1 = *(const bf16x8*)&V_[(n * 16 + l16) * TSTR + 32 + quad * 8];
        Ol[n] = __builtin_amdgcn_mfma_f32_16x16x32_bf16(aL0, bv0, Ol[n], 0, 0, 0);
        Ol[n] = __builtin_amdgcn_mfma_f32_16x16x32_bf16(aL1, bv1, Ol[n], 0, 0, 0);
      }
    }
    __syncthreads();
    if (it < 15) {
      unsigned short* KL = Ks[1 - cur];
      unsigned short* VL = Vs[1 - cur];
      *(uint4*)&KL[of0] = pk0; *(uint4*)&KL[of1] = pk1;
      *(uint4*)&VL[of0] = pv0; *(uint4*)&VL[of1] = pv1;
    }
    __syncthreads();
  }

  float* osdp = half ? Ps1 : Ps0;
  float* oloc = half ? Pl1 : Pl0;
  float* sp = st + half * 32768;
#pragma unroll
  for (int r = 0; r < 4; ++r) {
    int t = tbase + quad * 4 + r;
#pragma unroll
    for (int n = 0; n < 4; ++n) {
      size_t o = (size_t)(b * LDEC + t) * DMODEL + h * HD + n * 16 + l16;
      osdp[o] = Os[n][r];
      oloc[o] = Ol[n][r];
    }
    if (l16 == 0) {
      int sr = bh * 512 + t;
      sp[sr] = lS[r];
      sp[16384 + sr] = lL[r];
    }
  }
}

// fused: split-K combine (plain sums, max-free) + probsparse fill
__global__ __launch_bounds__(256) void combine_fill(
    float* __restrict__ braw, const float* __restrict__ Ps1,
    const float* __restrict__ Pl1, const float* __restrict__ st,
    const float* __restrict__ vmean, const int* __restrict__ sel) {
  int i4 = blockIdx.x * 256 + threadIdx.x;
  int i = i4 * 4;
  int col = i & 1023, bt = i >> 10;
  int t = bt & 511, b = bt >> 9, h = col >> 6, d = col & 63;
  int bh = b * 16 + h;
  int sr = bh * 512 + t;
  float iS = 1.f / (st[sr] + st[32768 + sr]);
  float iL = 1.f / (st[16384 + sr] + st[49152 + sr]);
  float4 s0 = *(const float4*)(braw + i);
  float4 s1 = *(const float4*)(Ps1 + i);
  float4 l0 = *(const float4*)(braw + 4194304 + i);
  float4 l1 = *(const float4*)(Pl1 + i);
  float4 os = make_float4((s0.x + s1.x) * iS, (s0.y + s1.y) * iS,
                          (s0.z + s1.z) * iS, (s0.w + s1.w) * iS);
  float4 ol = make_float4((l0.x + l1.x) * iL, (l0.y + l1.y) * iL,
                          (l0.z + l1.z) * iL, (l0.w + l1.w) * iL);
  *(float4*)(braw + i) = os;
  *(float4*)(braw + 4194304 + i) = ol;
  float4 pp = sel[sr] ? os : *(const float4*)(vmean + bh * 64 + d);
  *(float4*)(braw + 2097152 + i) = pp;
}

// ---------------- linear + cosine branch stats (split-K, 16 parts; bf16 K)
__global__ __launch_bounds__(256) void lin_cos_stats(
    const unsigned short* __restrict__ Kb, const float* __restrict__ V,
    float* __restrict__ kvpL, float* __restrict__ kvpC,
    float* __restrict__ kspL, float* __restrict__ kspC, float* __restrict__ vsp) {
  __shared__ float kS[64][68];
  __shared__ float vSS[64][68];
  __shared__ float nrm[64];
  int bx = blockIdx.x;
  int bh = bx >> 4, part = bx & 15;
  int b = bh >> 4, h = bh & 15;
  int tid = threadIdx.x, lane = tid & 63, g = tid >> 6;
  const float* Vb = V + (b * LENC) * DMODEL + h * HD;
  float accL[16], accC[16];
#pragma unroll
  for (int i = 0; i < 16; ++i) { accL[i] = 0.f; accC[i] = 0.f; }
  float ksl = 0.f, ksc = 0.f, vs = 0.f;
  for (int tile = 0; tile < 2; ++tile) {
    int s0 = part * 128 + tile * 64;
#pragma unroll
    for (int i = 0; i < 2; ++i) {
      int slot = tid + 256 * i;
      int j = slot >> 3, d8 = (slot & 7) * 8;
      uint4 kv = *(const uint4*)(Kb + (size_t)(b * LENC + s0 + j) * DMODEL + h * HD + d8);
      const unsigned short* sp16 = (const unsigned short*)&kv;
#pragma unroll
      for (int q = 0; q < 8; ++q) kS[j][d8 + q] = bf2f(sp16[q]);
    }
#pragma unroll
    for (int i = 0; i < 4; ++i) {
      int slot = tid + 256 * i;
      int j = slot >> 4, d4 = slot & 15;
      *(float4*)&vSS[j][d4 * 4] = *(const float4*)(Vb + (s0 + j) * DMODEL + d4 * 4);
    }
    __syncthreads();
#pragma unroll
    for (int rr = 0; rr < 16; ++rr) {
      int row = g * 16 + rr;
      float x = kS[row][lane];
      float ssum = wave_sum(x * x);
      if (lane == 0) nrm[row] = sqrtf(ssum);
    }
    __syncthreads();
    for (int s = 0; s < 64; ++s) {
      float kval = kS[s][lane];
      float kfl = kval > 0.f ? kval + 1.f : __expf(kval);
      float kn = kval / fmaxf(nrm[s], 1e-12f);
      float kfc = fmaxf(kn, 0.f) + 1e-6f;
      const float4* vrow = (const float4*)&vSS[s][g * 16];
      float4 v0 = vrow[0], v1 = vrow[1], v2 = vrow[2], v3 = vrow[3];
      accL[0] = fmaf(kfl, v0.x, accL[0]);   accC[0] = fmaf(kfc, v0.x, accC[0]);
      accL[1] = fmaf(kfl, v0.y, accL[1]);   accC[1] = fmaf(kfc, v0.y, accC[1]);
      accL[2] = fmaf(kfl, v0.z, accL[2]);   accC[2] = fmaf(kfc, v0.z, accC[2]);
      accL[3] = fmaf(kfl, v0.w, accL[3]);   accC[3] = fmaf(kfc, v0.w, accC[3]);
      accL[4] = fmaf(kfl, v1.x, accL[4]);   accC[4] = fmaf(kfc, v1.x, accC[4]);
      accL[5] = fmaf(kfl, v1.y, accL[5]);   accC[5] = fmaf(kfc, v1.y, accC[5]);
      accL[6] = fmaf(kfl, v1.z, accL[6]);   accC[6] = fmaf(kfc, v1.z, accC[6]);
      accL[7] = fmaf(kfl, v1.w, accL[7]);   accC[7] = fmaf(kfc, v1.w, accC[7]);
      accL[8] = fmaf(kfl, v2.x, accL[8]);   accC[8] = fmaf(kfc, v2.x, accC[8]);
      accL[9] = fmaf(kfl, v2.y, accL[9]);   accC[9] = fmaf(kfc, v2.y, accC[9]);
      accL[10] = fmaf(kfl, v2.z, accL[10]); accC[10] = fmaf(kfc, v2.z, accC[10]);
      accL[11] = fmaf(kfl, v2.w, accL[11]); accC[11] = fmaf(kfc, v2.w, accC[11]);
      accL[12] = fmaf(kfl, v3.x, accL[12]); accC[12] = fmaf(kfc, v3.x, accC[12]);
      accL[13] = fmaf(kfl, v3.y, accL[13]); accC[13] = fmaf(kfc, v3.y, accC[13]);
      accL[14] = fmaf(kfl, v3.z, accL[14]); accC[14] = fmaf(kfc, v3.z, accC[14]);
      accL[15] = fmaf(kfl, v3.w, accL[15]); accC[15] = fmaf(kfc, v3.w, accC[15]);
      if (g == 0) { ksl += kfl; ksc += kfc; vs += vSS[s][lane]; }
    }
    __syncthreads();
  }
  int base = part * 131072 + bh * 4096 + lane * 64 + g * 16;
#pragma unroll
  for (int i4 = 0; i4 < 4; ++i4) {
    *(float4*)&kvpL[base + i4 * 4] = make_float4(accL[i4*4], accL[i4*4+1], accL[i4*4+2], accL[i4*4+3]);
    *(float4*)&kvpC[base + i4 * 4] = make_float4(accC[i4*4], accC[i4*4+1], accC[i4*4+2], accC[i4*4+3]);
  }
  if (g == 0) {
    kspL[part * 2048 + bh * 64 + lane] = ksl;
    kspC[part * 2048 + bh * 64 + lane] = ksc;
    vsp[part * 2048 + bh * 64 + lane] = vs;
  }
}

// fused reduction of all lin/cos partials
__global__ __launch_bounds__(256) void reduce_all(
    const float* __restrict__ kvpL, const float* __restrict__ kvpC,
    const float* __restrict__ kspL, const float* __restrict__ kspC,
    const float* __restrict__ vsp, float* __restrict__ kvL,
    float* __restrict__ kvC, float* __restrict__ ksL,
    float* __restrict__ ksC, float* __restrict__ vmean) {
  int i = blockIdx.x * 256 + threadIdx.x;
  if (i < 131072) {
    float s = 0.f;
#pragma unroll
    for (int p = 0; p < 16; ++p) s += kvpL[p * 131072 + i];
    kvL[i] = s;
  } else if (i < 262144) {
    int j = i - 131072;
    float s = 0.f;
#pragma unroll
    for (int p = 0; p < 16; ++p) s += kvpC[p * 131072 + j];
    kvC[j] = s;
  } else {
    int j = i - 262144;
    int which = j >> 11, jj = j & 2047;
    const float* src = which == 0 ? kspL : (which == 1 ? kspC : vsp);
    float s = 0.f;
#pragma unroll
    for (int p = 0; p < 16; ++p) s += src[p * 2048 + jj];
    if (which == 0) ksL[jj] = s;
    else if (which == 1) ksC[jj] = s;
    else vmean[jj] = s * (1.f / 2048.f);
  }
}

// ---------------- linear + cosine apply
__global__ __launch_bounds__(256) void lin_cos_apply(
    const float* __restrict__ Q, const float* __restrict__ kvL, const float* __restrict__ kvC,
    const float* __restrict__ ksL, const float* __restrict__ ksC,
    float* __restrict__ obL, float* __restrict__ obC) {
  __shared__ float sh[2][4][64];
  int tid = threadIdx.x, lane = tid & 63, g = tid >> 6;
  int row = blockIdx.x * 4 + g;
  int bh = row >> 9, t = row & 511;
  int b = bh >> 4, h = bh & 15;
  float qv = Q[(b * LDEC + t) * DMODEL + h * HD + lane];
  float x = qv * SCALE;
  float qfl = x > 0.f ? x + 1.f : __expf(x);
  float qnorm = sqrtf(wave_sum(qv * qv));
  float qn = qv / fmaxf(qnorm, 1e-12f);
  float qfc = fmaxf(qn, 0.f) + 1e-6f;
  sh[0][g][lane] = qfl;
  sh[1][g][lane] = qfc;
  float denL = fmaxf(wave_sum(qfl * ksL[bh * 64 + lane]), 1e-6f);
  float denC = fmaxf(wave_sum(qfc * ksC[bh * 64 + lane]), 1e-6f);
  const float* kvLb = kvL + bh * 4096;
  const float* kvCb = kvC + bh * 4096;
  float aL = 0.f, aC = 0.f;
#pragma unroll
  for (int d = 0; d < 64; ++d) {
    aL = fmaf(sh[0][g][d], kvLb[d * 64 + lane], aL);
    aC = fmaf(sh[1][g][d], kvCb[d * 64 + lane], aC);
  }
  int o = (b * LDEC + t) * DMODEL + h * HD + lane;
  obL[o] = aL / denL;
  obC[o] = aC / denC;
}

// ---------------- probsparse: sampled scores -> M (fp32 Q + fp32 KsAcc)
__global__ __launch_bounds__(128) void pp_scores(
    const float* __restrict__ Q, const float* __restrict__ KsAcc,
    float* __restrict__ Mout) {
  __shared__ float qL[128][65];
  __shared__ float ksL[NSAMP][65];
  int bx = blockIdx.x;
  int bh = bx >> 2, chunk = bx & 3;
  int b = bh >> 4, h = bh & 15;
  int t0 = chunk * 128;
  int tid = threadIdx.x;
  const float* Qb = Q + (b * LDEC) * DMODEL + h * HD;
#pragma unroll
  for (int i = 0; i < 16; ++i) {
    int slot = tid + 128 * i;
    int r = slot >> 4, c4 = slot & 15;
    float4 qx = *(const float4*)(Qb + (t0 + r) * DMODEL + c4 * 4);
    qL[r][c4 * 4 + 0] = qx.x; qL[r][c4 * 4 + 1] = qx.y;
    qL[r][c4 * 4 + 2] = qx.z; qL[r][c4 * 4 + 3] = qx.w;
  }
  for (int slot = tid; slot < NSAMP * 16; slot += 128) {
    int r = slot >> 4, c4 = slot & 15;
    float4 kx = *(const float4*)(KsAcc + r * DMODEL + h * HD + c4 * 4);
    ksL[r][c4 * 4 + 0] = kx.x; ksL[r][c4 * 4 + 1] = kx.y;
    ksL[r][c4 * 4 + 2] = kx.z; ksL[r][c4 * 4 + 3] = kx.w;
  }
  __syncthreads();
  float qr[64];
#pragma unroll
  for (int d = 0; d < 64; ++d) qr[d] = qL[tid][d];
  float mx = -INFINITY, sm = 0.f;
  for (int j = 0; j < NSAMP; ++j) {
    float s = 0.f;
#pragma unroll
    for (int d = 0; d < 64; ++d) s = fmaf(qr[d], ksL[j][d], s);
    s *= SCALE;
    mx = fmaxf(mx, s);
    sm += s;
  }
  Mout[bh * LDEC + t0 + tid] = mx - sm / (float)NSAMP;
}

// ---------------- probsparse: top-31 (tie -> lower index)
__global__ __launch_bounds__(256) void pp_topk(const float* __restrict__ Mbuf,
                                               int* __restrict__ sel) {
  __shared__ float vals[512];
  __shared__ int flag[512];
  __shared__ float wvs[4];
  __shared__ int wis[4];
  int bh = blockIdx.x;
  int tid = threadIdx.x, lane = tid & 63, g = tid >> 6;
  vals[tid] = Mbuf[bh * 512 + tid];
  vals[tid + 256] = Mbuf[bh * 512 + tid + 256];
  flag[tid] = 0; flag[tid + 256] = 0;
  __syncthreads();
  for (int it = 0; it < NTOP; ++it) {
    float v0 = vals[tid]; int i0 = tid;
    float v1 = vals[tid + 256];
    if (v1 > v0) { v0 = v1; i0 = tid + 256; }
#pragma unroll
    for (int mm = 32; mm > 0; mm >>= 1) {
      float ov = __shfl_xor(v0, mm);
      int oi = __shfl_xor(i0, mm);
      if (ov > v0 || (ov == v0 && oi < i0)) { v0 = ov; i0 = oi; }
    }
    if (lane == 0) { wvs[g] = v0; wis[g] = i0; }
    __syncthreads();
    if (tid == 0) {
      float bv = wvs[0]; int bi = wis[0];
#pragma unroll
      for (int w = 1; w < 4; ++w)
        if (wvs[w] > bv || (wvs[w] == bv && wis[w] < bi)) { bv = wvs[w]; bi = wis[w]; }
      vals[bi] = -INFINITY;
      flag[bi] = 1;
    }
    __syncthreads();
  }
  sel[bh * 512 + tid] = flag[tid];
  sel[bh * 512 + tid + 256] = flag[tid + 256];
}

// ---------------- final combine
__global__ __launch_bounds__(256) void combine(
    const float* __restrict__ dec, const float* __restrict__ proj,
    const float* __restrict__ rmsw, const float* __restrict__ alphas,
    float* __restrict__ out) {
  __shared__ float red[4];
  int row = blockIdx.x;
  int tid = threadIdx.x, lane = tid & 63, g = tid >> 6;
  int base = row * DMODEL + tid * 4;
  float4 dv = *(const float4*)(dec + base);
  float4 wv = *(const float4*)(rmsw + tid * 4);
  float a[6];
  float amax = -INFINITY;
#pragma unroll
  for (int i = 0; i < 6; ++i) { a[i] = alphas[i]; amax = fmaxf(amax, a[i]); }
  float asum = 0.f;
#pragma unroll
  for (int i = 0; i < 6; ++i) { a[i] = __expf(a[i] - amax); asum += a[i]; }
#pragma unroll
  for (int i = 0; i < 6; ++i) a[i] /= asum;
  float4 acc = make_float4(a[0] * dv.x, a[0] * dv.y, a[0] * dv.z, a[0] * dv.w);
  for (int br = 0; br < 5; ++br) {
    float4 pv = *(const float4*)(proj + br * 1048576 + base);
    float4 xx = make_float4(dv.x + pv.x, dv.y + pv.y, dv.z + pv.z, dv.w + pv.w);
    float ssq = xx.x * xx.x + xx.y * xx.y + xx.z * xx.z + xx.w * xx.w;
    float wsum = wave_sum(ssq);
    if (lane == 0) red[g] = wsum;
    __syncthreads();
    float tot = red[0] + red[1] + red[2] + red[3];
    float rr = rsqrtf(tot / 1024.f + 1e-6f);
    float wb = a[br + 1];
    acc.x += wb * xx.x * rr * wv.x;
    acc.y += wb * xx.y * rr * wv.y;
    acc.z += wb * xx.z * rr * wv.z;
    acc.w += wb * xx.w * rr * wv.w;
    __syncthreads();
  }
  *(float4*)(out + base) = acc;
}

extern "C" void kernel_launch(void* const* d_in, const int* in_sizes, int n_in,
                              void* d_out, int out_size, void* d_ws, size_t ws_size,
                              hipStream_t stream) {
  const float* dec = (const float*)d_in[0];
  const float* enc = (const float*)d_in[1];
  const float* Wq = (const float*)d_in[2];
  const float* Wk = (const float*)d_in[3];
  const float* Wv = (const float*)d_in[4];
  const float* Wo = (const float*)d_in[5];
  const float* rmsw = (const float*)d_in[6];
  const float* alphas = (const float*)d_in[7];
  const int* sidx = (const int*)d_in[8];

  const size_t M = 1048576;
  float* ws = (float*)d_ws;
  float* Q    = ws;                                  // [0,1M)
  unsigned short* Kb16 = (unsigned short*)(ws + M);  // [1M,3M)
  float* KsAcc = ws + 3 * M;                         // [3M,+38912)
  float* V    = ws + 5 * M;                          // [5M,9M)
  float* Vtb_f= ws + 9 * M;                          // [9M,11M)
  float* braw = ws + 11 * M;                         // [11M,16M)
  unsigned short* Wqh = (unsigned short*)(ws + 9 * M);
  unsigned short* Wql = (unsigned short*)(ws + 9 * M + M / 2);
  unsigned short* Wkh = (unsigned short*)(ws + 10 * M);
  unsigned short* Wvh = (unsigned short*)(ws + 10 * M + M / 2);
  unsigned short* eh  = (unsigned short*)(ws + 11 * M);
  unsigned short* dh  = (unsigned short*)(ws + 15 * M);
  unsigned short* dl  = (unsigned short*)(ws + 15 * M + M / 2);
  unsigned short* Vtb = (unsigned short*)Vtb_f;
  float* kvpL = ws + 11 * M;
  float* kvpC = ws + 13 * M;
  float* kspL = ws + 15 * M;
  float* kspC = ws + 15 * M + 32768;
  float* vsp  = ws + 15 * M + 65536;
  float* Ps1   = ws + 5 * M;
  float* Pl1   = ws + 6 * M;
  float* stats = ws + 7 * M;
  float* tail = ws + 16 * M;
  float* kvL  = tail;
  float* kvC  = tail + 131072;
  float* ksL  = tail + 262144;
  float* ksC  = tail + 264192;
  float* vmean= tail + 266240;
  float* Mbuf = tail + 317440;
  int*   sel  = (int*)(tail + 333824);
  unsigned short* Woh = (unsigned short*)ws;
  unsigned short* braw16 = (unsigned short*)(ws + M);
  float* proj = ws + 3 * M + M / 2;

  hipLaunchKernelGGL(cvt_in, dim3(5120), dim3(256), 0, stream, dec, enc, dh, dl, eh);
  hipLaunchKernelGGL(cvt_w3, dim3(16, 16, 3), dim3(256), 0, stream,
                     Wq, Wk, Wv, Wqh, Wql, Wkh, Wvh);
  hipLaunchKernelGGL(k_samp, dim3(38, 8), dim3(128), 0, stream, enc, Wk, sidx, KsAcc);
  hipLaunchKernelGGL(gemm_qkv, dim3(72, 8), dim3(256), 40960, stream,
                     dh, dl, Wqh, Wql, Q, eh, Wkh, Kb16, Wvh, V);
  hipLaunchKernelGGL(pp_scores, dim3(128), dim3(128), 0, stream, Q, KsAcc, Mbuf);
  hipLaunchKernelGGL(pp_topk, dim3(32), dim3(256), 0, stream, Mbuf, sel);
  hipLaunchKernelGGL(cvt_vt, dim3(1024), dim3(256), 0, stream, V, Vtb);
  hipLaunchKernelGGL(lin_cos_stats, dim3(512), dim3(256), 0, stream, Kb16, V,
                     kvpL, kvpC, kspL, kspC, vsp);
  hipLaunchKernelGGL(reduce_all, dim3(1048), dim3(256), 0, stream,
                     kvpL, kvpC, kspL, kspC, vsp, kvL, kvC, ksL, ksC, vmean);
  hipLaunchKernelGGL(attn_mfma, dim3(512), dim3(256), 0, stream, Q, Kb16, Vtb,
                     braw, Ps1, braw + 4 * M, Pl1, stats);
  hipLaunchKernelGGL(combine_fill, dim3(1024), dim3(256), 0, stream,
                     braw, Ps1, Pl1, stats, vmean, sel);
  hipLaunchKernelGGL(lin_cos_apply, dim3(4096), dim3(256), 0, stream, Q, kvL, kvC, ksL, ksC,
                     braw + M, braw + 3 * M);
  hipLaunchKernelGGL(cvt_w, dim3(16, 16), dim3(256), 0, stream, Wo, Woh);
  hipLaunchKernelGGL(cvt_braw, dim3(5120), dim3(256), 0, stream, braw, braw16);
  hipLaunchKernelGGL(gemm_one, dim3(40, 8), dim3(256), 40960, stream, braw16, Woh, proj);
  hipLaunchKernelGGL(combine, dim3(1024), dim3(256), 0, stream, dec, proj, rmsw, alphas,
                     (float*)d_out);
}

// Round 15
// 382.810 us; speedup vs baseline: 1.0227x; 1.0227x over previous
//
#include <hip/hip_runtime.h>
#include <math.h>

#define LDEC 512
#define LENC 2048
#define DMODEL 1024
#define NH 16
#define HD 64
#define SCALE 0.125f
#define NTOP 31
#define NSAMP 38

typedef __attribute__((ext_vector_type(8))) short bf16x8;
typedef __attribute__((ext_vector_type(4))) float f32x4;

__device__ inline float wave_sum(float v) {
#pragma unroll
  for (int m = 32; m > 0; m >>= 1) v += __shfl_xor(v, m);
  return v;
}

__device__ inline unsigned short f2bf(float x) {
  unsigned u = __float_as_uint(x);
  u += 0x7fff + ((u >> 16) & 1);  // RNE
  return (unsigned short)(u >> 16);
}
__device__ inline float bf2f(unsigned short h) {
  return __uint_as_float(((unsigned)h) << 16);
}

// ---------------- fp32 -> bf16 hi/lo split for dec (hi+lo) and enc (hi only)
__global__ __launch_bounds__(256) void cvt_in(const float* __restrict__ dec,
                                              const float* __restrict__ enc,
                                              unsigned short* __restrict__ dh,
                                              unsigned short* __restrict__ dl,
                                              unsigned short* __restrict__ eh) {
  int i = blockIdx.x * 256 + threadIdx.x;
  if (i < 262144) {
    float4 v = ((const float4*)dec)[i];
    ushort4 h = make_ushort4(f2bf(v.x), f2bf(v.y), f2bf(v.z), f2bf(v.w));
    ushort4 l = make_ushort4(f2bf(v.x - bf2f(h.x)), f2bf(v.y - bf2f(h.y)),
                             f2bf(v.z - bf2f(h.z)), f2bf(v.w - bf2f(h.w)));
    *(ushort4*)(dh + i * 4) = h;
    *(ushort4*)(dl + i * 4) = l;
  } else {
    int j = i - 262144;
    float4 v = ((const float4*)enc)[j];
    *(ushort4*)(eh + j * 4) =
        make_ushort4(f2bf(v.x), f2bf(v.y), f2bf(v.z), f2bf(v.w));
  }
}

// ---------------- W[k][n] fp32 -> Wt[n][k] bf16; z selects Wq(hi+lo)/Wk/Wv
__global__ __launch_bounds__(256) void cvt_w3(
    const float* __restrict__ Wq, const float* __restrict__ Wk,
    const float* __restrict__ Wv, unsigned short* __restrict__ Wqh,
    unsigned short* __restrict__ Wql, unsigned short* __restrict__ Wkh,
    unsigned short* __restrict__ Wvh) {
  __shared__ float t[64][68];
  int which = blockIdx.z;
  const float* W = which == 0 ? Wq : (which == 1 ? Wk : Wv);
  unsigned short* Th = which == 0 ? Wqh : (which == 1 ? Wkh : Wvh);
  unsigned short* Tl = which == 0 ? Wql : nullptr;
  int k0 = blockIdx.x * 64, n0 = blockIdx.y * 64;
  int tid = threadIdx.x;
#pragma unroll
  for (int i = 0; i < 4; ++i) {
    int c = tid + 256 * i;
    int r = c >> 4, c4 = (c & 15) * 4;
    float4 v = *(const float4*)(W + (size_t)(k0 + r) * DMODEL + n0 + c4);
    t[c4 + 0][r] = v.x; t[c4 + 1][r] = v.y; t[c4 + 2][r] = v.z; t[c4 + 3][r] = v.w;
  }
  __syncthreads();
#pragma unroll
  for (int i = 0; i < 4; ++i) {
    int c = tid + 256 * i;
    int n = c >> 4, k4 = (c & 15) * 4;
    float4 v = *(const float4*)&t[n][k4];
    ushort4 h = make_ushort4(f2bf(v.x), f2bf(v.y), f2bf(v.z), f2bf(v.w));
    *(ushort4*)(Th + (size_t)(n0 + n) * DMODEL + k0 + k4) = h;
    if (Tl) {
      ushort4 l = make_ushort4(f2bf(v.x - bf2f(h.x)), f2bf(v.y - bf2f(h.y)),
                               f2bf(v.z - bf2f(h.z)), f2bf(v.w - bf2f(h.w)));
      *(ushort4*)(Tl + (size_t)(n0 + n) * DMODEL + k0 + k4) = l;
    }
  }
}

// ---------------- W[k][n] fp32 -> Wt[n][k] bf16 hi only (Wo, late phase)
__global__ __launch_bounds__(256) void cvt_w(const float* __restrict__ W,
                                             unsigned short* __restrict__ Th) {
  __shared__ float t[64][68];
  int k0 = blockIdx.x * 64, n0 = blockIdx.y * 64;
  int tid = threadIdx.x;
#pragma unroll
  for (int i = 0; i < 4; ++i) {
    int c = tid + 256 * i;
    int r = c >> 4, c4 = (c & 15) * 4;
    float4 v = *(const float4*)(W + (size_t)(k0 + r) * DMODEL + n0 + c4);
    t[c4 + 0][r] = v.x; t[c4 + 1][r] = v.y; t[c4 + 2][r] = v.z; t[c4 + 3][r] = v.w;
  }
  __syncthreads();
#pragma unroll
  for (int i = 0; i < 4; ++i) {
    int c = tid + 256 * i;
    int n = c >> 4, k4 = (c & 15) * 4;
    float4 v = *(const float4*)&t[n][k4];
    *(ushort4*)(Th + (size_t)(n0 + n) * DMODEL + k0 + k4) =
        make_ushort4(f2bf(v.x), f2bf(v.y), f2bf(v.z), f2bf(v.w));
  }
}

// ---------------- fp32 -> bf16 flat (braw only)
__global__ __launch_bounds__(256) void cvt_braw(const float* __restrict__ src,
                                                unsigned short* __restrict__ dst) {
  int i = blockIdx.x * 256 + threadIdx.x;
  float4 v = ((const float4*)src)[i];
  *(ushort4*)(dst + i * 4) = make_ushort4(f2bf(v.x), f2bf(v.y), f2bf(v.z), f2bf(v.w));
}

// ---------------- sampled K rows in pure fp32 (top-k accuracy anchor)
__global__ __launch_bounds__(128) void k_samp(const float* __restrict__ enc,
                                              const float* __restrict__ Wk,
                                              const int* __restrict__ sidx,
                                              float* __restrict__ KsAcc) {
  __shared__ float er[1024];
  int s = blockIdx.x;
  int c = blockIdx.y * 128 + threadIdx.x;
  int srow = sidx[s];
#pragma unroll
  for (int i = 0; i < 2; ++i) {
    int idx = (threadIdx.x + 128 * i) * 4;
    *(float4*)&er[idx] = *(const float4*)(enc + (size_t)srow * DMODEL + idx);
  }
  __syncthreads();
  float acc = 0.f;
  for (int k = 0; k < 1024; ++k)
    acc = fmaf(er[k], Wk[(size_t)k * DMODEL + c], acc);
  KsAcc[s * DMODEL + c] = acc;
}

// ======= shared epilogue: 64x64 wave tile via LDS transpose (stride 72) ====
template <int BF16OUT>
__device__ __forceinline__ void gemm_epi64(
    unsigned short* sm, f32x4 (&acc)[4][4], float* __restrict__ C,
    unsigned short* __restrict__ Cb, int row0, int col0, int wave, int lane) {
  const int l16 = lane & 15, quad = lane >> 4;
  const int wr = wave >> 1, wc = wave & 1;
  float* eL = (float*)sm + wave * 1152;  // 16 rows x stride 72
  const int rr = lane >> 2, cc = (lane & 3) * 16;
#pragma unroll
  for (int x = 0; x < 4; ++x) {
#pragma unroll
    for (int y = 0; y < 4; ++y)
#pragma unroll
      for (int q = 0; q < 4; ++q)
        eL[(quad * 4 + q) * 72 + y * 16 + l16] = acc[x][y][q];
    size_t ro = (size_t)(row0 + wr * 64 + x * 16 + rr) * DMODEL + col0 + wc * 64 + cc;
    float4 v0 = *(const float4*)&eL[rr * 72 + cc];
    float4 v1 = *(const float4*)&eL[rr * 72 + cc + 4];
    float4 v2 = *(const float4*)&eL[rr * 72 + cc + 8];
    float4 v3 = *(const float4*)&eL[rr * 72 + cc + 12];
    if (BF16OUT) {
      uint4 o0, o1;
      o0.x = (unsigned)f2bf(v0.x) | ((unsigned)f2bf(v0.y) << 16);
      o0.y = (unsigned)f2bf(v0.z) | ((unsigned)f2bf(v0.w) << 16);
      o0.z = (unsigned)f2bf(v1.x) | ((unsigned)f2bf(v1.y) << 16);
      o0.w = (unsigned)f2bf(v1.z) | ((unsigned)f2bf(v1.w) << 16);
      o1.x = (unsigned)f2bf(v2.x) | ((unsigned)f2bf(v2.y) << 16);
      o1.y = (unsigned)f2bf(v2.z) | ((unsigned)f2bf(v2.w) << 16);
      o1.z = (unsigned)f2bf(v3.x) | ((unsigned)f2bf(v3.y) << 16);
      o1.w = (unsigned)f2bf(v3.z) | ((unsigned)f2bf(v3.w) << 16);
      *(uint4*)(Cb + ro) = o0;
      *(uint4*)(Cb + ro + 8) = o1;
    } else {
      *(float4*)(C + ro) = v0;
      *(float4*)(C + ro + 4) = v1;
      *(float4*)(C + ro + 8) = v2;
      *(float4*)(C + ro + 12) = v3;
    }
  }
}

// ======= 1-pass bf16 GEMM, 256 thr, 4 waves 2x2, wave-tile 64x64, dbuf LDS ==
template <int BF16OUT>
__device__ __forceinline__ void gemm256_db(
    const unsigned short* __restrict__ Ah, const unsigned short* __restrict__ Bh,
    float* __restrict__ C, unsigned short* __restrict__ Cb, int row0, int col0) {
  extern __shared__ unsigned short sm[];
  const int BUFS = 10240;
  const int tid = threadIdx.x, lane = tid & 63, wave = tid >> 6;
  const int l16 = lane & 15, quad = lane >> 4;
  const int wr = wave >> 1, wc = wave & 1;

  const int r = tid >> 2, kc = tid & 3;  // 2 chunks: rows r and r+64
  const unsigned short* gA0 = Ah + (size_t)(row0 + r) * DMODEL + kc * 8;
  const unsigned short* gA1 = Ah + (size_t)(row0 + r + 64) * DMODEL + kc * 8;
  const unsigned short* gB0 = Bh + (size_t)(col0 + r) * DMODEL + kc * 8;
  const unsigned short* gB1 = Bh + (size_t)(col0 + r + 64) * DMODEL + kc * 8;
  const int lo0 = r * 40 + kc * 8, lo1 = (r + 64) * 40 + kc * 8;

  f32x4 acc[4][4];
#pragma unroll
  for (int x = 0; x < 4; ++x)
#pragma unroll
    for (int y = 0; y < 4; ++y) acc[x][y] = (f32x4){0.f, 0.f, 0.f, 0.f};

  uint4 pa0 = *(const uint4*)gA0, pa1 = *(const uint4*)gA1;
  uint4 pb0 = *(const uint4*)gB0, pb1 = *(const uint4*)gB1;
  *(uint4*)&sm[lo0] = pa0; *(uint4*)&sm[lo1] = pa1;
  *(uint4*)&sm[5120 + lo0] = pb0; *(uint4*)&sm[5120 + lo1] = pb1;
  pa0 = *(const uint4*)(gA0 + 32); pa1 = *(const uint4*)(gA1 + 32);
  pb0 = *(const uint4*)(gB0 + 32); pb1 = *(const uint4*)(gB1 + 32);
  __syncthreads();

  for (int it = 0; it < 32; ++it) {
    const unsigned short* cur = sm + (it & 1) * BUFS;
    bf16x8 a[4], b[4];
#pragma unroll
    for (int x = 0; x < 4; ++x)
      a[x] = *(const bf16x8*)&cur[(wr * 64 + x * 16 + l16) * 40 + quad * 8];
#pragma unroll
    for (int y = 0; y < 4; ++y)
      b[y] = *(const bf16x8*)&cur[5120 + (wc * 64 + y * 16 + l16) * 40 + quad * 8];
#pragma unroll
    for (int x = 0; x < 4; ++x)
#pragma unroll
      for (int y = 0; y < 4; ++y)
        acc[x][y] = __builtin_amdgcn_mfma_f32_16x16x32_bf16(a[x], b[y], acc[x][y], 0, 0, 0);
    if (it < 31) {
      unsigned short* nxt = sm + ((it + 1) & 1) * BUFS;
      *(uint4*)&nxt[lo0] = pa0; *(uint4*)&nxt[lo1] = pa1;
      *(uint4*)&nxt[5120 + lo0] = pb0; *(uint4*)&nxt[5120 + lo1] = pb1;
      if (it < 30) {
        int ko = (it + 2) * 32;
        pa0 = *(const uint4*)(gA0 + ko); pa1 = *(const uint4*)(gA1 + ko);
        pb0 = *(const uint4*)(gB0 + ko); pb1 = *(const uint4*)(gB1 + ko);
      }
    }
    __syncthreads();
  }
  gemm_epi64<BF16OUT>(sm, acc, C, Cb, row0, col0, wave, lane);
}

// ======= 3-pass hi/lo GEMM, 256 thr, wave-tile 64x64, single-buffer LDS =====
__device__ __forceinline__ void gemm256_3p(
    const unsigned short* __restrict__ Ah, const unsigned short* __restrict__ Al,
    const unsigned short* __restrict__ Bh, const unsigned short* __restrict__ Bl,
    float* __restrict__ C, int row0, int col0) {
  extern __shared__ unsigned short sm[];
  const int tid = threadIdx.x, lane = tid & 63, wave = tid >> 6;
  const int l16 = lane & 15, quad = lane >> 4;
  const int wr = wave >> 1, wc = wave & 1;

  const int r = tid >> 2, kc = tid & 3;
  const unsigned short* gAh0 = Ah + (size_t)(row0 + r) * DMODEL + kc * 8;
  const unsigned short* gAh1 = Ah + (size_t)(row0 + r + 64) * DMODEL + kc * 8;
  const unsigned short* gBh0 = Bh + (size_t)(col0 + r) * DMODEL + kc * 8;
  const unsigned short* gBh1 = Bh + (size_t)(col0 + r + 64) * DMODEL + kc * 8;
  const unsigned short* gAl0 = Al + (size_t)(row0 + r) * DMODEL + kc * 8;
  const unsigned short* gAl1 = Al + (size_t)(row0 + r + 64) * DMODEL + kc * 8;
  const unsigned short* gBl0 = Bl + (size_t)(col0 + r) * DMODEL + kc * 8;
  const unsigned short* gBl1 = Bl + (size_t)(col0 + r + 64) * DMODEL + kc * 8;
  const int lo0 = r * 40 + kc * 8, lo1 = (r + 64) * 40 + kc * 8;

  f32x4 acc[4][4];
#pragma unroll
  for (int x = 0; x < 4; ++x)
#pragma unroll
    for (int y = 0; y < 4; ++y) acc[x][y] = (f32x4){0.f, 0.f, 0.f, 0.f};

  uint4 ph0 = *(const uint4*)gAh0, ph1 = *(const uint4*)gAh1;
  uint4 ph2 = *(const uint4*)gBh0, ph3 = *(const uint4*)gBh1;
  uint4 pl0 = *(const uint4*)gAl0, pl1 = *(const uint4*)gAl1;
  uint4 pl2 = *(const uint4*)gBl0, pl3 = *(const uint4*)gBl1;
  *(uint4*)&sm[lo0] = ph0; *(uint4*)&sm[lo1] = ph1;
  *(uint4*)&sm[5120 + lo0] = ph2; *(uint4*)&sm[5120 + lo1] = ph3;
  *(uint4*)&sm[10240 + lo0] = pl0; *(uint4*)&sm[10240 + lo1] = pl1;
  *(uint4*)&sm[15360 + lo0] = pl2; *(uint4*)&sm[15360 + lo1] = pl3;
  __syncthreads();

  for (int it = 0; it < 32; ++it) {
    if (it < 31) {
      int ko = (it + 1) * 32;
      ph0 = *(const uint4*)(gAh0 + ko); ph1 = *(const uint4*)(gAh1 + ko);
      ph2 = *(const uint4*)(gBh0 + ko); ph3 = *(const uint4*)(gBh1 + ko);
      pl0 = *(const uint4*)(gAl0 + ko); pl1 = *(const uint4*)(gAl1 + ko);
      pl2 = *(const uint4*)(gBl0 + ko); pl3 = *(const uint4*)(gBl1 + ko);
    }
    bf16x8 ah[4], bh[4], al[4], bl[4];
#pragma unroll
    for (int x = 0; x < 4; ++x) {
      ah[x] = *(const bf16x8*)&sm[(wr * 64 + x * 16 + l16) * 40 + quad * 8];
      al[x] = *(const bf16x8*)&sm[10240 + (wr * 64 + x * 16 + l16) * 40 + quad * 8];
    }
#pragma unroll
    for (int y = 0; y < 4; ++y) {
      bh[y] = *(const bf16x8*)&sm[5120 + (wc * 64 + y * 16 + l16) * 40 + quad * 8];
      bl[y] = *(const bf16x8*)&sm[15360 + (wc * 64 + y * 16 + l16) * 40 + quad * 8];
    }
#pragma unroll
    for (int x = 0; x < 4; ++x)
#pragma unroll
      for (int y = 0; y < 4; ++y) {
        acc[x][y] = __builtin_amdgcn_mfma_f32_16x16x32_bf16(ah[x], bh[y], acc[x][y], 0, 0, 0);
        acc[x][y] = __builtin_amdgcn_mfma_f32_16x16x32_bf16(ah[x], bl[y], acc[x][y], 0, 0, 0);
        acc[x][y] = __builtin_amdgcn_mfma_f32_16x16x32_bf16(al[x], bh[y], acc[x][y], 0, 0, 0);
      }
    __syncthreads();
    if (it < 31) {
      *(uint4*)&sm[lo0] = ph0; *(uint4*)&sm[lo1] = ph1;
      *(uint4*)&sm[5120 + lo0] = ph2; *(uint4*)&sm[5120 + lo1] = ph3;
      *(uint4*)&sm[10240 + lo0] = pl0; *(uint4*)&sm[10240 + lo1] = pl1;
      *(uint4*)&sm[15360 + lo0] = pl2; *(uint4*)&sm[15360 + lo1] = pl3;
    }
    __syncthreads();
  }
  gemm_epi64<0>(sm, acc, C, nullptr, row0, col0, wave, lane);
}

// merged Q(3-pass) + K(1-pass,bf16-out) + V(1-pass) — uniform 40960 B LDS.
// launch_bounds(256, 2): VGPR cap 256 — the 64-float accumulator MUST stay in
// registers (round 14: (256,4) clamped VGPRs to 64 and spilled the acc).
__global__ __launch_bounds__(256, 2) void gemm_qkv(
    const unsigned short* __restrict__ dh, const unsigned short* __restrict__ dl,
    const unsigned short* __restrict__ Wqh, const unsigned short* __restrict__ Wql,
    float* __restrict__ Q,
    const unsigned short* __restrict__ eh, const unsigned short* __restrict__ Wkh,
    unsigned short* __restrict__ Kb16,
    const unsigned short* __restrict__ Wvh, float* __restrict__ V) {
  int bx = blockIdx.x;
  if (bx < 8)
    gemm256_3p(dh, dl, Wqh, Wql, Q, bx * 128, blockIdx.y * 128);
  else if (bx < 40)
    gemm256_db<1>(eh, Wkh, nullptr, Kb16, (bx - 8) * 128, blockIdx.y * 128);
  else
    gemm256_db<0>(eh, Wvh, V, nullptr, (bx - 40) * 128, blockIdx.y * 128);
}

__global__ __launch_bounds__(256, 2) void gemm_one(
    const unsigned short* __restrict__ Ah, const unsigned short* __restrict__ Bh,
    float* __restrict__ C) {
  gemm256_db<0>(Ah, Bh, C, nullptr, blockIdx.x * 128, blockIdx.y * 128);
}

// V fp32 -> bf16 transposed per head: Vt[(b*16+h)*64 + d][s]
__global__ __launch_bounds__(256) void cvt_vt(const float* __restrict__ V,
                                              unsigned short* __restrict__ Vt) {
  __shared__ unsigned short tile[64][72];
  int bh = blockIdx.x >> 5;
  int s0 = (blockIdx.x & 31) * 64;
  int b = bh >> 4, h = bh & 15;
  int tid = threadIdx.x;
#pragma unroll
  for (int i = 0; i < 4; ++i) {
    int c = tid + 256 * i;
    int s = c >> 4, d4 = (c & 15) * 4;
    float4 v = *(const float4*)(V + (size_t)(b * LENC + s0 + s) * DMODEL + h * HD + d4);
    tile[d4 + 0][s] = f2bf(v.x);
    tile[d4 + 1][s] = f2bf(v.y);
    tile[d4 + 2][s] = f2bf(v.z);
    tile[d4 + 3][s] = f2bf(v.w);
  }
  __syncthreads();
#pragma unroll
  for (int i = 0; i < 2; ++i) {
    int c = tid + 256 * i;
    int d = c >> 3, soff = (c & 7) * 8;
    uint4 o = *(const uint4*)&tile[d][soff];
    *(uint4*)(Vt + (size_t)(bh * 64 + d) * LENC + s0 + soff) = o;
  }
}

// ---------------- MFMA flash attention, split-K 2-way + XCD swizzle, bf16 K
#define TSTR 72

__global__ __launch_bounds__(256) void attn_mfma(
    const float* __restrict__ Qf, const unsigned short* __restrict__ Kb,
    const unsigned short* __restrict__ Vt,
    float* __restrict__ Ps0, float* __restrict__ Ps1,
    float* __restrict__ Pl0, float* __restrict__ Pl1,
    float* __restrict__ st) {
  __shared__ unsigned short Ks[2][64 * TSTR];
  __shared__ unsigned short Vs[2][64 * TSTR];
  __shared__ unsigned short Ps[4][16 * TSTR];
  const int tid = threadIdx.x;
  const int wave = tid >> 6, lane = tid & 63;
  const int l16 = lane & 15, quad = lane >> 4;
  const int bx = blockIdx.x;
  const int xcd = bx & 7, sub = bx >> 3;
  const int qt = sub & 7, half = (sub >> 3) & 1, grp = sub >> 4;
  const int bh = xcd + 8 * grp;
  const int b = bh >> 4, h = bh & 15;
  const int tbase = qt * 64 + wave * 16;
  const int sbase = half * 1024;

  const float* qrow = Qf + (size_t)(b * LDEC + tbase + l16) * DMODEL + h * HD + quad * 8;
  bf16x8 qa0, qa1;
  {
    float4 a0 = *(const float4*)qrow, a1 = *(const float4*)(qrow + 4);
    float4 a2 = *(const float4*)(qrow + 32), a3 = *(const float4*)(qrow + 36);
    qa0[0] = f2bf(a0.x * SCALE); qa0[1] = f2bf(a0.y * SCALE);
    qa0[2] = f2bf(a0.z * SCALE); qa0[3] = f2bf(a0.w * SCALE);
    qa0[4] = f2bf(a1.x * SCALE); qa0[5] = f2bf(a1.y * SCALE);
    qa0[6] = f2bf(a1.z * SCALE); qa0[7] = f2bf(a1.w * SCALE);
    qa1[0] = f2bf(a2.x * SCALE); qa1[1] = f2bf(a2.y * SCALE);
    qa1[2] = f2bf(a2.z * SCALE); qa1[3] = f2bf(a2.w * SCALE);
    qa1[4] = f2bf(a3.x * SCALE); qa1[5] = f2bf(a3.y * SCALE);
    qa1[6] = f2bf(a3.z * SCALE); qa1[7] = f2bf(a3.w * SCALE);
  }

  int loC[4], hiC[4];
#pragma unroll
  for (int r = 0; r < 4; ++r) {
    int t = tbase + quad * 4 + r;
    int c = min(4 * t, LENC - 1);
    loC[r] = max(c - 256, 0); hiC[r] = min(c + 256, LENC - 1);
  }
  int tA = tbase + l16;
  int cA = min(4 * tA, LENC - 1);
  int loA = max(cA - 256, 0), hiA = min(cA + 256, LENC - 1);
  const int loW = max(4 * tbase - 256, 0);
  const int hiW = min(4 * (tbase + 15) + 256, LENC - 1);

  f32x4 Os[4], Ol[4];
#pragma unroll
  for (int n = 0; n < 4; ++n) {
    Os[n] = (f32x4){0.f, 0.f, 0.f, 0.f};
    Ol[n] = (f32x4){0.f, 0.f, 0.f, 0.f};
  }
  float lS[4], lL[4];
#pragma unroll
  for (int r = 0; r < 4; ++r) { lS[r] = 0.f; lL[r] = 0.f; }

  const int c0 = tid, c1 = tid + 256;
  const unsigned short* kg0 = Kb + (size_t)(b * LENC + sbase + (c0 >> 3)) * DMODEL + h * HD + (c0 & 7) * 8;
  const unsigned short* kg1 = Kb + (size_t)(b * LENC + sbase + (c1 >> 3)) * DMODEL + h * HD + (c1 & 7) * 8;
  const unsigned short* vg0 = Vt + (size_t)(bh * 64 + (c0 >> 3)) * LENC + sbase + (c0 & 7) * 8;
  const unsigned short* vg1 = Vt + (size_t)(bh * 64 + (c1 >> 3)) * LENC + sbase + (c1 & 7) * 8;
  const int of0 = (c0 >> 3) * TSTR + (c0 & 7) * 8;
  const int of1 = (c1 >> 3) * TSTR + (c1 & 7) * 8;

  uint4 pk0, pk1, pv0, pv1;
  pk0 = *(const uint4*)kg0; pk1 = *(const uint4*)kg1;
  pv0 = *(const uint4*)vg0; pv1 = *(const uint4*)vg1;
  *(uint4*)&Ks[0][of0] = pk0; *(uint4*)&Ks[0][of1] = pk1;
  *(uint4*)&Vs[0][of0] = pv0; *(uint4*)&Vs[0][of1] = pv1;
  __syncthreads();

  for (int it = 0; it < 16; ++it) {
    const int cur = it & 1;
    const int s0 = sbase + it * 64;
    const bool anyL = (s0 <= hiW) && (s0 + 63 >= loW);
    if (it < 15) {
      pk0 = *(const uint4*)(kg0 + (size_t)(it + 1) * 64 * DMODEL);
      pk1 = *(const uint4*)(kg1 + (size_t)(it + 1) * 64 * DMODEL);
      pv0 = *(const uint4*)(vg0 + (it + 1) * 64);
      pv1 = *(const uint4*)(vg1 + (it + 1) * 64);
    }
    const unsigned short* K_ = Ks[cur];
    const unsigned short* V_ = Vs[cur];

    f32x4 S[4];
#pragma unroll
    for (int n = 0; n < 4; ++n) {
      bf16x8 bk0 = *(const bf16x8*)&K_[(n * 16 + l16) * TSTR + quad * 8];
      bf16x8 bk1 = *(const bf16x8*)&K_[(n * 16 + l16) * TSTR + 32 + quad * 8];
      f32x4 z = (f32x4){0.f, 0.f, 0.f, 0.f};
      z = __builtin_amdgcn_mfma_f32_16x16x32_bf16(qa0, bk0, z, 0, 0, 0);
      S[n] = __builtin_amdgcn_mfma_f32_16x16x32_bf16(qa1, bk1, z, 0, 0, 0);
    }

    float e[4][4];
#pragma unroll
    for (int r = 0; r < 4; ++r) {
#pragma unroll
      for (int n = 0; n < 4; ++n) e[n][r] = __expf(S[n][r]);
      float se = e[0][r] + e[1][r] + e[2][r] + e[3][r];
      float sl = 0.f;
      if (anyL) {
#pragma unroll
        for (int n = 0; n < 4; ++n) {
          int sc = s0 + n * 16 + l16;
          sl += (sc >= loC[r] && sc <= hiC[r]) ? e[n][r] : 0.f;
        }
      }
#pragma unroll
      for (int d = 1; d < 16; d <<= 1) { se += __shfl_xor(se, d); sl += __shfl_xor(sl, d); }
      lS[r] += se;
      lL[r] += sl;
    }

    unsigned short* Pw = Ps[wave];
#pragma unroll
    for (int n = 0; n < 4; ++n)
#pragma unroll
      for (int r = 0; r < 4; ++r)
        Pw[(quad * 4 + r) * TSTR + n * 16 + l16] = f2bf(e[n][r]);
    bf16x8 aP0 = *(const bf16x8*)&Pw[l16 * TSTR + quad * 8];
    bf16x8 aP1 = *(const bf16x8*)&Pw[l16 * TSTR + 32 + quad * 8];
#pragma unroll
    for (int n = 0; n < 4; ++n) {
      bf16x8 bv0 = *(const bf16x8*)&V_[(n * 16 + l16) * TSTR + quad * 8];
      bf16x8 bv1 = *(const bf16x8*)&V_[(n * 16 + l16) * TSTR + 32 + quad * 8];
      Os[n] = __builtin_amdgcn_mfma_f32_16x16x32_bf16(aP0, bv0, Os[n], 0, 0, 0);
      Os[n] = __builtin_amdgcn_mfma_f32_16x16x32_bf16(aP1, bv1, Os[n], 0, 0, 0);
    }
    if (anyL) {
      bf16x8 aL0 = aP0, aL1 = aP1;
#pragma unroll
      for (int j = 0; j < 8; ++j) {
        int sc = s0 + quad * 8 + j;
        if (sc < loA || sc > hiA) aL0[j] = 0;
        if (sc + 32 < loA || sc + 32 > hiA) aL1[j] = 0;
      }
#pragma unroll
      for (int n = 0; n < 4; ++n) {
        bf16x8 bv0 = *(const bf16x8*)&V_[(n * 16 + l16) * TSTR + quad * 8];
        bf16x8 bv1 = *(const bf16x8*)&V_[(n * 16 + l16) * TSTR + 32 + quad * 8];
        Ol[n] = __builtin_amdgcn_mfma_f32_16x16x32_bf16(aL0, bv0, Ol[n], 0, 0, 0);
        Ol[n] = __builtin_amdgcn_mfma_f32_16x16x32_bf16(aL1, bv1, Ol[n], 0, 0, 0);
      }
    }
    __syncthreads();
    if (it < 15) {
      unsigned short* KL = Ks[1 - cur];
      unsigned short* VL = Vs[1 - cur];
      *(uint4*)&KL[of0] = pk0; *(uint4*)&KL[of1] = pk1;
      *(uint4*)&VL[of0] = pv0; *(uint4*)&VL[of1] = pv1;
    }
    __syncthreads();
  }

  float* osdp = half ? Ps1 : Ps0;
  float* oloc = half ? Pl1 : Pl0;
  float* sp = st + half * 32768;
#pragma unroll
  for (int r = 0; r < 4; ++r) {
    int t = tbase + quad * 4 + r;
#pragma unroll
    for (int n = 0; n < 4; ++n) {
      size_t o = (size_t)(b * LDEC + t) * DMODEL + h * HD + n * 16 + l16;
      osdp[o] = Os[n][r];
      oloc[o] = Ol[n][r];
    }
    if (l16 == 0) {
      int sr = bh * 512 + t;
      sp[sr] = lS[r];
      sp[16384 + sr] = lL[r];
    }
  }
}

// fused: split-K combine (plain sums, max-free) + probsparse fill
__global__ __launch_bounds__(256) void combine_fill(
    float* __restrict__ braw, const float* __restrict__ Ps1,
    const float* __restrict__ Pl1, const float* __restrict__ st,
    const float* __restrict__ vmean, const int* __restrict__ sel) {
  int i4 = blockIdx.x * 256 + threadIdx.x;
  int i = i4 * 4;
  int col = i & 1023, bt = i >> 10;
  int t = bt & 511, b = bt >> 9, h = col >> 6, d = col & 63;
  int bh = b * 16 + h;
  int sr = bh * 512 + t;
  float iS = 1.f / (st[sr] + st[32768 + sr]);
  float iL = 1.f / (st[16384 + sr] + st[49152 + sr]);
  float4 s0 = *(const float4*)(braw + i);
  float4 s1 = *(const float4*)(Ps1 + i);
  float4 l0 = *(const float4*)(braw + 4194304 + i);
  float4 l1 = *(const float4*)(Pl1 + i);
  float4 os = make_float4((s0.x + s1.x) * iS, (s0.y + s1.y) * iS,
                          (s0.z + s1.z) * iS, (s0.w + s1.w) * iS);
  float4 ol = make_float4((l0.x + l1.x) * iL, (l0.y + l1.y) * iL,
                          (l0.z + l1.z) * iL, (l0.w + l1.w) * iL);
  *(float4*)(braw + i) = os;
  *(float4*)(braw + 4194304 + i) = ol;
  float4 pp = sel[sr] ? os : *(const float4*)(vmean + bh * 64 + d);
  *(float4*)(braw + 2097152 + i) = pp;
}

// ---------------- linear + cosine branch stats (split-K, 16 parts; bf16 K)
__global__ __launch_bounds__(256) void lin_cos_stats(
    const unsigned short* __restrict__ Kb, const float* __restrict__ V,
    float* __restrict__ kvpL, float* __restrict__ kvpC,
    float* __restrict__ kspL, float* __restrict__ kspC, float* __restrict__ vsp) {
  __shared__ float kS[64][68];
  __shared__ float vSS[64][68];
  __shared__ float nrm[64];
  int bx = blockIdx.x;
  int bh = bx >> 4, part = bx & 15;
  int b = bh >> 4, h = bh & 15;
  int tid = threadIdx.x, lane = tid & 63, g = tid >> 6;
  const float* Vb = V + (b * LENC) * DMODEL + h * HD;
  float accL[16], accC[16];
#pragma unroll
  for (int i = 0; i < 16; ++i) { accL[i] = 0.f; accC[i] = 0.f; }
  float ksl = 0.f, ksc = 0.f, vs = 0.f;
  for (int tile = 0; tile < 2; ++tile) {
    int s0 = part * 128 + tile * 64;
#pragma unroll
    for (int i = 0; i < 2; ++i) {
      int slot = tid + 256 * i;
      int j = slot >> 3, d8 = (slot & 7) * 8;
      uint4 kv = *(const uint4*)(Kb + (size_t)(b * LENC + s0 + j) * DMODEL + h * HD + d8);
      const unsigned short* sp16 = (const unsigned short*)&kv;
#pragma unroll
      for (int q = 0; q < 8; ++q) kS[j][d8 + q] = bf2f(sp16[q]);
    }
#pragma unroll
    for (int i = 0; i < 4; ++i) {
      int slot = tid + 256 * i;
      int j = slot >> 4, d4 = slot & 15;
      *(float4*)&vSS[j][d4 * 4] = *(const float4*)(Vb + (s0 + j) * DMODEL + d4 * 4);
    }
    __syncthreads();
#pragma unroll
    for (int rr = 0; rr < 16; ++rr) {
      int row = g * 16 + rr;
      float x = kS[row][lane];
      float ssum = wave_sum(x * x);
      if (lane == 0) nrm[row] = sqrtf(ssum);
    }
    __syncthreads();
    for (int s = 0; s < 64; ++s) {
      float kval = kS[s][lane];
      float kfl = kval > 0.f ? kval + 1.f : __expf(kval);
      float kn = kval / fmaxf(nrm[s], 1e-12f);
      float kfc = fmaxf(kn, 0.f) + 1e-6f;
      const float4* vrow = (const float4*)&vSS[s][g * 16];
      float4 v0 = vrow[0], v1 = vrow[1], v2 = vrow[2], v3 = vrow[3];
      accL[0] = fmaf(kfl, v0.x, accL[0]);   accC[0] = fmaf(kfc, v0.x, accC[0]);
      accL[1] = fmaf(kfl, v0.y, accL[1]);   accC[1] = fmaf(kfc, v0.y, accC[1]);
      accL[2] = fmaf(kfl, v0.z, accL[2]);   accC[2] = fmaf(kfc, v0.z, accC[2]);
      accL[3] = fmaf(kfl, v0.w, accL[3]);   accC[3] = fmaf(kfc, v0.w, accC[3]);
      accL[4] = fmaf(kfl, v1.x, accL[4]);   accC[4] = fmaf(kfc, v1.x, accC[4]);
      accL[5] = fmaf(kfl, v1.y, accL[5]);   accC[5] = fmaf(kfc, v1.y, accC[5]);
      accL[6] = fmaf(kfl, v1.z, accL[6]);   accC[6] = fmaf(kfc, v1.z, accC[6]);
      accL[7] = fmaf(kfl, v1.w, accL[7]);   accC[7] = fmaf(kfc, v1.w, accC[7]);
      accL[8] = fmaf(kfl, v2.x, accL[8]);   accC[8] = fmaf(kfc, v2.x, accC[8]);
      accL[9] = fmaf(kfl, v2.y, accL[9]);   accC[9] = fmaf(kfc, v2.y, accC[9]);
      accL[10] = fmaf(kfl, v2.z, accL[10]); accC[10] = fmaf(kfc, v2.z, accC[10]);
      accL[11] = fmaf(kfl, v2.w, accL[11]); accC[11] = fmaf(kfc, v2.w, accC[11]);
      accL[12] = fmaf(kfl, v3.x, accL[12]); accC[12] = fmaf(kfc, v3.x, accC[12]);
      accL[13] = fmaf(kfl, v3.y, accL[13]); accC[13] = fmaf(kfc, v3.y, accC[13]);
      accL[14] = fmaf(kfl, v3.z, accL[14]); accC[14] = fmaf(kfc, v3.z, accC[14]);
      accL[15] = fmaf(kfl, v3.w, accL[15]); accC[15] = fmaf(kfc, v3.w, accC[15]);
      if (g == 0) { ksl += kfl; ksc += kfc; vs += vSS[s][lane]; }
    }
    __syncthreads();
  }
  int base = part * 131072 + bh * 4096 + lane * 64 + g * 16;
#pragma unroll
  for (int i4 = 0; i4 < 4; ++i4) {
    *(float4*)&kvpL[base + i4 * 4] = make_float4(accL[i4*4], accL[i4*4+1], accL[i4*4+2], accL[i4*4+3]);
    *(float4*)&kvpC[base + i4 * 4] = make_float4(accC[i4*4], accC[i4*4+1], accC[i4*4+2], accC[i4*4+3]);
  }
  if (g == 0) {
    kspL[part * 2048 + bh * 64 + lane] = ksl;
    kspC[part * 2048 + bh * 64 + lane] = ksc;
    vsp[part * 2048 + bh * 64 + lane] = vs;
  }
}

// fused reduction of all lin/cos partials
__global__ __launch_bounds__(256) void reduce_all(
    const float* __restrict__ kvpL, const float* __restrict__ kvpC,
    const float* __restrict__ kspL, const float* __restrict__ kspC,
    const float* __restrict__ vsp, float* __restrict__ kvL,
    float* __restrict__ kvC, float* __restrict__ ksL,
    float* __restrict__ ksC, float* __restrict__ vmean) {
  int i = blockIdx.x * 256 + threadIdx.x;
  if (i < 131072) {
    float s = 0.f;
#pragma unroll
    for (int p = 0; p < 16; ++p) s += kvpL[p * 131072 + i];
    kvL[i] = s;
  } else if (i < 262144) {
    int j = i - 131072;
    float s = 0.f;
#pragma unroll
    for (int p = 0; p < 16; ++p) s += kvpC[p * 131072 + j];
    kvC[j] = s;
  } else {
    int j = i - 262144;
    int which = j >> 11, jj = j & 2047;
    const float* src = which == 0 ? kspL : (which == 1 ? kspC : vsp);
    float s = 0.f;
#pragma unroll
    for (int p = 0; p < 16; ++p) s += src[p * 2048 + jj];
    if (which == 0) ksL[jj] = s;
    else if (which == 1) ksC[jj] = s;
    else vmean[jj] = s * (1.f / 2048.f);
  }
}

// ---------------- linear + cosine apply
__global__ __launch_bounds__(256) void lin_cos_apply(
    const float* __restrict__ Q, const float* __restrict__ kvL, const float* __restrict__ kvC,
    const float* __restrict__ ksL, const float* __restrict__ ksC,
    float* __restrict__ obL, float* __restrict__ obC) {
  __shared__ float sh[2][4][64];
  int tid = threadIdx.x, lane = tid & 63, g = tid >> 6;
  int row = blockIdx.x * 4 + g;
  int bh = row >> 9, t = row & 511;
  int b = bh >> 4, h = bh & 15;
  float qv = Q[(b * LDEC + t) * DMODEL + h * HD + lane];
  float x = qv * SCALE;
  float qfl = x > 0.f ? x + 1.f : __expf(x);
  float qnorm = sqrtf(wave_sum(qv * qv));
  float qn = qv / fmaxf(qnorm, 1e-12f);
  float qfc = fmaxf(qn, 0.f) + 1e-6f;
  sh[0][g][lane] = qfl;
  sh[1][g][lane] = qfc;
  float denL = fmaxf(wave_sum(qfl * ksL[bh * 64 + lane]), 1e-6f);
  float denC = fmaxf(wave_sum(qfc * ksC[bh * 64 + lane]), 1e-6f);
  const float* kvLb = kvL + bh * 4096;
  const float* kvCb = kvC + bh * 4096;
  float aL = 0.f, aC = 0.f;
#pragma unroll
  for (int d = 0; d < 64; ++d) {
    aL = fmaf(sh[0][g][d], kvLb[d * 64 + lane], aL);
    aC = fmaf(sh[1][g][d], kvCb[d * 64 + lane], aC);
  }
  int o = (b * LDEC + t) * DMODEL + h * HD + lane;
  obL[o] = aL / denL;
  obC[o] = aC / denC;
}

// ---------------- probsparse: sampled scores -> M (fp32 Q + fp32 KsAcc)
__global__ __launch_bounds__(128) void pp_scores(
    const float* __restrict__ Q, const float* __restrict__ KsAcc,
    float* __restrict__ Mout) {
  __shared__ float qL[128][65];
  __shared__ float ksL[NSAMP][65];
  int bx = blockIdx.x;
  int bh = bx >> 2, chunk = bx & 3;
  int b = bh >> 4, h = bh & 15;
  int t0 = chunk * 128;
  int tid = threadIdx.x;
  const float* Qb = Q + (b * LDEC) * DMODEL + h * HD;
#pragma unroll
  for (int i = 0; i < 16; ++i) {
    int slot = tid + 128 * i;
    int r = slot >> 4, c4 = slot & 15;
    float4 qx = *(const float4*)(Qb + (t0 + r) * DMODEL + c4 * 4);
    qL[r][c4 * 4 + 0] = qx.x; qL[r][c4 * 4 + 1] = qx.y;
    qL[r][c4 * 4 + 2] = qx.z; qL[r][c4 * 4 + 3] = qx.w;
  }
  for (int slot = tid; slot < NSAMP * 16; slot += 128) {
    int r = slot >> 4, c4 = slot & 15;
    float4 kx = *(const float4*)(KsAcc + r * DMODEL + h * HD + c4 * 4);
    ksL[r][c4 * 4 + 0] = kx.x; ksL[r][c4 * 4 + 1] = kx.y;
    ksL[r][c4 * 4 + 2] = kx.z; ksL[r][c4 * 4 + 3] = kx.w;
  }
  __syncthreads();
  float qr[64];
#pragma unroll
  for (int d = 0; d < 64; ++d) qr[d] = qL[tid][d];
  float mx = -INFINITY, sm = 0.f;
  for (int j = 0; j < NSAMP; ++j) {
    float s = 0.f;
#pragma unroll
    for (int d = 0; d < 64; ++d) s = fmaf(qr[d], ksL[j][d], s);
    s *= SCALE;
    mx = fmaxf(mx, s);
    sm += s;
  }
  Mout[bh * LDEC + t0 + tid] = mx - sm / (float)NSAMP;
}

// ---------------- probsparse: top-31 (tie -> lower index)
__global__ __launch_bounds__(256) void pp_topk(const float* __restrict__ Mbuf,
                                               int* __restrict__ sel) {
  __shared__ float vals[512];
  __shared__ int flag[512];
  __shared__ float wvs[4];
  __shared__ int wis[4];
  int bh = blockIdx.x;
  int tid = threadIdx.x, lane = tid & 63, g = tid >> 6;
  vals[tid] = Mbuf[bh * 512 + tid];
  vals[tid + 256] = Mbuf[bh * 512 + tid + 256];
  flag[tid] = 0; flag[tid + 256] = 0;
  __syncthreads();
  for (int it = 0; it < NTOP; ++it) {
    float v0 = vals[tid]; int i0 = tid;
    float v1 = vals[tid + 256];
    if (v1 > v0) { v0 = v1; i0 = tid + 256; }
#pragma unroll
    for (int mm = 32; mm > 0; mm >>= 1) {
      float ov = __shfl_xor(v0, mm);
      int oi = __shfl_xor(i0, mm);
      if (ov > v0 || (ov == v0 && oi < i0)) { v0 = ov; i0 = oi; }
    }
    if (lane == 0) { wvs[g] = v0; wis[g] = i0; }
    __syncthreads();
    if (tid == 0) {
      float bv = wvs[0]; int bi = wis[0];
#pragma unroll
      for (int w = 1; w < 4; ++w)
        if (wvs[w] > bv || (wvs[w] == bv && wis[w] < bi)) { bv = wvs[w]; bi = wis[w]; }
      vals[bi] = -INFINITY;
      flag[bi] = 1;
    }
    __syncthreads();
  }
  sel[bh * 512 + tid] = flag[tid];
  sel[bh * 512 + tid + 256] = flag[tid + 256];
}

// ---------------- final combine
__global__ __launch_bounds__(256) void combine(
    const float* __restrict__ dec, const float* __restrict__ proj,
    const float* __restrict__ rmsw, const float* __restrict__ alphas,
    float* __restrict__ out) {
  __shared__ float red[4];
  int row = blockIdx.x;
  int tid = threadIdx.x, lane = tid & 63, g = tid >> 6;
  int base = row * DMODEL + tid * 4;
  float4 dv = *(const float4*)(dec + base);
  float4 wv = *(const float4*)(rmsw + tid * 4);
  float a[6];
  float amax = -INFINITY;
#pragma unroll
  for (int i = 0; i < 6; ++i) { a[i] = alphas[i]; amax = fmaxf(amax, a[i]); }
  float asum = 0.f;
#pragma unroll
  for (int i = 0; i < 6; ++i) { a[i] = __expf(a[i] - amax); asum += a[i]; }
#pragma unroll
  for (int i = 0; i < 6; ++i) a[i] /= asum;
  float4 acc = make_float4(a[0] * dv.x, a[0] * dv.y, a[0] * dv.z, a[0] * dv.w);
  for (int br = 0; br < 5; ++br) {
    float4 pv = *(const float4*)(proj + br * 1048576 + base);
    float4 xx = make_float4(dv.x + pv.x, dv.y + pv.y, dv.z + pv.z, dv.w + pv.w);
    float ssq = xx.x * xx.x + xx.y * xx.y + xx.z * xx.z + xx.w * xx.w;
    float wsum = wave_sum(ssq);
    if (lane == 0) red[g] = wsum;
    __syncthreads();
    float tot = red[0] + red[1] + red[2] + red[3];
    float rr = rsqrtf(tot / 1024.f + 1e-6f);
    float wb = a[br + 1];
    acc.x += wb * xx.x * rr * wv.x;
    acc.y += wb * xx.y * rr * wv.y;
    acc.z += wb * xx.z * rr * wv.z;
    acc.w += wb * xx.w * rr * wv.w;
    __syncthreads();
  }
  *(float4*)(out + base) = acc;
}

extern "C" void kernel_launch(void* const* d_in, const int* in_sizes, int n_in,
                              void* d_out, int out_size, void* d_ws, size_t ws_size,
                              hipStream_t stream) {
  const float* dec = (const float*)d_in[0];
  const float* enc = (const float*)d_in[1];
  const float* Wq = (const float*)d_in[2];
  const float* Wk = (const float*)d_in[3];
  const float* Wv = (const float*)d_in[4];
  const float* Wo = (const float*)d_in[5];
  const float* rmsw = (const float*)d_in[6];
  const float* alphas = (const float*)d_in[7];
  const int* sidx = (const int*)d_in[8];

  const size_t M = 1048576;
  float* ws = (float*)d_ws;
  float* Q    = ws;                                  // [0,1M)
  unsigned short* Kb16 = (unsigned short*)(ws + M);  // [1M,3M)
  float* KsAcc = ws + 3 * M;                         // [3M,+38912)
  float* V    = ws + 5 * M;                          // [5M,9M)
  float* Vtb_f= ws + 9 * M;                          // [9M,11M)
  float* braw = ws + 11 * M;                         // [11M,16M)
  unsigned short* Wqh = (unsigned short*)(ws + 9 * M);
  unsigned short* Wql = (unsigned short*)(ws + 9 * M + M / 2);
  unsigned short* Wkh = (unsigned short*)(ws + 10 * M);
  unsigned short* Wvh = (unsigned short*)(ws + 10 * M + M / 2);
  unsigned short* eh  = (unsigned short*)(ws + 11 * M);
  unsigned short* dh  = (unsigned short*)(ws + 15 * M);
  unsigned short* dl  = (unsigned short*)(ws + 15 * M + M / 2);
  unsigned short* Vtb = (unsigned short*)Vtb_f;
  float* kvpL = ws + 11 * M;
  float* kvpC = ws + 13 * M;
  float* kspL = ws + 15 * M;
  float* kspC = ws + 15 * M + 32768;
  float* vsp  = ws + 15 * M + 65536;
  float* Ps1   = ws + 5 * M;
  float* Pl1   = ws + 6 * M;
  float* stats = ws + 7 * M;
  float* tail = ws + 16 * M;
  float* kvL  = tail;
  float* kvC  = tail + 131072;
  float* ksL  = tail + 262144;
  float* ksC  = tail + 264192;
  float* vmean= tail + 266240;
  float* Mbuf = tail + 317440;
  int*   sel  = (int*)(tail + 333824);
  unsigned short* Woh = (unsigned short*)ws;
  unsigned short* braw16 = (unsigned short*)(ws + M);
  float* proj = ws + 3 * M + M / 2;

  hipLaunchKernelGGL(cvt_in, dim3(5120), dim3(256), 0, stream, dec, enc, dh, dl, eh);
  hipLaunchKernelGGL(cvt_w3, dim3(16, 16, 3), dim3(256), 0, stream,
                     Wq, Wk, Wv, Wqh, Wql, Wkh, Wvh);
  hipLaunchKernelGGL(k_samp, dim3(38, 8), dim3(128), 0, stream, enc, Wk, sidx, KsAcc);
  hipLaunchKernelGGL(gemm_qkv, dim3(72, 8), dim3(256), 40960, stream,
                     dh, dl, Wqh, Wql, Q, eh, Wkh, Kb16, Wvh, V);
  hipLaunchKernelGGL(pp_scores, dim3(128), dim3(128), 0, stream, Q, KsAcc, Mbuf);
  hipLaunchKernelGGL(pp_topk, dim3(32), dim3(256), 0, stream, Mbuf, sel);
  hipLaunchKernelGGL(cvt_vt, dim3(1024), dim3(256), 0, stream, V, Vtb);
  hipLaunchKernelGGL(lin_cos_stats, dim3(512), dim3(256), 0, stream, Kb16, V,
                     kvpL, kvpC, kspL, kspC, vsp);
  hipLaunchKernelGGL(reduce_all, dim3(1048), dim3(256), 0, stream,
                     kvpL, kvpC, kspL, kspC, vsp, kvL, kvC, ksL, ksC, vmean);
  hipLaunchKernelGGL(attn_mfma, dim3(512), dim3(256), 0, stream, Q, Kb16, Vtb,
                     braw, Ps1, braw + 4 * M, Pl1, stats);
  hipLaunchKernelGGL(combine_fill, dim3(1024), dim3(256), 0, stream,
                     braw, Ps1, Pl1, stats, vmean, sel);
  hipLaunchKernelGGL(lin_cos_apply, dim3(4096), dim3(256), 0, stream, Q, kvL, kvC, ksL, ksC,
                     braw + M, braw + 3 * M);
  hipLaunchKernelGGL(cvt_w, dim3(16, 16), dim3(256), 0, stream, Wo, Woh);
  hipLaunchKernelGGL(cvt_braw, dim3(5120), dim3(256), 0, stream, braw, braw16);
  hipLaunchKernelGGL(gemm_one, dim3(40, 8), dim3(256), 40960, stream, braw16, Woh, proj);
  hipLaunchKernelGGL(combine, dim3(1024), dim3(256), 0, stream, dec, proj, rmsw, alphas,
                     (float*)d_out);
}

// Round 16
// 367.897 us; speedup vs baseline: 1.0642x; 1.0405x over previous
//
#include <hip/hip_runtime.h>
#include <math.h>

#define LDEC 512
#define LENC 2048
#define DMODEL 1024
#define NH 16
#define HD 64
#define SCALE 0.125f
#define NTOP 31
#define NSAMP 38

typedef __attribute__((ext_vector_type(8))) short bf16x8;
typedef __attribute__((ext_vector_type(4))) float f32x4;

__device__ inline float wave_sum(float v) {
#pragma unroll
  for (int m = 32; m > 0; m >>= 1) v += __shfl_xor(v, m);
  return v;
}

__device__ inline unsigned short f2bf(float x) {
  unsigned u = __float_as_uint(x);
  u += 0x7fff + ((u >> 16) & 1);  // RNE
  return (unsigned short)(u >> 16);
}
__device__ inline float bf2f(unsigned short h) {
  return __uint_as_float(((unsigned)h) << 16);
}

// async HBM -> LDS, 16 B per lane; lds base must be wave-uniform
__device__ __forceinline__ void gld16(const unsigned short* g, unsigned short* l) {
  __builtin_amdgcn_global_load_lds(
      (const __attribute__((address_space(1))) unsigned int*)g,
      (__attribute__((address_space(3))) unsigned int*)l, 16, 0, 0);
}

// ---------------- fp32 -> bf16 hi/lo split for dec (hi+lo) and enc (hi only)
__global__ __launch_bounds__(256) void cvt_in(const float* __restrict__ dec,
                                              const float* __restrict__ enc,
                                              unsigned short* __restrict__ dh,
                                              unsigned short* __restrict__ dl,
                                              unsigned short* __restrict__ eh) {
  int i = blockIdx.x * 256 + threadIdx.x;
  if (i < 262144) {
    float4 v = ((const float4*)dec)[i];
    ushort4 h = make_ushort4(f2bf(v.x), f2bf(v.y), f2bf(v.z), f2bf(v.w));
    ushort4 l = make_ushort4(f2bf(v.x - bf2f(h.x)), f2bf(v.y - bf2f(h.y)),
                             f2bf(v.z - bf2f(h.z)), f2bf(v.w - bf2f(h.w)));
    *(ushort4*)(dh + i * 4) = h;
    *(ushort4*)(dl + i * 4) = l;
  } else {
    int j = i - 262144;
    float4 v = ((const float4*)enc)[j];
    *(ushort4*)(eh + j * 4) =
        make_ushort4(f2bf(v.x), f2bf(v.y), f2bf(v.z), f2bf(v.w));
  }
}

// ---------------- W[k][n] fp32 -> Wt[n][k] bf16; z selects Wq(hi+lo)/Wk/Wv
__global__ __launch_bounds__(256) void cvt_w3(
    const float* __restrict__ Wq, const float* __restrict__ Wk,
    const float* __restrict__ Wv, unsigned short* __restrict__ Wqh,
    unsigned short* __restrict__ Wql, unsigned short* __restrict__ Wkh,
    unsigned short* __restrict__ Wvh) {
  __shared__ float t[64][68];
  int which = blockIdx.z;
  const float* W = which == 0 ? Wq : (which == 1 ? Wk : Wv);
  unsigned short* Th = which == 0 ? Wqh : (which == 1 ? Wkh : Wvh);
  unsigned short* Tl = which == 0 ? Wql : nullptr;
  int k0 = blockIdx.x * 64, n0 = blockIdx.y * 64;
  int tid = threadIdx.x;
#pragma unroll
  for (int i = 0; i < 4; ++i) {
    int c = tid + 256 * i;
    int r = c >> 4, c4 = (c & 15) * 4;
    float4 v = *(const float4*)(W + (size_t)(k0 + r) * DMODEL + n0 + c4);
    t[c4 + 0][r] = v.x; t[c4 + 1][r] = v.y; t[c4 + 2][r] = v.z; t[c4 + 3][r] = v.w;
  }
  __syncthreads();
#pragma unroll
  for (int i = 0; i < 4; ++i) {
    int c = tid + 256 * i;
    int n = c >> 4, k4 = (c & 15) * 4;
    float4 v = *(const float4*)&t[n][k4];
    ushort4 h = make_ushort4(f2bf(v.x), f2bf(v.y), f2bf(v.z), f2bf(v.w));
    *(ushort4*)(Th + (size_t)(n0 + n) * DMODEL + k0 + k4) = h;
    if (Tl) {
      ushort4 l = make_ushort4(f2bf(v.x - bf2f(h.x)), f2bf(v.y - bf2f(h.y)),
                               f2bf(v.z - bf2f(h.z)), f2bf(v.w - bf2f(h.w)));
      *(ushort4*)(Tl + (size_t)(n0 + n) * DMODEL + k0 + k4) = l;
    }
  }
}

// ---------------- W[k][n] fp32 -> Wt[n][k] bf16 hi only (Wo, late phase)
__global__ __launch_bounds__(256) void cvt_w(const float* __restrict__ W,
                                             unsigned short* __restrict__ Th) {
  __shared__ float t[64][68];
  int k0 = blockIdx.x * 64, n0 = blockIdx.y * 64;
  int tid = threadIdx.x;
#pragma unroll
  for (int i = 0; i < 4; ++i) {
    int c = tid + 256 * i;
    int r = c >> 4, c4 = (c & 15) * 4;
    float4 v = *(const float4*)(W + (size_t)(k0 + r) * DMODEL + n0 + c4);
    t[c4 + 0][r] = v.x; t[c4 + 1][r] = v.y; t[c4 + 2][r] = v.z; t[c4 + 3][r] = v.w;
  }
  __syncthreads();
#pragma unroll
  for (int i = 0; i < 4; ++i) {
    int c = tid + 256 * i;
    int n = c >> 4, k4 = (c & 15) * 4;
    float4 v = *(const float4*)&t[n][k4];
    *(ushort4*)(Th + (size_t)(n0 + n) * DMODEL + k0 + k4) =
        make_ushort4(f2bf(v.x), f2bf(v.y), f2bf(v.z), f2bf(v.w));
  }
}

// ---------------- fp32 -> bf16 flat (braw only)
__global__ __launch_bounds__(256) void cvt_braw(const float* __restrict__ src,
                                                unsigned short* __restrict__ dst) {
  int i = blockIdx.x * 256 + threadIdx.x;
  float4 v = ((const float4*)src)[i];
  *(ushort4*)(dst + i * 4) = make_ushort4(f2bf(v.x), f2bf(v.y), f2bf(v.z), f2bf(v.w));
}

// ---------------- sampled K rows in pure fp32 (top-k accuracy anchor)
__global__ __launch_bounds__(128) void k_samp(const float* __restrict__ enc,
                                              const float* __restrict__ Wk,
                                              const int* __restrict__ sidx,
                                              float* __restrict__ KsAcc) {
  __shared__ float er[1024];
  int s = blockIdx.x;
  int c = blockIdx.y * 128 + threadIdx.x;
  int srow = sidx[s];
#pragma unroll
  for (int i = 0; i < 2; ++i) {
    int idx = (threadIdx.x + 128 * i) * 4;
    *(float4*)&er[idx] = *(const float4*)(enc + (size_t)srow * DMODEL + idx);
  }
  __syncthreads();
  float acc = 0.f;
  for (int k = 0; k < 1024; ++k)
    acc = fmaf(er[k], Wk[(size_t)k * DMODEL + c], acc);
  KsAcc[s * DMODEL + c] = acc;
}

// ======= shared epilogue: 64x32 wave tile via LDS transpose (stride 36) ====
template <int BF16OUT>
__device__ __forceinline__ void gemm_epilogue(
    unsigned short* sm, f32x4 (&acc)[4][2], float* __restrict__ C,
    unsigned short* __restrict__ Cb, int row0, int col0, int wave, int lane) {
  const int l16 = lane & 15, quad = lane >> 4;
  float* eL = (float*)sm + wave * 576;
  const int rr = lane >> 2, cc = (lane & 3) * 8;
  const int wr = wave >> 2, wc = wave & 3;
#pragma unroll
  for (int x = 0; x < 4; ++x) {
#pragma unroll
    for (int y = 0; y < 2; ++y)
#pragma unroll
      for (int q = 0; q < 4; ++q)
        eL[(quad * 4 + q) * 36 + y * 16 + l16] = acc[x][y][q];
    float4 v0 = *(const float4*)&eL[rr * 36 + cc];
    float4 v1 = *(const float4*)&eL[rr * 36 + cc + 4];
    size_t ro = (size_t)(row0 + wr * 64 + x * 16 + rr) * DMODEL + col0 + wc * 32 + cc;
    if (BF16OUT) {
      uint2 o;
      o.x = (unsigned)f2bf(v0.x) | ((unsigned)f2bf(v0.y) << 16);
      o.y = (unsigned)f2bf(v0.z) | ((unsigned)f2bf(v0.w) << 16);
      *(uint2*)(Cb + ro) = o;
      o.x = (unsigned)f2bf(v1.x) | ((unsigned)f2bf(v1.y) << 16);
      o.y = (unsigned)f2bf(v1.z) | ((unsigned)f2bf(v1.w) << 16);
      *(uint2*)(Cb + ro + 4) = o;
    } else {
      *(float4*)(C + ro) = v0;
      *(float4*)(C + ro + 4) = v1;
    }
  }
}

// ======= 1-pass bf16 GEMM, 512 thr, wave-tile 64x32, ASYNC global->LDS ====
// LDS: linear unpadded A[128][32]+B[128][32] bf16, dbuf = 32768 B total.
// Staging via global_load_lds width=16 (m97 lever): wave w stages 16 rows,
// lane-contiguous dest = wave_base + lane*16 B (row w*16+l/4, col (l%4)*8).
template <int BF16OUT>
__device__ __forceinline__ void gemm512_1p_async(
    const unsigned short* __restrict__ Ah, const unsigned short* __restrict__ Bh,
    float* __restrict__ C, unsigned short* __restrict__ Cb, int row0, int col0) {
  extern __shared__ unsigned short sm[];
  const int BUFS = 8192;  // shorts per buffer (A 4096 + B 4096)
  const int tid = threadIdx.x, lane = tid & 63, wave = tid >> 6;
  const int l16 = lane & 15, quad = lane >> 4;
  const int wr = wave >> 2, wc = wave & 3;

  const int srow = wave * 16 + (lane >> 2);
  const int scol = (lane & 3) * 8;
  const unsigned short* gA = Ah + (size_t)(row0 + srow) * DMODEL + scol;
  const unsigned short* gB = Bh + (size_t)(col0 + srow) * DMODEL + scol;
  const int wofs = wave * 512;  // shorts; wave-uniform

  f32x4 acc[4][2];
#pragma unroll
  for (int x = 0; x < 4; ++x)
#pragma unroll
    for (int y = 0; y < 2; ++y) acc[x][y] = (f32x4){0.f, 0.f, 0.f, 0.f};

  gld16(gA, sm + wofs);
  gld16(gB, sm + 4096 + wofs);
  __syncthreads();  // vmcnt(0): tile 0 resident

  for (int it = 0; it < 32; ++it) {
    const unsigned short* cur = sm + (it & 1) * BUFS;
    if (it < 31) {
      int ko = (it + 1) * 32;
      unsigned short* nxt = sm + ((it + 1) & 1) * BUFS;
      gld16(gA + ko, nxt + wofs);
      gld16(gB + ko, nxt + 4096 + wofs);
    }
    bf16x8 a[4], b[2];
#pragma unroll
    for (int x = 0; x < 4; ++x)
      a[x] = *(const bf16x8*)&cur[(wr * 64 + x * 16 + l16) * 32 + quad * 8];
#pragma unroll
    for (int y = 0; y < 2; ++y)
      b[y] = *(const bf16x8*)&cur[4096 + (wc * 32 + y * 16 + l16) * 32 + quad * 8];
#pragma unroll
    for (int x = 0; x < 4; ++x)
#pragma unroll
      for (int y = 0; y < 2; ++y)
        acc[x][y] = __builtin_amdgcn_mfma_f32_16x16x32_bf16(a[x], b[y], acc[x][y], 0, 0, 0);
    __syncthreads();  // drains prefetch (vmcnt 0) + read/write fence
  }
  gemm_epilogue<BF16OUT>(sm, acc, C, Cb, row0, col0, wave, lane);
}

// ======= 3-pass hi/lo GEMM, 512 thr, padded dbuf (round-12 proven path) ====
__device__ __forceinline__ void gemm512_3p(
    const unsigned short* __restrict__ Ah, const unsigned short* __restrict__ Al,
    const unsigned short* __restrict__ Bh, const unsigned short* __restrict__ Bl,
    float* __restrict__ C, int row0, int col0) {
  extern __shared__ unsigned short sm[];
  const int BUFS = 20480;
  const int tid = threadIdx.x, lane = tid & 63, wave = tid >> 6;
  const int l16 = lane & 15, quad = lane >> 4;
  const int wr = wave >> 2, wc = wave & 3;

  const int r = tid >> 2, kc = tid & 3;
  const unsigned short* gAh = Ah + (size_t)(row0 + r) * DMODEL + kc * 8;
  const unsigned short* gBh = Bh + (size_t)(col0 + r) * DMODEL + kc * 8;
  const unsigned short* gAl = Al + (size_t)(row0 + r) * DMODEL + kc * 8;
  const unsigned short* gBl = Bl + (size_t)(col0 + r) * DMODEL + kc * 8;
  const int lofs = r * 40 + kc * 8;

  f32x4 acc[4][2];
#pragma unroll
  for (int x = 0; x < 4; ++x)
#pragma unroll
    for (int y = 0; y < 2; ++y) acc[x][y] = (f32x4){0.f, 0.f, 0.f, 0.f};

  uint4 pah = *(const uint4*)gAh, pbh = *(const uint4*)gBh;
  uint4 pal = *(const uint4*)gAl, pbl = *(const uint4*)gBl;
  *(uint4*)&sm[lofs] = pah;
  *(uint4*)&sm[5120 + lofs] = pbh;
  *(uint4*)&sm[10240 + lofs] = pal;
  *(uint4*)&sm[15360 + lofs] = pbl;
  pah = *(const uint4*)(gAh + 32);
  pbh = *(const uint4*)(gBh + 32);
  pal = *(const uint4*)(gAl + 32);
  pbl = *(const uint4*)(gBl + 32);
  __syncthreads();

  for (int it = 0; it < 32; ++it) {
    const unsigned short* cur = sm + (it & 1) * BUFS;
    bf16x8 ah[4], bh[2], al[4], bl[2];
#pragma unroll
    for (int x = 0; x < 4; ++x) {
      ah[x] = *(const bf16x8*)&cur[(wr * 64 + x * 16 + l16) * 40 + quad * 8];
      al[x] = *(const bf16x8*)&cur[10240 + (wr * 64 + x * 16 + l16) * 40 + quad * 8];
    }
#pragma unroll
    for (int y = 0; y < 2; ++y) {
      bh[y] = *(const bf16x8*)&cur[5120 + (wc * 32 + y * 16 + l16) * 40 + quad * 8];
      bl[y] = *(const bf16x8*)&cur[15360 + (wc * 32 + y * 16 + l16) * 40 + quad * 8];
    }
#pragma unroll
    for (int x = 0; x < 4; ++x)
#pragma unroll
      for (int y = 0; y < 2; ++y) {
        acc[x][y] = __builtin_amdgcn_mfma_f32_16x16x32_bf16(ah[x], bh[y], acc[x][y], 0, 0, 0);
        acc[x][y] = __builtin_amdgcn_mfma_f32_16x16x32_bf16(ah[x], bl[y], acc[x][y], 0, 0, 0);
        acc[x][y] = __builtin_amdgcn_mfma_f32_16x16x32_bf16(al[x], bh[y], acc[x][y], 0, 0, 0);
      }
    if (it < 31) {
      unsigned short* nxt = sm + ((it + 1) & 1) * BUFS;
      *(uint4*)&nxt[lofs] = pah;
      *(uint4*)&nxt[5120 + lofs] = pbh;
      *(uint4*)&nxt[10240 + lofs] = pal;
      *(uint4*)&nxt[15360 + lofs] = pbl;
      if (it < 30) {
        int ko = (it + 2) * 32;
        pah = *(const uint4*)(gAh + ko);
        pbh = *(const uint4*)(gBh + ko);
        pal = *(const uint4*)(gAl + ko);
        pbl = *(const uint4*)(gBl + ko);
      }
    }
    __syncthreads();
  }
  gemm_epilogue<0>(sm, acc, C, nullptr, row0, col0, wave, lane);
}

// merged Q(3-pass) + K(1-pass async, bf16-out) + V(1-pass async)
__global__ __launch_bounds__(512, 4) void gemm_qkv(
    const unsigned short* __restrict__ dh, const unsigned short* __restrict__ dl,
    const unsigned short* __restrict__ Wqh, const unsigned short* __restrict__ Wql,
    float* __restrict__ Q,
    const unsigned short* __restrict__ eh, const unsigned short* __restrict__ Wkh,
    unsigned short* __restrict__ Kb16,
    const unsigned short* __restrict__ Wvh, float* __restrict__ V) {
  int bx = blockIdx.x;
  if (bx < 8)
    gemm512_3p(dh, dl, Wqh, Wql, Q, bx * 128, blockIdx.y * 128);
  else if (bx < 40)
    gemm512_1p_async<1>(eh, Wkh, nullptr, Kb16, (bx - 8) * 128, blockIdx.y * 128);
  else
    gemm512_1p_async<0>(eh, Wvh, V, nullptr, (bx - 40) * 128, blockIdx.y * 128);
}

__global__ __launch_bounds__(512, 4) void gemm_one(
    const unsigned short* __restrict__ Ah, const unsigned short* __restrict__ Bh,
    float* __restrict__ C) {
  gemm512_1p_async<0>(Ah, Bh, C, nullptr, blockIdx.x * 128, blockIdx.y * 128);
}

// V fp32 -> bf16 transposed per head: Vt[(b*16+h)*64 + d][s]
__global__ __launch_bounds__(256) void cvt_vt(const float* __restrict__ V,
                                              unsigned short* __restrict__ Vt) {
  __shared__ unsigned short tile[64][72];
  int bh = blockIdx.x >> 5;
  int s0 = (blockIdx.x & 31) * 64;
  int b = bh >> 4, h = bh & 15;
  int tid = threadIdx.x;
#pragma unroll
  for (int i = 0; i < 4; ++i) {
    int c = tid + 256 * i;
    int s = c >> 4, d4 = (c & 15) * 4;
    float4 v = *(const float4*)(V + (size_t)(b * LENC + s0 + s) * DMODEL + h * HD + d4);
    tile[d4 + 0][s] = f2bf(v.x);
    tile[d4 + 1][s] = f2bf(v.y);
    tile[d4 + 2][s] = f2bf(v.z);
    tile[d4 + 3][s] = f2bf(v.w);
  }
  __syncthreads();
#pragma unroll
  for (int i = 0; i < 2; ++i) {
    int c = tid + 256 * i;
    int d = c >> 3, soff = (c & 7) * 8;
    uint4 o = *(const uint4*)&tile[d][soff];
    *(uint4*)(Vt + (size_t)(bh * 64 + d) * LENC + s0 + soff) = o;
  }
}

// ---------------- MFMA flash attention, split-K 2-way + XCD swizzle, bf16 K
#define TSTR 72

__global__ __launch_bounds__(256) void attn_mfma(
    const float* __restrict__ Qf, const unsigned short* __restrict__ Kb,
    const unsigned short* __restrict__ Vt,
    float* __restrict__ Ps0, float* __restrict__ Ps1,
    float* __restrict__ Pl0, float* __restrict__ Pl1,
    float* __restrict__ st) {
  __shared__ unsigned short Ks[2][64 * TSTR];
  __shared__ unsigned short Vs[2][64 * TSTR];
  __shared__ unsigned short Ps[4][16 * TSTR];
  const int tid = threadIdx.x;
  const int wave = tid >> 6, lane = tid & 63;
  const int l16 = lane & 15, quad = lane >> 4;
  const int bx = blockIdx.x;
  const int xcd = bx & 7, sub = bx >> 3;
  const int qt = sub & 7, half = (sub >> 3) & 1, grp = sub >> 4;
  const int bh = xcd + 8 * grp;
  const int b = bh >> 4, h = bh & 15;
  const int tbase = qt * 64 + wave * 16;
  const int sbase = half * 1024;

  const float* qrow = Qf + (size_t)(b * LDEC + tbase + l16) * DMODEL + h * HD + quad * 8;
  bf16x8 qa0, qa1;
  {
    float4 a0 = *(const float4*)qrow, a1 = *(const float4*)(qrow + 4);
    float4 a2 = *(const float4*)(qrow + 32), a3 = *(const float4*)(qrow + 36);
    qa0[0] = f2bf(a0.x * SCALE); qa0[1] = f2bf(a0.y * SCALE);
    qa0[2] = f2bf(a0.z * SCALE); qa0[3] = f2bf(a0.w * SCALE);
    qa0[4] = f2bf(a1.x * SCALE); qa0[5] = f2bf(a1.y * SCALE);
    qa0[6] = f2bf(a1.z * SCALE); qa0[7] = f2bf(a1.w * SCALE);
    qa1[0] = f2bf(a2.x * SCALE); qa1[1] = f2bf(a2.y * SCALE);
    qa1[2] = f2bf(a2.z * SCALE); qa1[3] = f2bf(a2.w * SCALE);
    qa1[4] = f2bf(a3.x * SCALE); qa1[5] = f2bf(a3.y * SCALE);
    qa1[6] = f2bf(a3.z * SCALE); qa1[7] = f2bf(a3.w * SCALE);
  }

  int loC[4], hiC[4];
#pragma unroll
  for (int r = 0; r < 4; ++r) {
    int t = tbase + quad * 4 + r;
    int c = min(4 * t, LENC - 1);
    loC[r] = max(c - 256, 0); hiC[r] = min(c + 256, LENC - 1);
  }
  int tA = tbase + l16;
  int cA = min(4 * tA, LENC - 1);
  int loA = max(cA - 256, 0), hiA = min(cA + 256, LENC - 1);
  const int loW = max(4 * tbase - 256, 0);
  const int hiW = min(4 * (tbase + 15) + 256, LENC - 1);

  f32x4 Os[4], Ol[4];
#pragma unroll
  for (int n = 0; n < 4; ++n) {
    Os[n] = (f32x4){0.f, 0.f, 0.f, 0.f};
    Ol[n] = (f32x4){0.f, 0.f, 0.f, 0.f};
  }
  float lS[4], lL[4];
#pragma unroll
  for (int r = 0; r < 4; ++r) { lS[r] = 0.f; lL[r] = 0.f; }

  const int c0 = tid, c1 = tid + 256;
  const unsigned short* kg0 = Kb + (size_t)(b * LENC + sbase + (c0 >> 3)) * DMODEL + h * HD + (c0 & 7) * 8;
  const unsigned short* kg1 = Kb + (size_t)(b * LENC + sbase + (c1 >> 3)) * DMODEL + h * HD + (c1 & 7) * 8;
  const unsigned short* vg0 = Vt + (size_t)(bh * 64 + (c0 >> 3)) * LENC + sbase + (c0 & 7) * 8;
  const unsigned short* vg1 = Vt + (size_t)(bh * 64 + (c1 >> 3)) * LENC + sbase + (c1 & 7) * 8;
  const int of0 = (c0 >> 3) * TSTR + (c0 & 7) * 8;
  const int of1 = (c1 >> 3) * TSTR + (c1 & 7) * 8;

  uint4 pk0, pk1, pv0, pv1;
  pk0 = *(const uint4*)kg0; pk1 = *(const uint4*)kg1;
  pv0 = *(const uint4*)vg0; pv1 = *(const uint4*)vg1;
  *(uint4*)&Ks[0][of0] = pk0; *(uint4*)&Ks[0][of1] = pk1;
  *(uint4*)&Vs[0][of0] = pv0; *(uint4*)&Vs[0][of1] = pv1;
  __syncthreads();

  for (int it = 0; it < 16; ++it) {
    const int cur = it & 1;
    const int s0 = sbase + it * 64;
    const bool anyL = (s0 <= hiW) && (s0 + 63 >= loW);
    if (it < 15) {
      pk0 = *(const uint4*)(kg0 + (size_t)(it + 1) * 64 * DMODEL);
      pk1 = *(const uint4*)(kg1 + (size_t)(it + 1) * 64 * DMODEL);
      pv0 = *(const uint4*)(vg0 + (it + 1) * 64);
      pv1 = *(const uint4*)(vg1 + (it + 1) * 64);
    }
    const unsigned short* K_ = Ks[cur];
    const unsigned short* V_ = Vs[cur];

    f32x4 S[4];
#pragma unroll
    for (int n = 0; n < 4; ++n) {
      bf16x8 bk0 = *(const bf16x8*)&K_[(n * 16 + l16) * TSTR + quad * 8];
      bf16x8 bk1 = *(const bf16x8*)&K_[(n * 16 + l16) * TSTR + 32 + quad * 8];
      f32x4 z = (f32x4){0.f, 0.f, 0.f, 0.f};
      z = __builtin_amdgcn_mfma_f32_16x16x32_bf16(qa0, bk0, z, 0, 0, 0);
      S[n] = __builtin_amdgcn_mfma_f32_16x16x32_bf16(qa1, bk1, z, 0, 0, 0);
    }

    float e[4][4];
#pragma unroll
    for (int r = 0; r < 4; ++r) {
#pragma unroll
      for (int n = 0; n < 4; ++n) e[n][r] = __expf(S[n][r]);
      float se = e[0][r] + e[1][r] + e[2][r] + e[3][r];
      float sl = 0.f;
      if (anyL) {
#pragma unroll
        for (int n = 0; n < 4; ++n) {
          int sc = s0 + n * 16 + l16;
          sl += (sc >= loC[r] && sc <= hiC[r]) ? e[n][r] : 0.f;
        }
      }
#pragma unroll
      for (int d = 1; d < 16; d <<= 1) { se += __shfl_xor(se, d); sl += __shfl_xor(sl, d); }
      lS[r] += se;
      lL[r] += sl;
    }

    unsigned short* Pw = Ps[wave];
#pragma unroll
    for (int n = 0; n < 4; ++n)
#pragma unroll
      for (int r = 0; r < 4; ++r)
        Pw[(quad * 4 + r) * TSTR + n * 16 + l16] = f2bf(e[n][r]);
    bf16x8 aP0 = *(const bf16x8*)&Pw[l16 * TSTR + quad * 8];
    bf16x8 aP1 = *(const bf16x8*)&Pw[l16 * TSTR + 32 + quad * 8];
#pragma unroll
    for (int n = 0; n < 4; ++n) {
      bf16x8 bv0 = *(const bf16x8*)&V_[(n * 16 + l16) * TSTR + quad * 8];
      bf16x8 bv1 = *(const bf16x8*)&V_[(n * 16 + l16) * TSTR + 32 + quad * 8];
      Os[n] = __builtin_amdgcn_mfma_f32_16x16x32_bf16(aP0, bv0, Os[n], 0, 0, 0);
      Os[n] = __builtin_amdgcn_mfma_f32_16x16x32_bf16(aP1, bv1, Os[n], 0, 0, 0);
    }
    if (anyL) {
      bf16x8 aL0 = aP0, aL1 = aP1;
#pragma unroll
      for (int j = 0; j < 8; ++j) {
        int sc = s0 + quad * 8 + j;
        if (sc < loA || sc > hiA) aL0[j] = 0;
        if (sc + 32 < loA || sc + 32 > hiA) aL1[j] = 0;
      }
#pragma unroll
      for (int n = 0; n < 4; ++n) {
        bf16x8 bv0 = *(const bf16x8*)&V_[(n * 16 + l16) * TSTR + quad * 8];
        bf16x8 bv1 = *(const bf16x8*)&V_[(n * 16 + l16) * TSTR + 32 + quad * 8];
        Ol[n] = __builtin_amdgcn_mfma_f32_16x16x32_bf16(aL0, bv0, Ol[n], 0, 0, 0);
        Ol[n] = __builtin_amdgcn_mfma_f32_16x16x32_bf16(aL1, bv1, Ol[n], 0, 0, 0);
      }
    }
    __syncthreads();
    if (it < 15) {
      unsigned short* KL = Ks[1 - cur];
      unsigned short* VL = Vs[1 - cur];
      *(uint4*)&KL[of0] = pk0; *(uint4*)&KL[of1] = pk1;
      *(uint4*)&VL[of0] = pv0; *(uint4*)&VL[of1] = pv1;
    }
    __syncthreads();
  }

  float* osdp = half ? Ps1 : Ps0;
  float* oloc = half ? Pl1 : Pl0;
  float* sp = st + half * 32768;
#pragma unroll
  for (int r = 0; r < 4; ++r) {
    int t = tbase + quad * 4 + r;
#pragma unroll
    for (int n = 0; n < 4; ++n) {
      size_t o = (size_t)(b * LDEC + t) * DMODEL + h * HD + n * 16 + l16;
      osdp[o] = Os[n][r];
      oloc[o] = Ol[n][r];
    }
    if (l16 == 0) {
      int sr = bh * 512 + t;
      sp[sr] = lS[r];
      sp[16384 + sr] = lL[r];
    }
  }
}

// fused: split-K combine (plain sums, max-free) + probsparse fill
__global__ __launch_bounds__(256) void combine_fill(
    float* __restrict__ braw, const float* __restrict__ Ps1,
    const float* __restrict__ Pl1, const float* __restrict__ st,
    const float* __restrict__ vmean, const int* __restrict__ sel) {
  int i4 = blockIdx.x * 256 + threadIdx.x;
  int i = i4 * 4;
  int col = i & 1023, bt = i >> 10;
  int t = bt & 511, b = bt >> 9, h = col >> 6, d = col & 63;
  int bh = b * 16 + h;
  int sr = bh * 512 + t;
  float iS = 1.f / (st[sr] + st[32768 + sr]);
  float iL = 1.f / (st[16384 + sr] + st[49152 + sr]);
  float4 s0 = *(const float4*)(braw + i);
  float4 s1 = *(const float4*)(Ps1 + i);
  float4 l0 = *(const float4*)(braw + 4194304 + i);
  float4 l1 = *(const float4*)(Pl1 + i);
  float4 os = make_float4((s0.x + s1.x) * iS, (s0.y + s1.y) * iS,
                          (s0.z + s1.z) * iS, (s0.w + s1.w) * iS);
  float4 ol = make_float4((l0.x + l1.x) * iL, (l0.y + l1.y) * iL,
                          (l0.z + l1.z) * iL, (l0.w + l1.w) * iL);
  *(float4*)(braw + i) = os;
  *(float4*)(braw + 4194304 + i) = ol;
  float4 pp = sel[sr] ? os : *(const float4*)(vmean + bh * 64 + d);
  *(float4*)(braw + 2097152 + i) = pp;
}

// ---------------- linear + cosine branch stats (split-K, 16 parts; bf16 K)
__global__ __launch_bounds__(256) void lin_cos_stats(
    const unsigned short* __restrict__ Kb, const float* __restrict__ V,
    float* __restrict__ kvpL, float* __restrict__ kvpC,
    float* __restrict__ kspL, float* __restrict__ kspC, float* __restrict__ vsp) {
  __shared__ float kS[64][68];
  __shared__ float vSS[64][68];
  __shared__ float nrm[64];
  int bx = blockIdx.x;
  int bh = bx >> 4, part = bx & 15;
  int b = bh >> 4, h = bh & 15;
  int tid = threadIdx.x, lane = tid & 63, g = tid >> 6;
  const float* Vb = V + (b * LENC) * DMODEL + h * HD;
  float accL[16], accC[16];
#pragma unroll
  for (int i = 0; i < 16; ++i) { accL[i] = 0.f; accC[i] = 0.f; }
  float ksl = 0.f, ksc = 0.f, vs = 0.f;
  for (int tile = 0; tile < 2; ++tile) {
    int s0 = part * 128 + tile * 64;
#pragma unroll
    for (int i = 0; i < 2; ++i) {
      int slot = tid + 256 * i;
      int j = slot >> 3, d8 = (slot & 7) * 8;
      uint4 kv = *(const uint4*)(Kb + (size_t)(b * LENC + s0 + j) * DMODEL + h * HD + d8);
      const unsigned short* sp16 = (const unsigned short*)&kv;
#pragma unroll
      for (int q = 0; q < 8; ++q) kS[j][d8 + q] = bf2f(sp16[q]);
    }
#pragma unroll
    for (int i = 0; i < 4; ++i) {
      int slot = tid + 256 * i;
      int j = slot >> 4, d4 = slot & 15;
      *(float4*)&vSS[j][d4 * 4] = *(const float4*)(Vb + (s0 + j) * DMODEL + d4 * 4);
    }
    __syncthreads();
#pragma unroll
    for (int rr = 0; rr < 16; ++rr) {
      int row = g * 16 + rr;
      float x = kS[row][lane];
      float ssum = wave_sum(x * x);
      if (lane == 0) nrm[row] = sqrtf(ssum);
    }
    __syncthreads();
    for (int s = 0; s < 64; ++s) {
      float kval = kS[s][lane];
      float kfl = kval > 0.f ? kval + 1.f : __expf(kval);
      float kn = kval / fmaxf(nrm[s], 1e-12f);
      float kfc = fmaxf(kn, 0.f) + 1e-6f;
      const float4* vrow = (const float4*)&vSS[s][g * 16];
      float4 v0 = vrow[0], v1 = vrow[1], v2 = vrow[2], v3 = vrow[3];
      accL[0] = fmaf(kfl, v0.x, accL[0]);   accC[0] = fmaf(kfc, v0.x, accC[0]);
      accL[1] = fmaf(kfl, v0.y, accL[1]);   accC[1] = fmaf(kfc, v0.y, accC[1]);
      accL[2] = fmaf(kfl, v0.z, accL[2]);   accC[2] = fmaf(kfc, v0.z, accC[2]);
      accL[3] = fmaf(kfl, v0.w, accL[3]);   accC[3] = fmaf(kfc, v0.w, accC[3]);
      accL[4] = fmaf(kfl, v1.x, accL[4]);   accC[4] = fmaf(kfc, v1.x, accC[4]);
      accL[5] = fmaf(kfl, v1.y, accL[5]);   accC[5] = fmaf(kfc, v1.y, accC[5]);
      accL[6] = fmaf(kfl, v1.z, accL[6]);   accC[6] = fmaf(kfc, v1.z, accC[6]);
      accL[7] = fmaf(kfl, v1.w, accL[7]);   accC[7] = fmaf(kfc, v1.w, accC[7]);
      accL[8] = fmaf(kfl, v2.x, accL[8]);   accC[8] = fmaf(kfc, v2.x, accC[8]);
      accL[9] = fmaf(kfl, v2.y, accL[9]);   accC[9] = fmaf(kfc, v2.y, accC[9]);
      accL[10] = fmaf(kfl, v2.z, accL[10]); accC[10] = fmaf(kfc, v2.z, accC[10]);
      accL[11] = fmaf(kfl, v2.w, accL[11]); accC[11] = fmaf(kfc, v2.w, accC[11]);
      accL[12] = fmaf(kfl, v3.x, accL[12]); accC[12] = fmaf(kfc, v3.x, accC[12]);
      accL[13] = fmaf(kfl, v3.y, accL[13]); accC[13] = fmaf(kfc, v3.y, accC[13]);
      accL[14] = fmaf(kfl, v3.z, accL[14]); accC[14] = fmaf(kfc, v3.z, accC[14]);
      accL[15] = fmaf(kfl, v3.w, accL[15]); accC[15] = fmaf(kfc, v3.w, accC[15]);
      if (g == 0) { ksl += kfl; ksc += kfc; vs += vSS[s][lane]; }
    }
    __syncthreads();
  }
  int base = part * 131072 + bh * 4096 + lane * 64 + g * 16;
#pragma unroll
  for (int i4 = 0; i4 < 4; ++i4) {
    *(float4*)&kvpL[base + i4 * 4] = make_float4(accL[i4*4], accL[i4*4+1], accL[i4*4+2], accL[i4*4+3]);
    *(float4*)&kvpC[base + i4 * 4] = make_float4(accC[i4*4], accC[i4*4+1], accC[i4*4+2], accC[i4*4+3]);
  }
  if (g == 0) {
    kspL[part * 2048 + bh * 64 + lane] = ksl;
    kspC[part * 2048 + bh * 64 + lane] = ksc;
    vsp[part * 2048 + bh * 64 + lane] = vs;
  }
}

// fused reduction of all lin/cos partials
__global__ __launch_bounds__(256) void reduce_all(
    const float* __restrict__ kvpL, const float* __restrict__ kvpC,
    const float* __restrict__ kspL, const float* __restrict__ kspC,
    const float* __restrict__ vsp, float* __restrict__ kvL,
    float* __restrict__ kvC, float* __restrict__ ksL,
    float* __restrict__ ksC, float* __restrict__ vmean) {
  int i = blockIdx.x * 256 + threadIdx.x;
  if (i < 131072) {
    float s = 0.f;
#pragma unroll
    for (int p = 0; p < 16; ++p) s += kvpL[p * 131072 + i];
    kvL[i] = s;
  } else if (i < 262144) {
    int j = i - 131072;
    float s = 0.f;
#pragma unroll
    for (int p = 0; p < 16; ++p) s += kvpC[p * 131072 + j];
    kvC[j] = s;
  } else {
    int j = i - 262144;
    int which = j >> 11, jj = j & 2047;
    const float* src = which == 0 ? kspL : (which == 1 ? kspC : vsp);
    float s = 0.f;
#pragma unroll
    for (int p = 0; p < 16; ++p) s += src[p * 2048 + jj];
    if (which == 0) ksL[jj] = s;
    else if (which == 1) ksC[jj] = s;
    else vmean[jj] = s * (1.f / 2048.f);
  }
}

// ---------------- linear + cosine apply
__global__ __launch_bounds__(256) void lin_cos_apply(
    const float* __restrict__ Q, const float* __restrict__ kvL, const float* __restrict__ kvC,
    const float* __restrict__ ksL, const float* __restrict__ ksC,
    float* __restrict__ obL, float* __restrict__ obC) {
  __shared__ float sh[2][4][64];
  int tid = threadIdx.x, lane = tid & 63, g = tid >> 6;
  int row = blockIdx.x * 4 + g;
  int bh = row >> 9, t = row & 511;
  int b = bh >> 4, h = bh & 15;
  float qv = Q[(b * LDEC + t) * DMODEL + h * HD + lane];
  float x = qv * SCALE;
  float qfl = x > 0.f ? x + 1.f : __expf(x);
  float qnorm = sqrtf(wave_sum(qv * qv));
  float qn = qv / fmaxf(qnorm, 1e-12f);
  float qfc = fmaxf(qn, 0.f) + 1e-6f;
  sh[0][g][lane] = qfl;
  sh[1][g][lane] = qfc;
  float denL = fmaxf(wave_sum(qfl * ksL[bh * 64 + lane]), 1e-6f);
  float denC = fmaxf(wave_sum(qfc * ksC[bh * 64 + lane]), 1e-6f);
  const float* kvLb = kvL + bh * 4096;
  const float* kvCb = kvC + bh * 4096;
  float aL = 0.f, aC = 0.f;
#pragma unroll
  for (int d = 0; d < 64; ++d) {
    aL = fmaf(sh[0][g][d], kvLb[d * 64 + lane], aL);
    aC = fmaf(sh[1][g][d], kvCb[d * 64 + lane], aC);
  }
  int o = (b * LDEC + t) * DMODEL + h * HD + lane;
  obL[o] = aL / denL;
  obC[o] = aC / denC;
}

// ---------------- probsparse: sampled scores -> M (fp32 Q + fp32 KsAcc)
__global__ __launch_bounds__(128) void pp_scores(
    const float* __restrict__ Q, const float* __restrict__ KsAcc,
    float* __restrict__ Mout) {
  __shared__ float qL[128][65];
  __shared__ float ksL[NSAMP][65];
  int bx = blockIdx.x;
  int bh = bx >> 2, chunk = bx & 3;
  int b = bh >> 4, h = bh & 15;
  int t0 = chunk * 128;
  int tid = threadIdx.x;
  const float* Qb = Q + (b * LDEC) * DMODEL + h * HD;
#pragma unroll
  for (int i = 0; i < 16; ++i) {
    int slot = tid + 128 * i;
    int r = slot >> 4, c4 = slot & 15;
    float4 qx = *(const float4*)(Qb + (t0 + r) * DMODEL + c4 * 4);
    qL[r][c4 * 4 + 0] = qx.x; qL[r][c4 * 4 + 1] = qx.y;
    qL[r][c4 * 4 + 2] = qx.z; qL[r][c4 * 4 + 3] = qx.w;
  }
  for (int slot = tid; slot < NSAMP * 16; slot += 128) {
    int r = slot >> 4, c4 = slot & 15;
    float4 kx = *(const float4*)(KsAcc + r * DMODEL + h * HD + c4 * 4);
    ksL[r][c4 * 4 + 0] = kx.x; ksL[r][c4 * 4 + 1] = kx.y;
    ksL[r][c4 * 4 + 2] = kx.z; ksL[r][c4 * 4 + 3] = kx.w;
  }
  __syncthreads();
  float qr[64];
#pragma unroll
  for (int d = 0; d < 64; ++d) qr[d] = qL[tid][d];
  float mx = -INFINITY, sm = 0.f;
  for (int j = 0; j < NSAMP; ++j) {
    float s = 0.f;
#pragma unroll
    for (int d = 0; d < 64; ++d) s = fmaf(qr[d], ksL[j][d], s);
    s *= SCALE;
    mx = fmaxf(mx, s);
    sm += s;
  }
  Mout[bh * LDEC + t0 + tid] = mx - sm / (float)NSAMP;
}

// ---------------- probsparse: top-31 (tie -> lower index)
__global__ __launch_bounds__(256) void pp_topk(const float* __restrict__ Mbuf,
                                               int* __restrict__ sel) {
  __shared__ float vals[512];
  __shared__ int flag[512];
  __shared__ float wvs[4];
  __shared__ int wis[4];
  int bh = blockIdx.x;
  int tid = threadIdx.x, lane = tid & 63, g = tid >> 6;
  vals[tid] = Mbuf[bh * 512 + tid];
  vals[tid + 256] = Mbuf[bh * 512 + tid + 256];
  flag[tid] = 0; flag[tid + 256] = 0;
  __syncthreads();
  for (int it = 0; it < NTOP; ++it) {
    float v0 = vals[tid]; int i0 = tid;
    float v1 = vals[tid + 256];
    if (v1 > v0) { v0 = v1; i0 = tid + 256; }
#pragma unroll
    for (int mm = 32; mm > 0; mm >>= 1) {
      float ov = __shfl_xor(v0, mm);
      int oi = __shfl_xor(i0, mm);
      if (ov > v0 || (ov == v0 && oi < i0)) { v0 = ov; i0 = oi; }
    }
    if (lane == 0) { wvs[g] = v0; wis[g] = i0; }
    __syncthreads();
    if (tid == 0) {
      float bv = wvs[0]; int bi = wis[0];
#pragma unroll
      for (int w = 1; w < 4; ++w)
        if (wvs[w] > bv || (wvs[w] == bv && wis[w] < bi)) { bv = wvs[w]; bi = wis[w]; }
      vals[bi] = -INFINITY;
      flag[bi] = 1;
    }
    __syncthreads();
  }
  sel[bh * 512 + tid] = flag[tid];
  sel[bh * 512 + tid + 256] = flag[tid + 256];
}

// ---------------- final combine
__global__ __launch_bounds__(256) void combine(
    const float* __restrict__ dec, const float* __restrict__ proj,
    const float* __restrict__ rmsw, const float* __restrict__ alphas,
    float* __restrict__ out) {
  __shared__ float red[4];
  int row = blockIdx.x;
  int tid = threadIdx.x, lane = tid & 63, g = tid >> 6;
  int base = row * DMODEL + tid * 4;
  float4 dv = *(const float4*)(dec + base);
  float4 wv = *(const float4*)(rmsw + tid * 4);
  float a[6];
  float amax = -INFINITY;
#pragma unroll
  for (int i = 0; i < 6; ++i) { a[i] = alphas[i]; amax = fmaxf(amax, a[i]); }
  float asum = 0.f;
#pragma unroll
  for (int i = 0; i < 6; ++i) { a[i] = __expf(a[i] - amax); asum += a[i]; }
#pragma unroll
  for (int i = 0; i < 6; ++i) a[i] /= asum;
  float4 acc = make_float4(a[0] * dv.x, a[0] * dv.y, a[0] * dv.z, a[0] * dv.w);
  for (int br = 0; br < 5; ++br) {
    float4 pv = *(const float4*)(proj + br * 1048576 + base);
    float4 xx = make_float4(dv.x + pv.x, dv.y + pv.y, dv.z + pv.z, dv.w + pv.w);
    float ssq = xx.x * xx.x + xx.y * xx.y + xx.z * xx.z + xx.w * xx.w;
    float wsum = wave_sum(ssq);
    if (lane == 0) red[g] = wsum;
    __syncthreads();
    float tot = red[0] + red[1] + red[2] + red[3];
    float rr = rsqrtf(tot / 1024.f + 1e-6f);
    float wb = a[br + 1];
    acc.x += wb * xx.x * rr * wv.x;
    acc.y += wb * xx.y * rr * wv.y;
    acc.z += wb * xx.z * rr * wv.z;
    acc.w += wb * xx.w * rr * wv.w;
    __syncthreads();
  }
  *(float4*)(out + base) = acc;
}

extern "C" void kernel_launch(void* const* d_in, const int* in_sizes, int n_in,
                              void* d_out, int out_size, void* d_ws, size_t ws_size,
                              hipStream_t stream) {
  const float* dec = (const float*)d_in[0];
  const float* enc = (const float*)d_in[1];
  const float* Wq = (const float*)d_in[2];
  const float* Wk = (const float*)d_in[3];
  const float* Wv = (const float*)d_in[4];
  const float* Wo = (const float*)d_in[5];
  const float* rmsw = (const float*)d_in[6];
  const float* alphas = (const float*)d_in[7];
  const int* sidx = (const int*)d_in[8];

  const size_t M = 1048576;
  float* ws = (float*)d_ws;
  float* Q    = ws;                                  // [0,1M)
  unsigned short* Kb16 = (unsigned short*)(ws + M);  // [1M,3M)
  float* KsAcc = ws + 3 * M;                         // [3M,+38912)
  float* V    = ws + 5 * M;                          // [5M,9M)
  float* Vtb_f= ws + 9 * M;                          // [9M,11M)
  float* braw = ws + 11 * M;                         // [11M,16M)
  unsigned short* Wqh = (unsigned short*)(ws + 9 * M);
  unsigned short* Wql = (unsigned short*)(ws + 9 * M + M / 2);
  unsigned short* Wkh = (unsigned short*)(ws + 10 * M);
  unsigned short* Wvh = (unsigned short*)(ws + 10 * M + M / 2);
  unsigned short* eh  = (unsigned short*)(ws + 11 * M);
  unsigned short* dh  = (unsigned short*)(ws + 15 * M);
  unsigned short* dl  = (unsigned short*)(ws + 15 * M + M / 2);
  unsigned short* Vtb = (unsigned short*)Vtb_f;
  float* kvpL = ws + 11 * M;
  float* kvpC = ws + 13 * M;
  float* kspL = ws + 15 * M;
  float* kspC = ws + 15 * M + 32768;
  float* vsp  = ws + 15 * M + 65536;
  float* Ps1   = ws + 5 * M;
  float* Pl1   = ws + 6 * M;
  float* stats = ws + 7 * M;
  float* tail = ws + 16 * M;
  float* kvL  = tail;
  float* kvC  = tail + 131072;
  float* ksL  = tail + 262144;
  float* ksC  = tail + 264192;
  float* vmean= tail + 266240;
  float* Mbuf = tail + 317440;
  int*   sel  = (int*)(tail + 333824);
  unsigned short* Woh = (unsigned short*)ws;
  unsigned short* braw16 = (unsigned short*)(ws + M);
  float* proj = ws + 3 * M + M / 2;

  hipLaunchKernelGGL(cvt_in, dim3(5120), dim3(256), 0, stream, dec, enc, dh, dl, eh);
  hipLaunchKernelGGL(cvt_w3, dim3(16, 16, 3), dim3(256), 0, stream,
                     Wq, Wk, Wv, Wqh, Wql, Wkh, Wvh);
  hipLaunchKernelGGL(k_samp, dim3(38, 8), dim3(128), 0, stream, enc, Wk, sidx, KsAcc);
  hipLaunchKernelGGL(gemm_qkv, dim3(72, 8), dim3(512), 81920, stream,
                     dh, dl, Wqh, Wql, Q, eh, Wkh, Kb16, Wvh, V);
  hipLaunchKernelGGL(pp_scores, dim3(128), dim3(128), 0, stream, Q, KsAcc, Mbuf);
  hipLaunchKernelGGL(pp_topk, dim3(32), dim3(256), 0, stream, Mbuf, sel);
  hipLaunchKernelGGL(cvt_vt, dim3(1024), dim3(256), 0, stream, V, Vtb);
  hipLaunchKernelGGL(lin_cos_stats, dim3(512), dim3(256), 0, stream, Kb16, V,
                     kvpL, kvpC, kspL, kspC, vsp);
  hipLaunchKernelGGL(reduce_all, dim3(1048), dim3(256), 0, stream,
                     kvpL, kvpC, kspL, kspC, vsp, kvL, kvC, ksL, ksC, vmean);
  hipLaunchKernelGGL(attn_mfma, dim3(512), dim3(256), 0, stream, Q, Kb16, Vtb,
                     braw, Ps1, braw + 4 * M, Pl1, stats);
  hipLaunchKernelGGL(combine_fill, dim3(1024), dim3(256), 0, stream,
                     braw, Ps1, Pl1, stats, vmean, sel);
  hipLaunchKernelGGL(lin_cos_apply, dim3(4096), dim3(256), 0, stream, Q, kvL, kvC, ksL, ksC,
                     braw + M, braw + 3 * M);
  hipLaunchKernelGGL(cvt_w, dim3(16, 16), dim3(256), 0, stream, Wo, Woh);
  hipLaunchKernelGGL(cvt_braw, dim3(5120), dim3(256), 0, stream, braw, braw16);
  hipLaunchKernelGGL(gemm_one, dim3(40, 8), dim3(512), 32768, stream, braw16, Woh, proj);
  hipLaunchKernelGGL(combine, dim3(1024), dim3(256), 0, stream, dec, proj, rmsw, alphas,
                     (float*)d_out);
}

// Round 17
// 345.659 us; speedup vs baseline: 1.1326x; 1.0643x over previous
//
#include <hip/hip_runtime.h>
#include <math.h>

#define LDEC 512
#define LENC 2048
#define DMODEL 1024
#define NH 16
#define HD 64
#define SCALE 0.125f
#define NTOP 31
#define NSAMP 38

typedef __attribute__((ext_vector_type(8))) short bf16x8;
typedef __attribute__((ext_vector_type(4))) float f32x4;

__device__ inline float wave_sum(float v) {
#pragma unroll
  for (int m = 32; m > 0; m >>= 1) v += __shfl_xor(v, m);
  return v;
}

__device__ inline unsigned short f2bf(float x) {
  unsigned u = __float_as_uint(x);
  u += 0x7fff + ((u >> 16) & 1);  // RNE
  return (unsigned short)(u >> 16);
}
__device__ inline float bf2f(unsigned short h) {
  return __uint_as_float(((unsigned)h) << 16);
}

// async HBM -> LDS, 16 B per lane; lds base must be wave-uniform
__device__ __forceinline__ void gld16(const unsigned short* g, unsigned short* l) {
  __builtin_amdgcn_global_load_lds(
      (const __attribute__((address_space(1))) unsigned int*)g,
      (__attribute__((address_space(3))) unsigned int*)l, 16, 0, 0);
}

// ================== FUSED PROLOGUE: cvt_in + cvt_w3 + k_samp =================
// grid: [0,5120) cvt_in | [5120,5888) cvt_w3 | [5888,6040) k_samp. dyn LDS 17408.
__global__ __launch_bounds__(256) void prologue(
    const float* __restrict__ dec, const float* __restrict__ enc,
    const float* __restrict__ Wq, const float* __restrict__ Wk,
    const float* __restrict__ Wv, const int* __restrict__ sidx,
    unsigned short* __restrict__ dh, unsigned short* __restrict__ dl,
    unsigned short* __restrict__ eh,
    unsigned short* __restrict__ Wqh, unsigned short* __restrict__ Wql,
    unsigned short* __restrict__ Wkh, unsigned short* __restrict__ Wvh,
    float* __restrict__ KsAcc) {
  extern __shared__ char smraw[];
  int bx = blockIdx.x;
  int tid = threadIdx.x;
  if (bx < 5120) {
    // ---- cvt_in ----
    int i = bx * 256 + tid;
    if (i < 262144) {
      float4 v = ((const float4*)dec)[i];
      ushort4 h = make_ushort4(f2bf(v.x), f2bf(v.y), f2bf(v.z), f2bf(v.w));
      ushort4 l = make_ushort4(f2bf(v.x - bf2f(h.x)), f2bf(v.y - bf2f(h.y)),
                               f2bf(v.z - bf2f(h.z)), f2bf(v.w - bf2f(h.w)));
      *(ushort4*)(dh + i * 4) = h;
      *(ushort4*)(dl + i * 4) = l;
    } else {
      int j = i - 262144;
      float4 v = ((const float4*)enc)[j];
      *(ushort4*)(eh + j * 4) =
          make_ushort4(f2bf(v.x), f2bf(v.y), f2bf(v.z), f2bf(v.w));
    }
  } else if (bx < 5888) {
    // ---- cvt_w3 ----
    float (*t)[68] = (float(*)[68])smraw;
    int wb = bx - 5120;
    int which = wb >> 8, rem = wb & 255;
    const float* W = which == 0 ? Wq : (which == 1 ? Wk : Wv);
    unsigned short* Th = which == 0 ? Wqh : (which == 1 ? Wkh : Wvh);
    unsigned short* Tl = which == 0 ? Wql : nullptr;
    int k0 = (rem >> 4) * 64, n0 = (rem & 15) * 64;
#pragma unroll
    for (int i = 0; i < 4; ++i) {
      int c = tid + 256 * i;
      int r = c >> 4, c4 = (c & 15) * 4;
      float4 v = *(const float4*)(W + (size_t)(k0 + r) * DMODEL + n0 + c4);
      t[c4 + 0][r] = v.x; t[c4 + 1][r] = v.y; t[c4 + 2][r] = v.z; t[c4 + 3][r] = v.w;
    }
    __syncthreads();
#pragma unroll
    for (int i = 0; i < 4; ++i) {
      int c = tid + 256 * i;
      int n = c >> 4, k4 = (c & 15) * 4;
      float4 v = *(const float4*)&t[n][k4];
      ushort4 h = make_ushort4(f2bf(v.x), f2bf(v.y), f2bf(v.z), f2bf(v.w));
      *(ushort4*)(Th + (size_t)(n0 + n) * DMODEL + k0 + k4) = h;
      if (Tl) {
        ushort4 l = make_ushort4(f2bf(v.x - bf2f(h.x)), f2bf(v.y - bf2f(h.y)),
                                 f2bf(v.z - bf2f(h.z)), f2bf(v.w - bf2f(h.w)));
        *(ushort4*)(Tl + (size_t)(n0 + n) * DMODEL + k0 + k4) = l;
      }
    }
  } else {
    // ---- k_samp (fp32 sampled K rows; exact serial k-order preserved) ----
    float* er = (float*)smraw;
    int sb = bx - 5888;          // 0..151
    int s = sb >> 2;             // 0..37
    int c = (sb & 3) * 256 + tid;
    int srow = sidx[s];
    {
      int idx = tid * 4;
      *(float4*)&er[idx] = *(const float4*)(enc + (size_t)srow * DMODEL + idx);
    }
    __syncthreads();
    float acc = 0.f;
    for (int k = 0; k < 1024; ++k)
      acc = fmaf(er[k], Wk[(size_t)k * DMODEL + c], acc);
    KsAcc[s * DMODEL + c] = acc;
  }
}

// ======= shared epilogue: 64x32 wave tile via LDS transpose (stride 36) ====
template <int BF16OUT>
__device__ __forceinline__ void gemm_epilogue(
    unsigned short* sm, f32x4 (&acc)[4][2], float* __restrict__ C,
    unsigned short* __restrict__ Cb, int row0, int col0, int wave, int lane) {
  const int l16 = lane & 15, quad = lane >> 4;
  float* eL = (float*)sm + wave * 576;
  const int rr = lane >> 2, cc = (lane & 3) * 8;
  const int wr = wave >> 2, wc = wave & 3;
#pragma unroll
  for (int x = 0; x < 4; ++x) {
#pragma unroll
    for (int y = 0; y < 2; ++y)
#pragma unroll
      for (int q = 0; q < 4; ++q)
        eL[(quad * 4 + q) * 36 + y * 16 + l16] = acc[x][y][q];
    float4 v0 = *(const float4*)&eL[rr * 36 + cc];
    float4 v1 = *(const float4*)&eL[rr * 36 + cc + 4];
    size_t ro = (size_t)(row0 + wr * 64 + x * 16 + rr) * DMODEL + col0 + wc * 32 + cc;
    if (BF16OUT) {
      uint2 o;
      o.x = (unsigned)f2bf(v0.x) | ((unsigned)f2bf(v0.y) << 16);
      o.y = (unsigned)f2bf(v0.z) | ((unsigned)f2bf(v0.w) << 16);
      *(uint2*)(Cb + ro) = o;
      o.x = (unsigned)f2bf(v1.x) | ((unsigned)f2bf(v1.y) << 16);
      o.y = (unsigned)f2bf(v1.z) | ((unsigned)f2bf(v1.w) << 16);
      *(uint2*)(Cb + ro + 4) = o;
    } else {
      *(float4*)(C + ro) = v0;
      *(float4*)(C + ro + 4) = v1;
    }
  }
}

// ======= 1-pass bf16 GEMM, 512 thr, wave-tile 64x32, ASYNC global->LDS ====
template <int BF16OUT>
__device__ __forceinline__ void gemm512_1p_async(
    const unsigned short* __restrict__ Ah, const unsigned short* __restrict__ Bh,
    float* __restrict__ C, unsigned short* __restrict__ Cb, int row0, int col0) {
  extern __shared__ unsigned short sm[];
  const int BUFS = 8192;
  const int tid = threadIdx.x, lane = tid & 63, wave = tid >> 6;
  const int l16 = lane & 15, quad = lane >> 4;
  const int wr = wave >> 2, wc = wave & 3;

  const int srow = wave * 16 + (lane >> 2);
  const int scol = (lane & 3) * 8;
  const unsigned short* gA = Ah + (size_t)(row0 + srow) * DMODEL + scol;
  const unsigned short* gB = Bh + (size_t)(col0 + srow) * DMODEL + scol;
  const int wofs = wave * 512;

  f32x4 acc[4][2];
#pragma unroll
  for (int x = 0; x < 4; ++x)
#pragma unroll
    for (int y = 0; y < 2; ++y) acc[x][y] = (f32x4){0.f, 0.f, 0.f, 0.f};

  gld16(gA, sm + wofs);
  gld16(gB, sm + 4096 + wofs);
  __syncthreads();

  for (int it = 0; it < 32; ++it) {
    const unsigned short* cur = sm + (it & 1) * BUFS;
    if (it < 31) {
      int ko = (it + 1) * 32;
      unsigned short* nxt = sm + ((it + 1) & 1) * BUFS;
      gld16(gA + ko, nxt + wofs);
      gld16(gB + ko, nxt + 4096 + wofs);
    }
    bf16x8 a[4], b[2];
#pragma unroll
    for (int x = 0; x < 4; ++x)
      a[x] = *(const bf16x8*)&cur[(wr * 64 + x * 16 + l16) * 32 + quad * 8];
#pragma unroll
    for (int y = 0; y < 2; ++y)
      b[y] = *(const bf16x8*)&cur[4096 + (wc * 32 + y * 16 + l16) * 32 + quad * 8];
#pragma unroll
    for (int x = 0; x < 4; ++x)
#pragma unroll
      for (int y = 0; y < 2; ++y)
        acc[x][y] = __builtin_amdgcn_mfma_f32_16x16x32_bf16(a[x], b[y], acc[x][y], 0, 0, 0);
    __syncthreads();
  }
  gemm_epilogue<BF16OUT>(sm, acc, C, Cb, row0, col0, wave, lane);
}

// ======= 3-pass hi/lo GEMM, 512 thr, padded dbuf =====
__device__ __forceinline__ void gemm512_3p(
    const unsigned short* __restrict__ Ah, const unsigned short* __restrict__ Al,
    const unsigned short* __restrict__ Bh, const unsigned short* __restrict__ Bl,
    float* __restrict__ C, int row0, int col0) {
  extern __shared__ unsigned short sm[];
  const int BUFS = 20480;
  const int tid = threadIdx.x, lane = tid & 63, wave = tid >> 6;
  const int l16 = lane & 15, quad = lane >> 4;
  const int wr = wave >> 2, wc = wave & 3;

  const int r = tid >> 2, kc = tid & 3;
  const unsigned short* gAh = Ah + (size_t)(row0 + r) * DMODEL + kc * 8;
  const unsigned short* gBh = Bh + (size_t)(col0 + r) * DMODEL + kc * 8;
  const unsigned short* gAl = Al + (size_t)(row0 + r) * DMODEL + kc * 8;
  const unsigned short* gBl = Bl + (size_t)(col0 + r) * DMODEL + kc * 8;
  const int lofs = r * 40 + kc * 8;

  f32x4 acc[4][2];
#pragma unroll
  for (int x = 0; x < 4; ++x)
#pragma unroll
    for (int y = 0; y < 2; ++y) acc[x][y] = (f32x4){0.f, 0.f, 0.f, 0.f};

  uint4 pah = *(const uint4*)gAh, pbh = *(const uint4*)gBh;
  uint4 pal = *(const uint4*)gAl, pbl = *(const uint4*)gBl;
  *(uint4*)&sm[lofs] = pah;
  *(uint4*)&sm[5120 + lofs] = pbh;
  *(uint4*)&sm[10240 + lofs] = pal;
  *(uint4*)&sm[15360 + lofs] = pbl;
  pah = *(const uint4*)(gAh + 32);
  pbh = *(const uint4*)(gBh + 32);
  pal = *(const uint4*)(gAl + 32);
  pbl = *(const uint4*)(gBl + 32);
  __syncthreads();

  for (int it = 0; it < 32; ++it) {
    const unsigned short* cur = sm + (it & 1) * BUFS;
    bf16x8 ah[4], bh[2], al[4], bl[2];
#pragma unroll
    for (int x = 0; x < 4; ++x) {
      ah[x] = *(const bf16x8*)&cur[(wr * 64 + x * 16 + l16) * 40 + quad * 8];
      al[x] = *(const bf16x8*)&cur[10240 + (wr * 64 + x * 16 + l16) * 40 + quad * 8];
    }
#pragma unroll
    for (int y = 0; y < 2; ++y) {
      bh[y] = *(const bf16x8*)&cur[5120 + (wc * 32 + y * 16 + l16) * 40 + quad * 8];
      bl[y] = *(const bf16x8*)&cur[15360 + (wc * 32 + y * 16 + l16) * 40 + quad * 8];
    }
#pragma unroll
    for (int x = 0; x < 4; ++x)
#pragma unroll
      for (int y = 0; y < 2; ++y) {
        acc[x][y] = __builtin_amdgcn_mfma_f32_16x16x32_bf16(ah[x], bh[y], acc[x][y], 0, 0, 0);
        acc[x][y] = __builtin_amdgcn_mfma_f32_16x16x32_bf16(ah[x], bl[y], acc[x][y], 0, 0, 0);
        acc[x][y] = __builtin_amdgcn_mfma_f32_16x16x32_bf16(al[x], bh[y], acc[x][y], 0, 0, 0);
      }
    if (it < 31) {
      unsigned short* nxt = sm + ((it + 1) & 1) * BUFS;
      *(uint4*)&nxt[lofs] = pah;
      *(uint4*)&nxt[5120 + lofs] = pbh;
      *(uint4*)&nxt[10240 + lofs] = pal;
      *(uint4*)&nxt[15360 + lofs] = pbl;
      if (it < 30) {
        int ko = (it + 2) * 32;
        pah = *(const uint4*)(gAh + ko);
        pbh = *(const uint4*)(gBh + ko);
        pal = *(const uint4*)(gAl + ko);
        pbl = *(const uint4*)(gBl + ko);
      }
    }
    __syncthreads();
  }
  gemm_epilogue<0>(sm, acc, C, nullptr, row0, col0, wave, lane);
}

// merged Q(3-pass) + K(1-pass async, bf16-out) + V(1-pass async)
__global__ __launch_bounds__(512, 4) void gemm_qkv(
    const unsigned short* __restrict__ dh, const unsigned short* __restrict__ dl,
    const unsigned short* __restrict__ Wqh, const unsigned short* __restrict__ Wql,
    float* __restrict__ Q,
    const unsigned short* __restrict__ eh, const unsigned short* __restrict__ Wkh,
    unsigned short* __restrict__ Kb16,
    const unsigned short* __restrict__ Wvh, float* __restrict__ V) {
  int bx = blockIdx.x;
  if (bx < 8)
    gemm512_3p(dh, dl, Wqh, Wql, Q, bx * 128, blockIdx.y * 128);
  else if (bx < 40)
    gemm512_1p_async<1>(eh, Wkh, nullptr, Kb16, (bx - 8) * 128, blockIdx.y * 128);
  else
    gemm512_1p_async<0>(eh, Wvh, V, nullptr, (bx - 40) * 128, blockIdx.y * 128);
}

__global__ __launch_bounds__(512, 4) void gemm_one(
    const unsigned short* __restrict__ Ah, const unsigned short* __restrict__ Bh,
    float* __restrict__ C) {
  gemm512_1p_async<0>(Ah, Bh, C, nullptr, blockIdx.x * 128, blockIdx.y * 128);
}

// ============ FUSED TRIO: cvt_vt + lin_cos_stats + pp_scores ================
// grid: [0,1024) cvt_vt | [1024,1536) lin_cos_stats | [1536,1664) pp_scores.
// dyn LDS 43264 B (max branch).
__global__ __launch_bounds__(256) void trio(
    const float* __restrict__ V, unsigned short* __restrict__ Vt,
    const unsigned short* __restrict__ Kb,
    float* __restrict__ kvpL, float* __restrict__ kvpC,
    float* __restrict__ kspL, float* __restrict__ kspC, float* __restrict__ vsp,
    const float* __restrict__ Q, const float* __restrict__ KsAcc,
    float* __restrict__ Mout) {
  extern __shared__ char smraw[];
  int bx0 = blockIdx.x;
  int tid = threadIdx.x;
  if (bx0 < 1024) {
    // ---- cvt_vt ----
    unsigned short (*tile)[72] = (unsigned short(*)[72])smraw;
    int bh = bx0 >> 5;
    int s0 = (bx0 & 31) * 64;
    int b = bh >> 4, h = bh & 15;
#pragma unroll
    for (int i = 0; i < 4; ++i) {
      int c = tid + 256 * i;
      int s = c >> 4, d4 = (c & 15) * 4;
      float4 v = *(const float4*)(V + (size_t)(b * LENC + s0 + s) * DMODEL + h * HD + d4);
      tile[d4 + 0][s] = f2bf(v.x);
      tile[d4 + 1][s] = f2bf(v.y);
      tile[d4 + 2][s] = f2bf(v.z);
      tile[d4 + 3][s] = f2bf(v.w);
    }
    __syncthreads();
#pragma unroll
    for (int i = 0; i < 2; ++i) {
      int c = tid + 256 * i;
      int d = c >> 3, soff = (c & 7) * 8;
      uint4 o = *(const uint4*)&tile[d][soff];
      *(uint4*)(Vt + (size_t)(bh * 64 + d) * LENC + s0 + soff) = o;
    }
  } else if (bx0 < 1536) {
    // ---- lin_cos_stats (vectorized bf16 unpack; bit-exact) ----
    float (*kS)[68] = (float(*)[68])smraw;
    float (*vSS)[68] = (float(*)[68])(smraw + 17408);
    float* nrm = (float*)(smraw + 34816);
    int bx = bx0 - 1024;
    int bh = bx >> 4, part = bx & 15;
    int b = bh >> 4, h = bh & 15;
    int lane = tid & 63, g = tid >> 6;
    const float* Vb = V + (b * LENC) * DMODEL + h * HD;
    float accL[16], accC[16];
#pragma unroll
    for (int i = 0; i < 16; ++i) { accL[i] = 0.f; accC[i] = 0.f; }
    float ksl = 0.f, ksc = 0.f, vs = 0.f;
    for (int tile8 = 0; tile8 < 2; ++tile8) {
      int s0 = part * 128 + tile8 * 64;
#pragma unroll
      for (int i = 0; i < 2; ++i) {
        int slot = tid + 256 * i;
        int j = slot >> 3, d8 = (slot & 7) * 8;
        uint4 kv = *(const uint4*)(Kb + (size_t)(b * LENC + s0 + j) * DMODEL + h * HD + d8);
        float4 f0, f1;
        f0.x = __uint_as_float(kv.x << 16);
        f0.y = __uint_as_float(kv.x & 0xffff0000u);
        f0.z = __uint_as_float(kv.y << 16);
        f0.w = __uint_as_float(kv.y & 0xffff0000u);
        f1.x = __uint_as_float(kv.z << 16);
        f1.y = __uint_as_float(kv.z & 0xffff0000u);
        f1.z = __uint_as_float(kv.w << 16);
        f1.w = __uint_as_float(kv.w & 0xffff0000u);
        *(float4*)&kS[j][d8] = f0;
        *(float4*)&kS[j][d8 + 4] = f1;
      }
#pragma unroll
      for (int i = 0; i < 4; ++i) {
        int slot = tid + 256 * i;
        int j = slot >> 4, d4 = slot & 15;
        *(float4*)&vSS[j][d4 * 4] = *(const float4*)(Vb + (s0 + j) * DMODEL + d4 * 4);
      }
      __syncthreads();
#pragma unroll
      for (int rr = 0; rr < 16; ++rr) {
        int row = g * 16 + rr;
        float x = kS[row][lane];
        float ssum = wave_sum(x * x);
        if (lane == 0) nrm[row] = sqrtf(ssum);
      }
      __syncthreads();
      for (int s = 0; s < 64; ++s) {
        float kval = kS[s][lane];
        float kfl = kval > 0.f ? kval + 1.f : __expf(kval);
        float kn = kval / fmaxf(nrm[s], 1e-12f);
        float kfc = fmaxf(kn, 0.f) + 1e-6f;
        const float4* vrow = (const float4*)&vSS[s][g * 16];
        float4 v0 = vrow[0], v1 = vrow[1], v2 = vrow[2], v3 = vrow[3];
        accL[0] = fmaf(kfl, v0.x, accL[0]);   accC[0] = fmaf(kfc, v0.x, accC[0]);
        accL[1] = fmaf(kfl, v0.y, accL[1]);   accC[1] = fmaf(kfc, v0.y, accC[1]);
        accL[2] = fmaf(kfl, v0.z, accL[2]);   accC[2] = fmaf(kfc, v0.z, accC[2]);
        accL[3] = fmaf(kfl, v0.w, accL[3]);   accC[3] = fmaf(kfc, v0.w, accC[3]);
        accL[4] = fmaf(kfl, v1.x, accL[4]);   accC[4] = fmaf(kfc, v1.x, accC[4]);
        accL[5] = fmaf(kfl, v1.y, accL[5]);   accC[5] = fmaf(kfc, v1.y, accC[5]);
        accL[6] = fmaf(kfl, v1.z, accL[6]);   accC[6] = fmaf(kfc, v1.z, accC[6]);
        accL[7] = fmaf(kfl, v1.w, accL[7]);   accC[7] = fmaf(kfc, v1.w, accC[7]);
        accL[8] = fmaf(kfl, v2.x, accL[8]);   accC[8] = fmaf(kfc, v2.x, accC[8]);
        accL[9] = fmaf(kfl, v2.y, accL[9]);   accC[9] = fmaf(kfc, v2.y, accC[9]);
        accL[10] = fmaf(kfl, v2.z, accL[10]); accC[10] = fmaf(kfc, v2.z, accC[10]);
        accL[11] = fmaf(kfl, v2.w, accL[11]); accC[11] = fmaf(kfc, v2.w, accC[11]);
        accL[12] = fmaf(kfl, v3.x, accL[12]); accC[12] = fmaf(kfc, v3.x, accC[12]);
        accL[13] = fmaf(kfl, v3.y, accL[13]); accC[13] = fmaf(kfc, v3.y, accC[13]);
        accL[14] = fmaf(kfl, v3.z, accL[14]); accC[14] = fmaf(kfc, v3.z, accC[14]);
        accL[15] = fmaf(kfl, v3.w, accL[15]); accC[15] = fmaf(kfc, v3.w, accC[15]);
        if (g == 0) { ksl += kfl; ksc += kfc; vs += vSS[s][lane]; }
      }
      __syncthreads();
    }
    int base = part * 131072 + bh * 4096 + lane * 64 + g * 16;
#pragma unroll
    for (int i4 = 0; i4 < 4; ++i4) {
      *(float4*)&kvpL[base + i4 * 4] = make_float4(accL[i4*4], accL[i4*4+1], accL[i4*4+2], accL[i4*4+3]);
      *(float4*)&kvpC[base + i4 * 4] = make_float4(accC[i4*4], accC[i4*4+1], accC[i4*4+2], accC[i4*4+3]);
    }
    if (g == 0) {
      kspL[part * 2048 + bh * 64 + lane] = ksl;
      kspC[part * 2048 + bh * 64 + lane] = ksc;
      vsp[part * 2048 + bh * 64 + lane] = vs;
    }
  } else {
    // ---- pp_scores (fp32; exact same per-element arithmetic/order) ----
    float (*qL)[65] = (float(*)[65])smraw;
    float (*ksL)[65] = (float(*)[65])(smraw + 33280);
    int bx = bx0 - 1536;
    int bh = bx >> 2, chunk = bx & 3;
    int b = bh >> 4, h = bh & 15;
    int t0 = chunk * 128;
    const float* Qb = Q + (b * LDEC) * DMODEL + h * HD;
#pragma unroll
    for (int i = 0; i < 8; ++i) {
      int slot = tid + 256 * i;
      int r = slot >> 4, c4 = slot & 15;
      float4 qx = *(const float4*)(Qb + (t0 + r) * DMODEL + c4 * 4);
      qL[r][c4 * 4 + 0] = qx.x; qL[r][c4 * 4 + 1] = qx.y;
      qL[r][c4 * 4 + 2] = qx.z; qL[r][c4 * 4 + 3] = qx.w;
    }
    for (int slot = tid; slot < NSAMP * 16; slot += 256) {
      int r = slot >> 4, c4 = slot & 15;
      float4 kx = *(const float4*)(KsAcc + r * DMODEL + h * HD + c4 * 4);
      ksL[r][c4 * 4 + 0] = kx.x; ksL[r][c4 * 4 + 1] = kx.y;
      ksL[r][c4 * 4 + 2] = kx.z; ksL[r][c4 * 4 + 3] = kx.w;
    }
    __syncthreads();
    if (tid < 128) {
      float qr[64];
#pragma unroll
      for (int d = 0; d < 64; ++d) qr[d] = qL[tid][d];
      float mx = -INFINITY, sm = 0.f;
      for (int j = 0; j < NSAMP; ++j) {
        float s = 0.f;
#pragma unroll
        for (int d = 0; d < 64; ++d) s = fmaf(qr[d], ksL[j][d], s);
        s *= SCALE;
        mx = fmaxf(mx, s);
        sm += s;
      }
      Mout[bh * LDEC + t0 + tid] = mx - sm / (float)NSAMP;
    }
  }
}

// ============ FUSED TAIL: reduce_all + pp_topk ==============================
// grid: [0,1048) reduce_all | [1048,1080) pp_topk. dyn LDS 4224 B.
__global__ __launch_bounds__(256) void tail2(
    const float* __restrict__ kvpL, const float* __restrict__ kvpC,
    const float* __restrict__ kspL, const float* __restrict__ kspC,
    const float* __restrict__ vsp, float* __restrict__ kvL,
    float* __restrict__ kvC, float* __restrict__ ksL,
    float* __restrict__ ksC, float* __restrict__ vmean,
    const float* __restrict__ Mbuf, int* __restrict__ sel) {
  extern __shared__ char smraw[];
  int bx = blockIdx.x;
  int tid = threadIdx.x;
  if (bx < 1048) {
    int i = bx * 256 + tid;
    if (i < 131072) {
      float s = 0.f;
#pragma unroll
      for (int p = 0; p < 16; ++p) s += kvpL[p * 131072 + i];
      kvL[i] = s;
    } else if (i < 262144) {
      int j = i - 131072;
      float s = 0.f;
#pragma unroll
      for (int p = 0; p < 16; ++p) s += kvpC[p * 131072 + j];
      kvC[j] = s;
    } else if (i < 268288) {
      int j = i - 262144;
      int which = j >> 11, jj = j & 2047;
      const float* src = which == 0 ? kspL : (which == 1 ? kspC : vsp);
      float s = 0.f;
#pragma unroll
      for (int p = 0; p < 16; ++p) s += src[p * 2048 + jj];
      if (which == 0) ksL[jj] = s;
      else if (which == 1) ksC[jj] = s;
      else vmean[jj] = s * (1.f / 2048.f);
    }
  } else {
    // ---- pp_topk (tie -> lower index) ----
    float* vals = (float*)smraw;
    int* flag = (int*)(smraw + 2048);
    float* wvs = (float*)(smraw + 4096);
    int* wis = (int*)(smraw + 4112);
    int bh = bx - 1048;
    int lane = tid & 63, g = tid >> 6;
    vals[tid] = Mbuf[bh * 512 + tid];
    vals[tid + 256] = Mbuf[bh * 512 + tid + 256];
    flag[tid] = 0; flag[tid + 256] = 0;
    __syncthreads();
    for (int it = 0; it < NTOP; ++it) {
      float v0 = vals[tid]; int i0 = tid;
      float v1 = vals[tid + 256];
      if (v1 > v0) { v0 = v1; i0 = tid + 256; }
#pragma unroll
      for (int mm = 32; mm > 0; mm >>= 1) {
        float ov = __shfl_xor(v0, mm);
        int oi = __shfl_xor(i0, mm);
        if (ov > v0 || (ov == v0 && oi < i0)) { v0 = ov; i0 = oi; }
      }
      if (lane == 0) { wvs[g] = v0; wis[g] = i0; }
      __syncthreads();
      if (tid == 0) {
        float bv = wvs[0]; int bi = wis[0];
#pragma unroll
        for (int w = 1; w < 4; ++w)
          if (wvs[w] > bv || (wvs[w] == bv && wis[w] < bi)) { bv = wvs[w]; bi = wis[w]; }
        vals[bi] = -INFINITY;
        flag[bi] = 1;
      }
      __syncthreads();
    }
    sel[bh * 512 + tid] = flag[tid];
    sel[bh * 512 + tid + 256] = flag[tid + 256];
  }
}

// ---------------- MFMA flash attention, split-K 2-way + XCD swizzle, bf16 K
#define TSTR 72

__global__ __launch_bounds__(256) void attn_mfma(
    const float* __restrict__ Qf, const unsigned short* __restrict__ Kb,
    const unsigned short* __restrict__ Vt,
    float* __restrict__ Ps0, float* __restrict__ Ps1,
    float* __restrict__ Pl0, float* __restrict__ Pl1,
    float* __restrict__ st) {
  __shared__ unsigned short Ks[2][64 * TSTR];
  __shared__ unsigned short Vs[2][64 * TSTR];
  __shared__ unsigned short Ps[4][16 * TSTR];
  const int tid = threadIdx.x;
  const int wave = tid >> 6, lane = tid & 63;
  const int l16 = lane & 15, quad = lane >> 4;
  const int bx = blockIdx.x;
  const int xcd = bx & 7, sub = bx >> 3;
  const int qt = sub & 7, half = (sub >> 3) & 1, grp = sub >> 4;
  const int bh = xcd + 8 * grp;
  const int b = bh >> 4, h = bh & 15;
  const int tbase = qt * 64 + wave * 16;
  const int sbase = half * 1024;

  const float* qrow = Qf + (size_t)(b * LDEC + tbase + l16) * DMODEL + h * HD + quad * 8;
  bf16x8 qa0, qa1;
  {
    float4 a0 = *(const float4*)qrow, a1 = *(const float4*)(qrow + 4);
    float4 a2 = *(const float4*)(qrow + 32), a3 = *(const float4*)(qrow + 36);
    qa0[0] = f2bf(a0.x * SCALE); qa0[1] = f2bf(a0.y * SCALE);
    qa0[2] = f2bf(a0.z * SCALE); qa0[3] = f2bf(a0.w * SCALE);
    qa0[4] = f2bf(a1.x * SCALE); qa0[5] = f2bf(a1.y * SCALE);
    qa0[6] = f2bf(a1.z * SCALE); qa0[7] = f2bf(a1.w * SCALE);
    qa1[0] = f2bf(a2.x * SCALE); qa1[1] = f2bf(a2.y * SCALE);
    qa1[2] = f2bf(a2.z * SCALE); qa1[3] = f2bf(a2.w * SCALE);
    qa1[4] = f2bf(a3.x * SCALE); qa1[5] = f2bf(a3.y * SCALE);
    qa1[6] = f2bf(a3.z * SCALE); qa1[7] = f2bf(a3.w * SCALE);
  }

  int loC[4], hiC[4];
#pragma unroll
  for (int r = 0; r < 4; ++r) {
    int t = tbase + quad * 4 + r;
    int c = min(4 * t, LENC - 1);
    loC[r] = max(c - 256, 0); hiC[r] = min(c + 256, LENC - 1);
  }
  int tA = tbase + l16;
  int cA = min(4 * tA, LENC - 1);
  int loA = max(cA - 256, 0), hiA = min(cA + 256, LENC - 1);
  const int loW = max(4 * tbase - 256, 0);
  const int hiW = min(4 * (tbase + 15) + 256, LENC - 1);

  f32x4 Os[4], Ol[4];
#pragma unroll
  for (int n = 0; n < 4; ++n) {
    Os[n] = (f32x4){0.f, 0.f, 0.f, 0.f};
    Ol[n] = (f32x4){0.f, 0.f, 0.f, 0.f};
  }
  float lS[4], lL[4];
#pragma unroll
  for (int r = 0; r < 4; ++r) { lS[r] = 0.f; lL[r] = 0.f; }

  const int c0 = tid, c1 = tid + 256;
  const unsigned short* kg0 = Kb + (size_t)(b * LENC + sbase + (c0 >> 3)) * DMODEL + h * HD + (c0 & 7) * 8;
  const unsigned short* kg1 = Kb + (size_t)(b * LENC + sbase + (c1 >> 3)) * DMODEL + h * HD + (c1 & 7) * 8;
  const unsigned short* vg0 = Vt + (size_t)(bh * 64 + (c0 >> 3)) * LENC + sbase + (c0 & 7) * 8;
  const unsigned short* vg1 = Vt + (size_t)(bh * 64 + (c1 >> 3)) * LENC + sbase + (c1 & 7) * 8;
  const int of0 = (c0 >> 3) * TSTR + (c0 & 7) * 8;
  const int of1 = (c1 >> 3) * TSTR + (c1 & 7) * 8;

  uint4 pk0, pk1, pv0, pv1;
  pk0 = *(const uint4*)kg0; pk1 = *(const uint4*)kg1;
  pv0 = *(const uint4*)vg0; pv1 = *(const uint4*)vg1;
  *(uint4*)&Ks[0][of0] = pk0; *(uint4*)&Ks[0][of1] = pk1;
  *(uint4*)&Vs[0][of0] = pv0; *(uint4*)&Vs[0][of1] = pv1;
  __syncthreads();

  for (int it = 0; it < 16; ++it) {
    const int cur = it & 1;
    const int s0 = sbase + it * 64;
    const bool anyL = (s0 <= hiW) && (s0 + 63 >= loW);
    if (it < 15) {
      pk0 = *(const uint4*)(kg0 + (size_t)(it + 1) * 64 * DMODEL);
      pk1 = *(const uint4*)(kg1 + (size_t)(it + 1) * 64 * DMODEL);
      pv0 = *(const uint4*)(vg0 + (it + 1) * 64);
      pv1 = *(const uint4*)(vg1 + (it + 1) * 64);
    }
    const unsigned short* K_ = Ks[cur];
    const unsigned short* V_ = Vs[cur];

    f32x4 S[4];
#pragma unroll
    for (int n = 0; n < 4; ++n) {
      bf16x8 bk0 = *(const bf16x8*)&K_[(n * 16 + l16) * TSTR + quad * 8];
      bf16x8 bk1 = *(const bf16x8*)&K_[(n * 16 + l16) * TSTR + 32 + quad * 8];
      f32x4 z = (f32x4){0.f, 0.f, 0.f, 0.f};
      z = __builtin_amdgcn_mfma_f32_16x16x32_bf16(qa0, bk0, z, 0, 0, 0);
      S[n] = __builtin_amdgcn_mfma_f32_16x16x32_bf16(qa1, bk1, z, 0, 0, 0);
    }

    float e[4][4];
#pragma unroll
    for (int r = 0; r < 4; ++r) {
#pragma unroll
      for (int n = 0; n < 4; ++n) e[n][r] = __expf(S[n][r]);
      float se = e[0][r] + e[1][r] + e[2][r] + e[3][r];
      float sl = 0.f;
      if (anyL) {
#pragma unroll
        for (int n = 0; n < 4; ++n) {
          int sc = s0 + n * 16 + l16;
          sl += (sc >= loC[r] && sc <= hiC[r]) ? e[n][r] : 0.f;
        }
      }
#pragma unroll
      for (int d = 1; d < 16; d <<= 1) { se += __shfl_xor(se, d); sl += __shfl_xor(sl, d); }
      lS[r] += se;
      lL[r] += sl;
    }

    unsigned short* Pw = Ps[wave];
#pragma unroll
    for (int n = 0; n < 4; ++n)
#pragma unroll
      for (int r = 0; r < 4; ++r)
        Pw[(quad * 4 + r) * TSTR + n * 16 + l16] = f2bf(e[n][r]);
    bf16x8 aP0 = *(const bf16x8*)&Pw[l16 * TSTR + quad * 8];
    bf16x8 aP1 = *(const bf16x8*)&Pw[l16 * TSTR + 32 + quad * 8];
#pragma unroll
    for (int n = 0; n < 4; ++n) {
      bf16x8 bv0 = *(const bf16x8*)&V_[(n * 16 + l16) * TSTR + quad * 8];
      bf16x8 bv1 = *(const bf16x8*)&V_[(n * 16 + l16) * TSTR + 32 + quad * 8];
      Os[n] = __builtin_amdgcn_mfma_f32_16x16x32_bf16(aP0, bv0, Os[n], 0, 0, 0);
      Os[n] = __builtin_amdgcn_mfma_f32_16x16x32_bf16(aP1, bv1, Os[n], 0, 0, 0);
    }
    if (anyL) {
      bf16x8 aL0 = aP0, aL1 = aP1;
#pragma unroll
      for (int j = 0; j < 8; ++j) {
        int sc = s0 + quad * 8 + j;
        if (sc < loA || sc > hiA) aL0[j] = 0;
        if (sc + 32 < loA || sc + 32 > hiA) aL1[j] = 0;
      }
#pragma unroll
      for (int n = 0; n < 4; ++n) {
        bf16x8 bv0 = *(const bf16x8*)&V_[(n * 16 + l16) * TSTR + quad * 8];
        bf16x8 bv1 = *(const bf16x8*)&V_[(n * 16 + l16) * TSTR + 32 + quad * 8];
        Ol[n] = __builtin_amdgcn_mfma_f32_16x16x32_bf16(aL0, bv0, Ol[n], 0, 0, 0);
        Ol[n] = __builtin_amdgcn_mfma_f32_16x16x32_bf16(aL1, bv1, Ol[n], 0, 0, 0);
      }
    }
    __syncthreads();
    if (it < 15) {
      unsigned short* KL = Ks[1 - cur];
      unsigned short* VL = Vs[1 - cur];
      *(uint4*)&KL[of0] = pk0; *(uint4*)&KL[of1] = pk1;
      *(uint4*)&VL[of0] = pv0; *(uint4*)&VL[of1] = pv1;
    }
    __syncthreads();
  }

  float* osdp = half ? Ps1 : Ps0;
  float* oloc = half ? Pl1 : Pl0;
  float* sp = st + half * 32768;
#pragma unroll
  for (int r = 0; r < 4; ++r) {
    int t = tbase + quad * 4 + r;
#pragma unroll
    for (int n = 0; n < 4; ++n) {
      size_t o = (size_t)(b * LDEC + t) * DMODEL + h * HD + n * 16 + l16;
      osdp[o] = Os[n][r];
      oloc[o] = Ol[n][r];
    }
    if (l16 == 0) {
      int sr = bh * 512 + t;
      sp[sr] = lS[r];
      sp[16384 + sr] = lL[r];
    }
  }
}

// fused: split-K combine (plain sums, max-free) + probsparse fill
__global__ __launch_bounds__(256) void combine_fill(
    float* __restrict__ braw, const float* __restrict__ Ps1,
    const float* __restrict__ Pl1, const float* __restrict__ st,
    const float* __restrict__ vmean, const int* __restrict__ sel) {
  int i4 = blockIdx.x * 256 + threadIdx.x;
  int i = i4 * 4;
  int col = i & 1023, bt = i >> 10;
  int t = bt & 511, b = bt >> 9, h = col >> 6, d = col & 63;
  int bh = b * 16 + h;
  int sr = bh * 512 + t;
  float iS = 1.f / (st[sr] + st[32768 + sr]);
  float iL = 1.f / (st[16384 + sr] + st[49152 + sr]);
  float4 s0 = *(const float4*)(braw + i);
  float4 s1 = *(const float4*)(Ps1 + i);
  float4 l0 = *(const float4*)(braw + 4194304 + i);
  float4 l1 = *(const float4*)(Pl1 + i);
  float4 os = make_float4((s0.x + s1.x) * iS, (s0.y + s1.y) * iS,
                          (s0.z + s1.z) * iS, (s0.w + s1.w) * iS);
  float4 ol = make_float4((l0.x + l1.x) * iL, (l0.y + l1.y) * iL,
                          (l0.z + l1.z) * iL, (l0.w + l1.w) * iL);
  *(float4*)(braw + i) = os;
  *(float4*)(braw + 4194304 + i) = ol;
  float4 pp = sel[sr] ? os : *(const float4*)(vmean + bh * 64 + d);
  *(float4*)(braw + 2097152 + i) = pp;
}

// ---------------- linear + cosine apply
__global__ __launch_bounds__(256) void lin_cos_apply(
    const float* __restrict__ Q, const float* __restrict__ kvL, const float* __restrict__ kvC,
    const float* __restrict__ ksL, const float* __restrict__ ksC,
    float* __restrict__ obL, float* __restrict__ obC) {
  __shared__ float sh[2][4][64];
  int tid = threadIdx.x, lane = tid & 63, g = tid >> 6;
  int row = blockIdx.x * 4 + g;
  int bh = row >> 9, t = row & 511;
  int b = bh >> 4, h = bh & 15;
  float qv = Q[(b * LDEC + t) * DMODEL + h * HD + lane];
  float x = qv * SCALE;
  float qfl = x > 0.f ? x + 1.f : __expf(x);
  float qnorm = sqrtf(wave_sum(qv * qv));
  float qn = qv / fmaxf(qnorm, 1e-12f);
  float qfc = fmaxf(qn, 0.f) + 1e-6f;
  sh[0][g][lane] = qfl;
  sh[1][g][lane] = qfc;
  float denL = fmaxf(wave_sum(qfl * ksL[bh * 64 + lane]), 1e-6f);
  float denC = fmaxf(wave_sum(qfc * ksC[bh * 64 + lane]), 1e-6f);
  const float* kvLb = kvL + bh * 4096;
  const float* kvCb = kvC + bh * 4096;
  float aL = 0.f, aC = 0.f;
#pragma unroll
  for (int d = 0; d < 64; ++d) {
    aL = fmaf(sh[0][g][d], kvLb[d * 64 + lane], aL);
    aC = fmaf(sh[1][g][d], kvCb[d * 64 + lane], aC);
  }
  int o = (b * LDEC + t) * DMODEL + h * HD + lane;
  obL[o] = aL / denL;
  obC[o] = aC / denC;
}

// ============ FUSED EPILOGUE CVT: cvt_w(Wo) + cvt_braw ======================
// grid: [0,256) cvt_w | [256,5376) cvt_braw. dyn LDS 17408.
__global__ __launch_bounds__(256) void epi_cvt(
    const float* __restrict__ Wo, unsigned short* __restrict__ Woh,
    const float* __restrict__ braw, unsigned short* __restrict__ braw16) {
  extern __shared__ char smraw[];
  int bx = blockIdx.x;
  int tid = threadIdx.x;
  if (bx < 256) {
    float (*t)[68] = (float(*)[68])smraw;
    int k0 = (bx >> 4) * 64, n0 = (bx & 15) * 64;
#pragma unroll
    for (int i = 0; i < 4; ++i) {
      int c = tid + 256 * i;
      int r = c >> 4, c4 = (c & 15) * 4;
      float4 v = *(const float4*)(Wo + (size_t)(k0 + r) * DMODEL + n0 + c4);
      t[c4 + 0][r] = v.x; t[c4 + 1][r] = v.y; t[c4 + 2][r] = v.z; t[c4 + 3][r] = v.w;
    }
    __syncthreads();
#pragma unroll
    for (int i = 0; i < 4; ++i) {
      int c = tid + 256 * i;
      int n = c >> 4, k4 = (c & 15) * 4;
      float4 v = *(const float4*)&t[n][k4];
      *(ushort4*)(Woh + (size_t)(n0 + n) * DMODEL + k0 + k4) =
          make_ushort4(f2bf(v.x), f2bf(v.y), f2bf(v.z), f2bf(v.w));
    }
  } else {
    int i = (bx - 256) * 256 + tid;
    float4 v = ((const float4*)braw)[i];
    *(ushort4*)(braw16 + i * 4) = make_ushort4(f2bf(v.x), f2bf(v.y), f2bf(v.z), f2bf(v.w));
  }
}

// ---------------- final combine
__global__ __launch_bounds__(256) void combine(
    const float* __restrict__ dec, const float* __restrict__ proj,
    const float* __restrict__ rmsw, const float* __restrict__ alphas,
    float* __restrict__ out) {
  __shared__ float red[4];
  int row = blockIdx.x;
  int tid = threadIdx.x, lane = tid & 63, g = tid >> 6;
  int base = row * DMODEL + tid * 4;
  float4 dv = *(const float4*)(dec + base);
  float4 wv = *(const float4*)(rmsw + tid * 4);
  float a[6];
  float amax = -INFINITY;
#pragma unroll
  for (int i = 0; i < 6; ++i) { a[i] = alphas[i]; amax = fmaxf(amax, a[i]); }
  float asum = 0.f;
#pragma unroll
  for (int i = 0; i < 6; ++i) { a[i] = __expf(a[i] - amax); asum += a[i]; }
#pragma unroll
  for (int i = 0; i < 6; ++i) a[i] /= asum;
  float4 acc = make_float4(a[0] * dv.x, a[0] * dv.y, a[0] * dv.z, a[0] * dv.w);
  for (int br = 0; br < 5; ++br) {
    float4 pv = *(const float4*)(proj + br * 1048576 + base);
    float4 xx = make_float4(dv.x + pv.x, dv.y + pv.y, dv.z + pv.z, dv.w + pv.w);
    float ssq = xx.x * xx.x + xx.y * xx.y + xx.z * xx.z + xx.w * xx.w;
    float wsum = wave_sum(ssq);
    if (lane == 0) red[g] = wsum;
    __syncthreads();
    float tot = red[0] + red[1] + red[2] + red[3];
    float rr = rsqrtf(tot / 1024.f + 1e-6f);
    float wb = a[br + 1];
    acc.x += wb * xx.x * rr * wv.x;
    acc.y += wb * xx.y * rr * wv.y;
    acc.z += wb * xx.z * rr * wv.z;
    acc.w += wb * xx.w * rr * wv.w;
    __syncthreads();
  }
  *(float4*)(out + base) = acc;
}

extern "C" void kernel_launch(void* const* d_in, const int* in_sizes, int n_in,
                              void* d_out, int out_size, void* d_ws, size_t ws_size,
                              hipStream_t stream) {
  const float* dec = (const float*)d_in[0];
  const float* enc = (const float*)d_in[1];
  const float* Wq = (const float*)d_in[2];
  const float* Wk = (const float*)d_in[3];
  const float* Wv = (const float*)d_in[4];
  const float* Wo = (const float*)d_in[5];
  const float* rmsw = (const float*)d_in[6];
  const float* alphas = (const float*)d_in[7];
  const int* sidx = (const int*)d_in[8];

  const size_t M = 1048576;
  float* ws = (float*)d_ws;
  float* Q    = ws;                                  // [0,1M)
  unsigned short* Kb16 = (unsigned short*)(ws + M);  // [1M,3M)
  float* KsAcc = ws + 3 * M;                         // [3M,+38912)
  float* V    = ws + 5 * M;                          // [5M,9M)
  float* Vtb_f= ws + 9 * M;                          // [9M,11M)
  float* braw = ws + 11 * M;                         // [11M,16M)
  unsigned short* Wqh = (unsigned short*)(ws + 9 * M);
  unsigned short* Wql = (unsigned short*)(ws + 9 * M + M / 2);
  unsigned short* Wkh = (unsigned short*)(ws + 10 * M);
  unsigned short* Wvh = (unsigned short*)(ws + 10 * M + M / 2);
  unsigned short* eh  = (unsigned short*)(ws + 11 * M);
  unsigned short* dh  = (unsigned short*)(ws + 15 * M);
  unsigned short* dl  = (unsigned short*)(ws + 15 * M + M / 2);
  unsigned short* Vtb = (unsigned short*)Vtb_f;
  float* kvpL = ws + 11 * M;
  float* kvpC = ws + 13 * M;
  float* kspL = ws + 15 * M;
  float* kspC = ws + 15 * M + 32768;
  float* vsp  = ws + 15 * M + 65536;
  float* Ps1   = ws + 5 * M;
  float* Pl1   = ws + 6 * M;
  float* stats = ws + 7 * M;
  float* tail = ws + 16 * M;
  float* kvL  = tail;
  float* kvC  = tail + 131072;
  float* ksL  = tail + 262144;
  float* ksC  = tail + 264192;
  float* vmean= tail + 266240;
  float* Mbuf = tail + 317440;
  int*   sel  = (int*)(tail + 333824);
  unsigned short* Woh = (unsigned short*)ws;
  unsigned short* braw16 = (unsigned short*)(ws + M);
  float* proj = ws + 3 * M + M / 2;

  hipLaunchKernelGGL(prologue, dim3(6040), dim3(256), 17408, stream,
                     dec, enc, Wq, Wk, Wv, sidx, dh, dl, eh, Wqh, Wql, Wkh, Wvh, KsAcc);
  hipLaunchKernelGGL(gemm_qkv, dim3(72, 8), dim3(512), 81920, stream,
                     dh, dl, Wqh, Wql, Q, eh, Wkh, Kb16, Wvh, V);
  hipLaunchKernelGGL(trio, dim3(1664), dim3(256), 43264, stream,
                     V, Vtb, Kb16, kvpL, kvpC, kspL, kspC, vsp, Q, KsAcc, Mbuf);
  hipLaunchKernelGGL(tail2, dim3(1080), dim3(256), 4224, stream,
                     kvpL, kvpC, kspL, kspC, vsp, kvL, kvC, ksL, ksC, vmean, Mbuf, sel);
  hipLaunchKernelGGL(attn_mfma, dim3(512), dim3(256), 0, stream, Q, Kb16, Vtb,
                     braw, Ps1, braw + 4 * M, Pl1, stats);
  hipLaunchKernelGGL(combine_fill, dim3(1024), dim3(256), 0, stream,
                     braw, Ps1, Pl1, stats, vmean, sel);
  hipLaunchKernelGGL(lin_cos_apply, dim3(4096), dim3(256), 0, stream, Q, kvL, kvC, ksL, ksC,
                     braw + M, braw + 3 * M);
  hipLaunchKernelGGL(epi_cvt, dim3(5376), dim3(256), 17408, stream, Wo, Woh, braw, braw16);
  hipLaunchKernelGGL(gemm_one, dim3(40, 8), dim3(512), 32768, stream, braw16, Woh, proj);
  hipLaunchKernelGGL(combine, dim3(1024), dim3(256), 0, stream, dec, proj, rmsw, alphas,
                     (float*)d_out);
}